// Round 1
// baseline (1415.372 us; speedup 1.0000x reference)
//
#include <hip/hip_runtime.h>
#include <float.h>

// Problem constants (from reference): B=8, N=1024, D=256, K=16384, H=1024, IN=256
#define DIM      256
#define NK       16384
#define NH       1024
#define NIN      256
#define NBN      8192          // B*N rows
#define KSPLIT   8
#define KCHUNK   (NK / KSPLIT) // 2048
#define TILE     64
#define LSTR     68            // LDS row stride (floats): mult of 4 (16B align), conflict-free

#define OFF_ZREC 0
#define OFF_ZENC (NBN * DIM)        // 2097152
#define OFF_ZEMB (2 * NBN * DIM)    // 4194304

// ---------------- t2[k] = ||embd_k||^2 ----------------
__global__ void t2_kernel(const float* __restrict__ embd, float* __restrict__ t2) {
    int wid  = threadIdx.x >> 6;
    int lane = threadIdx.x & 63;
    int row  = blockIdx.x * 4 + wid;            // grid 4096 * 4 waves = 16384 rows
    float4 v = ((const float4*)(embd + (size_t)row * DIM))[lane];
    float s = v.x * v.x + v.y * v.y + v.z * v.z + v.w * v.w;
    #pragma unroll
    for (int off = 32; off > 0; off >>= 1) s += __shfl_down(s, off);
    if (lane == 0) t2[row] = s;
}

// ---------------- fused distance + partial argmin ----------------
// score(q,k) = t2[k] - 2 * dot(X[q], E[k]);  argmin_k == argmin of ||q-t||^2
__global__ __launch_bounds__(256) void dist_argmin_kernel(
    const float* __restrict__ X, const float* __restrict__ E,
    const float* __restrict__ t2,
    float* __restrict__ pmin, int* __restrict__ pidx)
{
    __shared__ float Qs[TILE][LSTR];
    __shared__ float Es[TILE][LSTR];

    int bx = blockIdx.x;            // 128 qtiles * KSPLIT
    int qb = bx >> 3;               // KSPLIT == 8
    int ks = bx & 7;
    int q0 = qb * TILE;
    int k0 = ks * KCHUNK;

    int tid = threadIdx.x;
    int ty = tid >> 4;              // 0..15 (q dim)
    int tx = tid & 15;              // 0..15 (k dim)
    int srow = tid >> 4;            // staging row 0..15
    int scol = (tid & 15) * 4;      // staging col 0..60

    float best[4];
    int   bidx[4];
    #pragma unroll
    for (int i = 0; i < 4; ++i) { best[i] = FLT_MAX; bidx[i] = 0; }

    for (int kt = 0; kt < KCHUNK / TILE; ++kt) {   // 32
        int kb = k0 + kt * TILE;
        float acc[4][4] = {};
        #pragma unroll
        for (int dc = 0; dc < DIM / TILE; ++dc) {  // 4
            int db = dc * TILE;
            __syncthreads();
            #pragma unroll
            for (int r = 0; r < 4; ++r) {
                int row = srow + r * 16;
                float4 qv = *(const float4*)(X + (size_t)(q0 + row) * DIM + db + scol);
                *(float4*)(&Qs[row][scol]) = qv;
                float4 ev = *(const float4*)(E + (size_t)(kb + row) * DIM + db + scol);
                *(float4*)(&Es[row][scol]) = ev;
            }
            __syncthreads();
            #pragma unroll
            for (int dd = 0; dd < 16; ++dd) {
                float4 a[4], b[4];
                #pragma unroll
                for (int i = 0; i < 4; ++i) a[i] = *(const float4*)(&Qs[ty + 16 * i][dd * 4]);
                #pragma unroll
                for (int j = 0; j < 4; ++j) b[j] = *(const float4*)(&Es[tx + 16 * j][dd * 4]);
                #pragma unroll
                for (int i = 0; i < 4; ++i)
                    #pragma unroll
                    for (int j = 0; j < 4; ++j) {
                        acc[i][j] = fmaf(a[i].x, b[j].x, acc[i][j]);
                        acc[i][j] = fmaf(a[i].y, b[j].y, acc[i][j]);
                        acc[i][j] = fmaf(a[i].z, b[j].z, acc[i][j]);
                        acc[i][j] = fmaf(a[i].w, b[j].w, acc[i][j]);
                    }
            }
        }
        // argmin update: k ascending within thread over time -> strict < keeps first min
        #pragma unroll
        for (int j = 0; j < 4; ++j) {
            int k = kb + tx + 16 * j;
            float tk = t2[k];
            #pragma unroll
            for (int i = 0; i < 4; ++i) {
                float score = fmaf(-2.0f, acc[i][j], tk);
                if (score < best[i]) { best[i] = score; bidx[i] = k; }
            }
        }
    }

    // block reduction over tx (16 candidates per q row), tie -> smaller idx
    __syncthreads();
    float (*rs)[16] = (float (*)[16]) & Qs[0][0];
    int   (*ri)[16] = (int   (*)[16]) & Es[0][0];
    #pragma unroll
    for (int i = 0; i < 4; ++i) { rs[ty + 16 * i][tx] = best[i]; ri[ty + 16 * i][tx] = bidx[i]; }
    __syncthreads();
    if (tid < TILE) {
        float bv = rs[tid][0]; int bi = ri[tid][0];
        #pragma unroll
        for (int t = 1; t < 16; ++t) {
            float v = rs[tid][t]; int id = ri[tid][t];
            if (v < bv || (v == bv && id < bi)) { bv = v; bi = id; }
        }
        pmin[(size_t)(q0 + tid) * KSPLIT + ks] = bv;
        pidx[(size_t)(q0 + tid) * KSPLIT + ks] = bi;
    }
}

// ---------------- final argmin merge + gather Z_emb + copy Z_enc ----------------
__global__ void gather_kernel(const float* __restrict__ X, const float* __restrict__ E,
                              const float* __restrict__ pmin, const int* __restrict__ pidx,
                              float* __restrict__ out)
{
    int wid  = threadIdx.x >> 6;
    int lane = threadIdx.x & 63;
    int q = blockIdx.x * 4 + wid;               // grid 2048 * 4 = 8192
    float bv = pmin[(size_t)q * KSPLIT];
    int   bi = pidx[(size_t)q * KSPLIT];
    #pragma unroll
    for (int s = 1; s < KSPLIT; ++s) {
        float v = pmin[(size_t)q * KSPLIT + s];
        int  id = pidx[(size_t)q * KSPLIT + s];
        if (v < bv || (v == bv && id < bi)) { bv = v; bi = id; }
    }
    float4 ev = ((const float4*)(E + (size_t)bi * DIM))[lane];
    ((float4*)(out + OFF_ZEMB + (size_t)q * DIM))[lane] = ev;
    float4 xv = ((const float4*)(X + (size_t)q * DIM))[lane];
    ((float4*)(out + OFF_ZENC + (size_t)q * DIM))[lane] = xv;
}

// ---------------- tiled fp32 GEMM: C[M][N] = A[M][KD] * B[N][KD]^T + bias (opt LeakyReLU) ----------------
template <int KD, bool LRELU>
__global__ __launch_bounds__(256) void gemm_kernel(
    const float* __restrict__ A, const float* __restrict__ B,
    const float* __restrict__ bias, float* __restrict__ C, int Ncols)
{
    __shared__ float As[TILE][LSTR];
    __shared__ float Bs[TILE][LSTR];

    int ntiles = Ncols / TILE;
    int mt = blockIdx.x / ntiles;
    int nt = blockIdx.x % ntiles;
    int m0 = mt * TILE, n0 = nt * TILE;

    int tid = threadIdx.x;
    int ty = tid >> 4, tx = tid & 15;
    int srow = tid >> 4;
    int scol = (tid & 15) * 4;

    float acc[4][4] = {};
    #pragma unroll 1
    for (int dc = 0; dc < KD / TILE; ++dc) {
        int db = dc * TILE;
        __syncthreads();
        #pragma unroll
        for (int r = 0; r < 4; ++r) {
            int row = srow + r * 16;
            float4 av = *(const float4*)(A + (size_t)(m0 + row) * KD + db + scol);
            *(float4*)(&As[row][scol]) = av;
            float4 bv = *(const float4*)(B + (size_t)(n0 + row) * KD + db + scol);
            *(float4*)(&Bs[row][scol]) = bv;
        }
        __syncthreads();
        #pragma unroll
        for (int dd = 0; dd < 16; ++dd) {
            float4 a[4], b[4];
            #pragma unroll
            for (int i = 0; i < 4; ++i) a[i] = *(const float4*)(&As[ty + 16 * i][dd * 4]);
            #pragma unroll
            for (int j = 0; j < 4; ++j) b[j] = *(const float4*)(&Bs[tx + 16 * j][dd * 4]);
            #pragma unroll
            for (int i = 0; i < 4; ++i)
                #pragma unroll
                for (int j = 0; j < 4; ++j) {
                    acc[i][j] = fmaf(a[i].x, b[j].x, acc[i][j]);
                    acc[i][j] = fmaf(a[i].y, b[j].y, acc[i][j]);
                    acc[i][j] = fmaf(a[i].z, b[j].z, acc[i][j]);
                    acc[i][j] = fmaf(a[i].w, b[j].w, acc[i][j]);
                }
        }
    }
    #pragma unroll
    for (int j = 0; j < 4; ++j) {
        int n = n0 + tx + 16 * j;
        float bb = bias[n];
        #pragma unroll
        for (int i = 0; i < 4; ++i) {
            float v = acc[i][j] + bb;
            if (LRELU) v = fmaxf(v, 0.1f * v);
            C[(size_t)(m0 + ty + 16 * i) * Ncols + n] = v;
        }
    }
}

extern "C" void kernel_launch(void* const* d_in, const int* in_sizes, int n_in,
                              void* d_out, int out_size, void* d_ws, size_t ws_size,
                              hipStream_t stream) {
    const float* X    = (const float*)d_in[0];
    const float* embd = (const float*)d_in[1];
    const float* W1   = (const float*)d_in[2];
    const float* b1   = (const float*)d_in[3];
    const float* W2   = (const float*)d_in[4];
    const float* b2   = (const float*)d_in[5];
    float* out = (float*)d_out;

    float* w    = (float*)d_ws;
    float* t2   = w;                                    // 16384
    float* pmin = w + NK;                               // 8192*8
    int*   pidx = (int*)(w + NK + NBN * KSPLIT);        // 8192*8
    float* h    = w + NK + 2 * NBN * KSPLIT;            // 8192*1024

    t2_kernel<<<dim3(NK / 4), dim3(256), 0, stream>>>(embd, t2);
    dist_argmin_kernel<<<dim3((NBN / TILE) * KSPLIT), dim3(256), 0, stream>>>(
        X, embd, t2, pmin, pidx);
    gather_kernel<<<dim3(NBN / 4), dim3(256), 0, stream>>>(X, embd, pmin, pidx, out);
    gemm_kernel<DIM, true><<<dim3((NBN / TILE) * (NH / TILE)), dim3(256), 0, stream>>>(
        out + OFF_ZEMB, W1, b1, h, NH);
    gemm_kernel<NH, false><<<dim3((NBN / TILE) * (NIN / TILE)), dim3(256), 0, stream>>>(
        h, W2, b2, out + OFF_ZREC, NIN);
}

// Round 2
// 497.824 us; speedup vs baseline: 2.8431x; 2.8431x over previous
//
#include <hip/hip_runtime.h>
#include <float.h>

// B=8, N=1024, D=256, K=16384, H=1024, IN=256
#define DIM      256
#define NK       16384
#define NH       1024
#define NIN      256
#define NBN      8192
#define TILE     64
#define LSTR     68
#define KBT      16            // kb units (32 k each) per packed row-block: h=0..7, m=8..15
#define NTILES   128           // NK / 128

#define OFF_ZREC 0
#define OFF_ZENC (NBN * DIM)
#define OFF_ZEMB (2 * NBN * DIM)

using short8 = __attribute__((ext_vector_type(8))) short;
using f32x4  = __attribute__((ext_vector_type(4))) float;
typedef unsigned long long u64;
typedef unsigned int u32;

__device__ __forceinline__ unsigned short f2bf(float f) {
    u32 u = __float_as_uint(f);
    u32 r = (u + 0x7FFFu + ((u >> 16) & 1u)) >> 16;   // RNE
    return (unsigned short)r;
}
__device__ __forceinline__ float bf2f(unsigned short h) {
    return __uint_as_float(((u32)h) << 16);
}
__device__ __forceinline__ u64 umin64(u64 a, u64 b) { return a < b ? a : b; }
__device__ __forceinline__ u64 umax64(u64 a, u64 b) { return a > b ? a : b; }

__device__ __forceinline__ void gload16(const void* g, void* l) {
    __builtin_amdgcn_global_load_lds(
        (const __attribute__((address_space(1))) void*)g,
        (__attribute__((address_space(3))) void*)l, 16, 0, 0);
}

// ---------------- pack fp32 rows into bf16 hi/mid MFMA A/B fragments ----------------
// Fragment (16x16x32 bf16): lane l <-> row/col = l&15, k = (l>>4)*8 + i (i=0..7).
// dst[rb][kb][lane][8] bf16, kb: hi -> kc (0..7), mid -> 8+kc.
__global__ __launch_bounds__(256) void pack_kernel(const float* __restrict__ src,
                                                   unsigned short* __restrict__ dst) {
    int gid  = blockIdx.x * 4 + (threadIdx.x >> 6);
    int lane = threadIdx.x & 63;
    int rb = gid >> 3, kc = gid & 7;
    int row = rb * 16 + (lane & 15);
    int k0  = kc * 32 + (lane >> 4) * 8;
    const float* p = src + (size_t)row * DIM + k0;
    float x[8];
    *(float4*)(x)     = *(const float4*)(p);
    *(float4*)(x + 4) = *(const float4*)(p + 4);
    short8 hv, mv;
    #pragma unroll
    for (int i = 0; i < 8; ++i) {
        unsigned short hb = f2bf(x[i]);
        hv[i] = (short)hb;
        mv[i] = (short)f2bf(x[i] - bf2f(hb));
    }
    *(short8*)(dst + ((size_t)(rb * KBT + kc)     * 64 + lane) * 8) = hv;
    *(short8*)(dst + ((size_t)(rb * KBT + 8 + kc) * 64 + lane) * 8) = mv;
}

// ---------------- t2[k] = ||embd_k||^2 (exact fp32) ----------------
__global__ void t2_kernel(const float* __restrict__ embd, float* __restrict__ t2) {
    int wid  = threadIdx.x >> 6;
    int lane = threadIdx.x & 63;
    int row  = blockIdx.x * 4 + wid;
    float4 v = ((const float4*)(embd + (size_t)row * DIM))[lane];
    float s = v.x * v.x + v.y * v.y + v.z * v.z + v.w * v.w;
    #pragma unroll
    for (int off = 32; off > 0; off >>= 1) s += __shfl_down(s, off);
    if (lane == 0) t2[row] = s;
}

// ---------------- MFMA distance + per-block top-2 ----------------
// score(q,k) = t2[k] - 2 * qt_emulated;  qt = Xh*Eh + Xh*Em + Xm*Eh  (err ~3e-4)
__global__ __launch_bounds__(256) void dist_topk_kernel(
    const unsigned short* __restrict__ Xp, const unsigned short* __restrict__ Ep,
    const float* __restrict__ t2, u64* __restrict__ ptop)
{
    __shared__ __align__(16) char lds[32768];
    char* ldsA = lds;
    char* ldsB = lds + 16384;

    int bx = blockIdx.x;
    int mt = bx >> 7;          // 64 m-tiles
    int nt = bx & 127;         // 128 n-tiles
    int mb0 = mt * 8, nb0 = nt * 8;
    int m0 = mt * 128, n0 = nt * 128;

    int tid = threadIdx.x;
    int wid = tid >> 6, lane = tid & 63;
    int wm = wid >> 1, wn = wid & 1;

    f32x4 acc[4][4] = {};

    const int A_off[3] = {0, 0, 8};   // (h,h) (h,m) (m,h)
    const int B_off[3] = {0, 8, 0};

    for (int s = 0; s < 12; ++s) {                 // 3 products x 4 BK64-steps
        int p = s >> 2, kq = s & 3;
        int akb = A_off[p] + kq * 2;
        int bkb = B_off[p] + kq * 2;
        __syncthreads();                           // prev compute done
        #pragma unroll
        for (int r = 0; r < 4; ++r) {
            int ci = wid * 4 + r;                  // chunk 0..15: (rbl = ci>>1, kbl = ci&1)
            int rbl = ci >> 1, kbl = ci & 1;
            const unsigned short* ga =
                Xp + ((size_t)((mb0 + rbl) * KBT + akb + kbl) * 64 + lane) * 8;
            gload16(ga, ldsA + ci * 1024);
            const unsigned short* gb =
                Ep + ((size_t)((nb0 + rbl) * KBT + bkb + kbl) * 64 + lane) * 8;
            gload16(gb, ldsB + ci * 1024);
        }
        __syncthreads();                           // vmcnt drained before barrier
        #pragma unroll
        for (int kk = 0; kk < 2; ++kk) {
            short8 a[4], b[4];
            #pragma unroll
            for (int i = 0; i < 4; ++i)
                a[i] = *(const short8*)(ldsA + (((wm * 4 + i) * 2 + kk) << 10) + (lane << 4));
            #pragma unroll
            for (int j = 0; j < 4; ++j)
                b[j] = *(const short8*)(ldsB + (((wn * 4 + j) * 2 + kk) << 10) + (lane << 4));
            #pragma unroll
            for (int i = 0; i < 4; ++i)
                #pragma unroll
                for (int j = 0; j < 4; ++j)
                    acc[i][j] = __builtin_amdgcn_mfma_f32_16x16x32_bf16(
                        a[i], b[j], acc[i][j], 0, 0, 0);
        }
    }

    // ---- epilogue: per-row top-2 over this block's 128 cols ----
    // C frag: col = lane&15, row = (lane>>4)*4 + r
    int col_l = lane & 15, lg = lane >> 4;
    float t2v[4];
    #pragma unroll
    for (int j = 0; j < 4; ++j) t2v[j] = t2[n0 + wn * 64 + j * 16 + col_l];
    __syncthreads();
    u64* smt = (u64*)lds;                          // [128 rows][2 wn][2]
    #pragma unroll
    for (int i = 0; i < 4; ++i)
        #pragma unroll
        for (int r = 0; r < 4; ++r) {
            u64 kkey[4];
            #pragma unroll
            for (int j = 0; j < 4; ++j) {
                float sc = fmaf(-2.0f, acc[i][j][r], t2v[j]);
                u32 u = __float_as_uint(sc);
                u ^= ((u32)((int)u >> 31)) | 0x80000000u;   // order-preserving map
                kkey[j] = ((u64)u << 32) | (u32)(n0 + wn * 64 + j * 16 + col_l);
            }
            u64 m01 = umin64(kkey[0], kkey[1]), M01 = umax64(kkey[0], kkey[1]);
            u64 m23 = umin64(kkey[2], kkey[3]), M23 = umax64(kkey[2], kkey[3]);
            u64 a0 = umin64(m01, m23);
            u64 a1 = umin64(umax64(m01, m23), umin64(M01, M23));
            #pragma unroll
            for (int mask = 1; mask <= 8; mask <<= 1) {     // reduce 16 lane-group
                u64 b0 = (u64)__shfl_xor((unsigned long long)a0, mask);
                u64 b1 = (u64)__shfl_xor((unsigned long long)a1, mask);
                u64 c0 = umin64(a0, b0);
                u64 c1 = umin64(umax64(a0, b0), umin64(a1, b1));
                a0 = c0; a1 = c1;
            }
            if (col_l == 0) {
                int rl = wm * 64 + i * 16 + lg * 4 + r;
                smt[(rl * 2 + wn) * 2 + 0] = a0;
                smt[(rl * 2 + wn) * 2 + 1] = a1;
            }
        }
    __syncthreads();
    if (tid < 128) {
        u64 a0 = smt[(tid * 2 + 0) * 2], a1 = smt[(tid * 2 + 0) * 2 + 1];
        u64 b0 = smt[(tid * 2 + 1) * 2], b1 = smt[(tid * 2 + 1) * 2 + 1];
        u64 c0 = umin64(a0, b0);
        u64 c1 = umin64(umax64(a0, b0), umin64(a1, b1));
        size_t o = ((size_t)(m0 + tid) * NTILES + nt) * 2;
        ptop[o] = c0; ptop[o + 1] = c1;
    }
}

// ---------------- merge partials -> top-3 -> exact fp64 rescreen -> gather ----------------
__global__ __launch_bounds__(256) void merge_rescreen_kernel(
    const float* __restrict__ X, const float* __restrict__ E,
    const u64* __restrict__ ptop, float* __restrict__ out)
{
    int wid = threadIdx.x >> 6, lane = threadIdx.x & 63;
    int q = blockIdx.x * 4 + wid;
    const u64* row = ptop + (size_t)q * (NTILES * 2);
    u64 k[4];
    #pragma unroll
    for (int t = 0; t < 4; ++t) k[t] = row[lane * 4 + t];
    int cand[3];
    #pragma unroll
    for (int pass = 0; pass < 3; ++pass) {
        u64 m = umin64(umin64(k[0], k[1]), umin64(k[2], k[3]));
        #pragma unroll
        for (int mask = 1; mask < 64; mask <<= 1)
            m = umin64(m, (u64)__shfl_xor((unsigned long long)m, mask));
        cand[pass] = (int)(u32)m;
        #pragma unroll
        for (int t = 0; t < 4; ++t) if (k[t] == m) k[t] = ~0ull;
    }
    float4 qv = ((const float4*)(X + (size_t)q * DIM))[lane];
    double bd = 1e300; int bi = NK;
    #pragma unroll 1
    for (int c = 0; c < 3; ++c) {
        int idx = cand[c];
        float4 ev = ((const float4*)(E + (size_t)idx * DIM))[lane];
        double d0 = (double)qv.x - (double)ev.x;
        double d1 = (double)qv.y - (double)ev.y;
        double d2 = (double)qv.z - (double)ev.z;
        double d3 = (double)qv.w - (double)ev.w;
        double s = d0 * d0 + d1 * d1 + d2 * d2 + d3 * d3;
        #pragma unroll
        for (int off = 32; off > 0; off >>= 1) s += __shfl_down(s, off);
        s = __shfl(s, 0);                           // broadcast: all lanes agree
        if (s < bd || (s == bd && idx < bi)) { bd = s; bi = idx; }
    }
    float4 ev = ((const float4*)(E + (size_t)bi * DIM))[lane];
    ((float4*)(out + OFF_ZEMB + (size_t)q * DIM))[lane] = ev;
    ((float4*)(out + OFF_ZENC + (size_t)q * DIM))[lane] = qv;
}

// ---------------- tiled fp32 GEMM: C = A * B^T + bias (opt LeakyReLU) ----------------
template <int KD, bool LRELU>
__global__ __launch_bounds__(256) void gemm_kernel(
    const float* __restrict__ A, const float* __restrict__ B,
    const float* __restrict__ bias, float* __restrict__ C, int Ncols)
{
    __shared__ float As[TILE][LSTR];
    __shared__ float Bs[TILE][LSTR];

    int ntiles = Ncols / TILE;
    int mt = blockIdx.x / ntiles;
    int nt = blockIdx.x % ntiles;
    int m0 = mt * TILE, n0 = nt * TILE;

    int tid = threadIdx.x;
    int ty = tid >> 4, tx = tid & 15;
    int srow = tid >> 4;
    int scol = (tid & 15) * 4;

    float acc[4][4] = {};
    #pragma unroll 1
    for (int dc = 0; dc < KD / TILE; ++dc) {
        int db = dc * TILE;
        __syncthreads();
        #pragma unroll
        for (int r = 0; r < 4; ++r) {
            int row = srow + r * 16;
            float4 av = *(const float4*)(A + (size_t)(m0 + row) * KD + db + scol);
            *(float4*)(&As[row][scol]) = av;
            float4 bv = *(const float4*)(B + (size_t)(n0 + row) * KD + db + scol);
            *(float4*)(&Bs[row][scol]) = bv;
        }
        __syncthreads();
        #pragma unroll
        for (int dd = 0; dd < 16; ++dd) {
            float4 a[4], b[4];
            #pragma unroll
            for (int i = 0; i < 4; ++i) a[i] = *(const float4*)(&As[ty + 16 * i][dd * 4]);
            #pragma unroll
            for (int j = 0; j < 4; ++j) b[j] = *(const float4*)(&Bs[tx + 16 * j][dd * 4]);
            #pragma unroll
            for (int i = 0; i < 4; ++i)
                #pragma unroll
                for (int j = 0; j < 4; ++j) {
                    acc[i][j] = fmaf(a[i].x, b[j].x, acc[i][j]);
                    acc[i][j] = fmaf(a[i].y, b[j].y, acc[i][j]);
                    acc[i][j] = fmaf(a[i].z, b[j].z, acc[i][j]);
                    acc[i][j] = fmaf(a[i].w, b[j].w, acc[i][j]);
                }
        }
    }
    #pragma unroll
    for (int j = 0; j < 4; ++j) {
        int n = n0 + tx + 16 * j;
        float bb = bias[n];
        #pragma unroll
        for (int i = 0; i < 4; ++i) {
            float v = acc[i][j] + bb;
            if (LRELU) v = fmaxf(v, 0.1f * v);
            C[(size_t)(m0 + ty + 16 * i) * Ncols + n] = v;
        }
    }
}

extern "C" void kernel_launch(void* const* d_in, const int* in_sizes, int n_in,
                              void* d_out, int out_size, void* d_ws, size_t ws_size,
                              hipStream_t stream) {
    const float* X    = (const float*)d_in[0];
    const float* embd = (const float*)d_in[1];
    const float* W1   = (const float*)d_in[2];
    const float* b1   = (const float*)d_in[3];
    const float* W2   = (const float*)d_in[4];
    const float* b2   = (const float*)d_in[5];
    float* out = (float*)d_out;

    // workspace layout (h aliases ptop/Xp/lower-Ep, all dead before gemm1):
    // [t2 64KB][ptop 16.78MB][Xp 8.39MB][Ep 16.78MB]  total ~42 MB
    char* w = (char*)d_ws;
    float* t2            = (float*)w;
    u64*   ptop          = (u64*)(w + 65536);
    unsigned short* Xp   = (unsigned short*)(w + 65536 + 16777216);
    unsigned short* Ep   = (unsigned short*)(w + 65536 + 16777216 + 8388608);
    float* h             = (float*)(w + 65536);   // 32 MB alias

    pack_kernel<<<dim3(1024), dim3(256), 0, stream>>>(X, Xp);      // 512 rb
    pack_kernel<<<dim3(2048), dim3(256), 0, stream>>>(embd, Ep);   // 1024 rb
    t2_kernel<<<dim3(NK / 4), dim3(256), 0, stream>>>(embd, t2);
    dist_topk_kernel<<<dim3(8192), dim3(256), 0, stream>>>(Xp, Ep, t2, ptop);
    merge_rescreen_kernel<<<dim3(NBN / 4), dim3(256), 0, stream>>>(X, embd, ptop, out);
    gemm_kernel<DIM, true><<<dim3((NBN / TILE) * (NH / TILE)), dim3(256), 0, stream>>>(
        out + OFF_ZEMB, W1, b1, h, NH);
    gemm_kernel<NH, false><<<dim3((NBN / TILE) * (NIN / TILE)), dim3(256), 0, stream>>>(
        h, W2, b2, out + OFF_ZREC, NIN);
}

// Round 3
// 333.348 us; speedup vs baseline: 4.2459x; 1.4934x over previous
//
#include <hip/hip_runtime.h>
#include <float.h>

// B=8, N=1024, D=256, K=16384, H=1024, IN=256
#define DIM      256
#define NK       16384
#define NH       1024
#define NIN      256
#define NBN      8192
#define NTILES   128           // NK / 128

#define OFF_ZREC 0
#define OFF_ZENC (NBN * DIM)
#define OFF_ZEMB (2 * NBN * DIM)

using short8 = __attribute__((ext_vector_type(8))) short;
using f32x4  = __attribute__((ext_vector_type(4))) float;
typedef unsigned long long u64;
typedef unsigned int u32;

__device__ __forceinline__ u32 f2bf(float f) {
    u32 u = __float_as_uint(f);
    return (u + 0x7FFFu + ((u >> 16) & 1u)) >> 16;   // RNE
}
__device__ __forceinline__ float bf2f(u32 h) {
    return __uint_as_float(h << 16);
}
__device__ __forceinline__ u64 umin64(u64 a, u64 b) { return a < b ? a : b; }
__device__ __forceinline__ u64 umax64(u64 a, u64 b) { return a > b ? a : b; }

__device__ __forceinline__ void gload16(const void* g, void* l) {
    __builtin_amdgcn_global_load_lds(
        (const __attribute__((address_space(1))) void*)g,
        (__attribute__((address_space(3))) void*)l, 16, 0, 0);
}

// ---------------- pack fp32 [rows][KD] into bf16 hi/mid MFMA fragments ----------------
// Fragment (16x16x32 bf16): lane l <-> row/col = l&15, k = (l>>4)*8 + i.
// dst[rb][unit][lane][8]: unit hi = kc (0..KD/32-1), mid = KD/32 + kc.
template <int KD>
__global__ __launch_bounds__(256) void pack_kernel(const float* __restrict__ src,
                                                   unsigned short* __restrict__ dst) {
    constexpr int KC = KD / 32;
    int gid  = blockIdx.x * 4 + (threadIdx.x >> 6);
    int lane = threadIdx.x & 63;
    int rb = gid / KC, kc = gid % KC;
    int row = rb * 16 + (lane & 15);
    int k0  = kc * 32 + (lane >> 4) * 8;
    const float* p = src + (size_t)row * KD + k0;
    float x[8];
    *(float4*)(x)     = *(const float4*)(p);
    *(float4*)(x + 4) = *(const float4*)(p + 4);
    short8 hv, mv;
    #pragma unroll
    for (int i = 0; i < 8; ++i) {
        u32 hb = f2bf(x[i]);
        hv[i] = (short)hb;
        mv[i] = (short)f2bf(x[i] - bf2f(hb));
    }
    *(short8*)(dst + ((size_t)(rb * (2 * KC) + kc)      * 64 + lane) * 8) = hv;
    *(short8*)(dst + ((size_t)(rb * (2 * KC) + KC + kc) * 64 + lane) * 8) = mv;
}

// ---------------- t2[k] = ||embd_k||^2 (exact fp32) ----------------
__global__ void t2_kernel(const float* __restrict__ embd, float* __restrict__ t2) {
    int wid  = threadIdx.x >> 6;
    int lane = threadIdx.x & 63;
    int row  = blockIdx.x * 4 + wid;
    float4 v = ((const float4*)(embd + (size_t)row * DIM))[lane];
    float s = v.x * v.x + v.y * v.y + v.z * v.z + v.w * v.w;
    #pragma unroll
    for (int off = 32; off > 0; off >>= 1) s += __shfl_down(s, off);
    if (lane == 0) t2[row] = s;
}

// ---------------- MFMA distance + per-block top-2 (double-buffered) ----------------
__global__ __launch_bounds__(256) void dist_topk_kernel(
    const unsigned short* __restrict__ Xp, const unsigned short* __restrict__ Ep,
    const float* __restrict__ t2, u64* __restrict__ ptop)
{
    __shared__ __align__(16) char lds[67584];   // main: 2 x (16K A + 16K B); epi: 128x33x16

    int bx = blockIdx.x;
    int mt = bx >> 7;          // 64 m-tiles
    int nt = bx & 127;         // 128 n-tiles
    int mb0 = mt * 8, nb0 = nt * 8;
    int m0 = mt * 128, n0 = nt * 128;

    int tid = threadIdx.x;
    int wid = tid >> 6, lane = tid & 63;
    int wm = wid >> 1, wn = wid & 1;

    f32x4 acc[4][4] = {};

    auto STAGE = [&](int s, int b) {
        int p = s >> 2, kq = s & 3;
        int akb = (p == 2 ? 8 : 0) + kq * 2;   // products: hh, hm, mh
        int bkb = (p == 1 ? 8 : 0) + kq * 2;
        char* LA = lds + b * 32768;
        char* LB = LA + 16384;
        #pragma unroll
        for (int r = 0; r < 4; ++r) {
            int ci = wid * 4 + r;              // 16 chunks: rbl = ci>>1, kbl = ci&1
            int rbl = ci >> 1, kbl = ci & 1;
            gload16(Xp + ((size_t)((mb0 + rbl) * 16 + akb + kbl) * 64 + lane) * 8,
                    LA + ci * 1024);
            gload16(Ep + ((size_t)((nb0 + rbl) * 16 + bkb + kbl) * 64 + lane) * 8,
                    LB + ci * 1024);
        }
    };

    STAGE(0, 0);
    __syncthreads();
    #pragma unroll
    for (int s = 0; s < 12; ++s) {
        int cur = s & 1;
        if (s + 1 < 12) STAGE(s + 1, cur ^ 1);
        const char* LA = lds + cur * 32768;
        const char* LB = LA + 16384;
        #pragma unroll
        for (int kk = 0; kk < 2; ++kk) {
            short8 a[4], b[4];
            #pragma unroll
            for (int i = 0; i < 4; ++i)
                a[i] = *(const short8*)(LA + (((wm * 4 + i) * 2 + kk) << 10) + (lane << 4));
            #pragma unroll
            for (int j = 0; j < 4; ++j)
                b[j] = *(const short8*)(LB + (((wn * 4 + j) * 2 + kk) << 10) + (lane << 4));
            #pragma unroll
            for (int i = 0; i < 4; ++i)
                #pragma unroll
                for (int j = 0; j < 4; ++j)
                    acc[i][j] = __builtin_amdgcn_mfma_f32_16x16x32_bf16(
                        a[i], b[j], acc[i][j], 0, 0, 0);
        }
        __syncthreads();
    }

    // ---- epilogue: per-row top-2 over this block's 128 cols ----
    // C frag: col = lane&15, row = (lane>>4)*4 + r
    int col_l = lane & 15, lg = lane >> 4;
    float t2v[4];
    #pragma unroll
    for (int j = 0; j < 4; ++j) t2v[j] = t2[n0 + wn * 64 + j * 16 + col_l];

    u64* cand = (u64*)lds;                     // [128 rows][33 slots][2], stride 33 kills conflicts
    #pragma unroll
    for (int i = 0; i < 4; ++i)
        #pragma unroll
        for (int r = 0; r < 4; ++r) {
            int row_l = wm * 64 + i * 16 + lg * 4 + r;
            u64 kkey[4];
            #pragma unroll
            for (int j = 0; j < 4; ++j) {
                float sc = fmaf(-2.0f, acc[i][j][r], t2v[j]);
                u32 u = __float_as_uint(sc);
                u ^= ((u32)((int)u >> 31)) | 0x80000000u;   // order-preserving map
                kkey[j] = ((u64)u << 32) | (u32)(n0 + wn * 64 + j * 16 + col_l);
            }
            u64 m01 = umin64(kkey[0], kkey[1]), M01 = umax64(kkey[0], kkey[1]);
            u64 m23 = umin64(kkey[2], kkey[3]), M23 = umax64(kkey[2], kkey[3]);
            u64 a0 = umin64(m01, m23);
            u64 a1 = umin64(umax64(m01, m23), umin64(M01, M23));
            u64* p = cand + ((size_t)row_l * 33 + wn * 16 + col_l) * 2;
            p[0] = a0; p[1] = a1;
        }
    __syncthreads();
    if (tid < 128) {
        int row = tid;
        u64 b0 = ~0ull, b1 = ~0ull;
        #pragma unroll
        for (int sl = 0; sl < 32; ++sl) {
            u64 a0 = cand[((size_t)row * 33 + sl) * 2];
            u64 a1 = cand[((size_t)row * 33 + sl) * 2 + 1];
            u64 n0_ = umin64(b0, a0);
            u64 n1_ = umin64(umax64(b0, a0), umin64(b1, a1));
            b0 = n0_; b1 = n1_;
        }
        size_t o = ((size_t)(m0 + row) * NTILES + nt) * 2;
        ptop[o] = b0; ptop[o + 1] = b1;
    }
}

// ---------------- merge partials -> top-3 -> exact fp64 rescreen -> gather ----------------
__global__ __launch_bounds__(256) void merge_rescreen_kernel(
    const float* __restrict__ X, const float* __restrict__ E,
    const u64* __restrict__ ptop, float* __restrict__ out)
{
    int wid = threadIdx.x >> 6, lane = threadIdx.x & 63;
    int q = blockIdx.x * 4 + wid;
    const u64* row = ptop + (size_t)q * (NTILES * 2);
    u64 k[4];
    #pragma unroll
    for (int t = 0; t < 4; ++t) k[t] = row[lane * 4 + t];
    int cand[3];
    #pragma unroll
    for (int pass = 0; pass < 3; ++pass) {
        u64 m = umin64(umin64(k[0], k[1]), umin64(k[2], k[3]));
        #pragma unroll
        for (int mask = 1; mask < 64; mask <<= 1)
            m = umin64(m, (u64)__shfl_xor((unsigned long long)m, mask));
        cand[pass] = (int)(u32)m;
        #pragma unroll
        for (int t = 0; t < 4; ++t) if (k[t] == m) k[t] = ~0ull;
    }
    float4 qv = ((const float4*)(X + (size_t)q * DIM))[lane];
    double bd = 1e300; int bi = NK;
    #pragma unroll 1
    for (int c = 0; c < 3; ++c) {
        int idx = cand[c];
        float4 ev = ((const float4*)(E + (size_t)idx * DIM))[lane];
        double d0 = (double)qv.x - (double)ev.x;
        double d1 = (double)qv.y - (double)ev.y;
        double d2 = (double)qv.z - (double)ev.z;
        double d3 = (double)qv.w - (double)ev.w;
        double s = d0 * d0 + d1 * d1 + d2 * d2 + d3 * d3;
        #pragma unroll
        for (int off = 32; off > 0; off >>= 1) s += __shfl_down(s, off);
        s = __shfl(s, 0);
        if (s < bd || (s == bd && idx < bi)) { bd = s; bi = idx; }
    }
    float4 ev = ((const float4*)(E + (size_t)bi * DIM))[lane];
    ((float4*)(out + OFF_ZEMB + (size_t)q * DIM))[lane] = ev;
    ((float4*)(out + OFF_ZENC + (size_t)q * DIM))[lane] = qv;
}

// ---------------- 3-limb bf16 MFMA GEMM: C[M][N] = A[M][KD]*B[N][KD]^T + bias ----------------
// G1: +LeakyReLU, write h packed 2-limb into Hp (gemm2 A-fragment layout, KD2=1024)
// else: write fp32 to C (Ncols = NT*BN)
template <int KD, int NRB_B, int NT, bool G1>
__global__ __launch_bounds__(256) void gemm_mfma_kernel(
    const unsigned short* __restrict__ Ap, const unsigned short* __restrict__ Bp,
    const float* __restrict__ bias, float* __restrict__ C,
    unsigned short* __restrict__ Hp)
{
    constexpr int AU    = KD / 32;          // hi units
    constexpr int KBT   = 2 * AU;
    constexpr int STEPS = 3 * (KD / 64);
    constexpr int FJ    = NRB_B / 2;        // n-frags per wave
    constexpr int CB    = NRB_B * 2;        // B chunks per step
    constexpr int PW    = (16 + CB) / 4;    // chunks per wave
    constexpr int BUFSZ = (16 + CB) * 1024;
    constexpr int BN    = NRB_B * 16;
    constexpr int LDSSZ = (2 * BUFSZ > 65536 || G1) ? 65536 : 2 * BUFSZ;

    __shared__ __align__(16) char lds[LDSSZ];

    int bx = blockIdx.x;
    int mt = bx / NT, nt = bx % NT;
    int mb0 = mt * 8, nb0 = nt * NRB_B;
    int m0 = mt * 128, n0 = nt * BN;

    int tid = threadIdx.x;
    int wid = tid >> 6, lane = tid & 63;
    int wm = wid >> 1, wn = wid & 1;

    f32x4 acc[4][FJ] = {};

    auto STAGE = [&](int s, int b) {
        int p = s / (KD / 64), kq = s % (KD / 64);
        int akb = (p == 2 ? AU : 0) + kq * 2;
        int bkb = (p == 1 ? AU : 0) + kq * 2;
        char* LA = lds + b * BUFSZ;
        char* LB = LA + 16384;
        #pragma unroll
        for (int r = 0; r < PW; ++r) {
            int ci = wid * PW + r;
            if (ci < 16) {
                int rbl = ci >> 1, kbl = ci & 1;
                gload16(Ap + ((size_t)((mb0 + rbl) * KBT + akb + kbl) * 64 + lane) * 8,
                        LA + ci * 1024);
            } else {
                int cj = ci - 16, rbl = cj >> 1, kbl = cj & 1;
                gload16(Bp + ((size_t)((nb0 + rbl) * KBT + bkb + kbl) * 64 + lane) * 8,
                        LB + cj * 1024);
            }
        }
    };

    STAGE(0, 0);
    __syncthreads();
    for (int s = 0; s < STEPS; ++s) {
        int cur = s & 1;
        if (s + 1 < STEPS) STAGE(s + 1, cur ^ 1);
        const char* LA = lds + cur * BUFSZ;
        const char* LB = LA + 16384;
        #pragma unroll
        for (int kk = 0; kk < 2; ++kk) {
            short8 a[4], b[FJ];
            #pragma unroll
            for (int i = 0; i < 4; ++i)
                a[i] = *(const short8*)(LA + (((wm * 4 + i) * 2 + kk) << 10) + (lane << 4));
            #pragma unroll
            for (int j = 0; j < FJ; ++j)
                b[j] = *(const short8*)(LB + (((wn * FJ + j) * 2 + kk) << 10) + (lane << 4));
            #pragma unroll
            for (int i = 0; i < 4; ++i)
                #pragma unroll
                for (int j = 0; j < FJ; ++j)
                    acc[i][j] = __builtin_amdgcn_mfma_f32_16x16x32_bf16(
                        a[i], b[j], acc[i][j], 0, 0, 0);
        }
        __syncthreads();
    }

    int col_l = lane & 15, lg = lane >> 4;
    if (!G1) {
        #pragma unroll
        for (int j = 0; j < FJ; ++j) {
            int n = n0 + wn * (BN / 2) + j * 16 + col_l;
            float bb = bias[n];
            #pragma unroll
            for (int i = 0; i < 4; ++i)
                #pragma unroll
                for (int r = 0; r < 4; ++r) {
                    int m = m0 + wm * 64 + i * 16 + lg * 4 + r;
                    C[(size_t)m * (NT * BN) + n] = acc[i][j][r] + bb;
                }
        }
    } else {
        // bias + LeakyReLU + 2-limb split -> swizzled LDS u32 tile -> repack to Hp frags
        u32* lds32 = (u32*)lds;
        #pragma unroll
        for (int j = 0; j < FJ; ++j) {
            int coln = wn * 64 + j * 16 + col_l;
            float bb = bias[n0 + coln];
            #pragma unroll
            for (int i = 0; i < 4; ++i)
                #pragma unroll
                for (int r = 0; r < 4; ++r) {
                    int row = wm * 64 + i * 16 + lg * 4 + r;
                    float v = acc[i][j][r] + bb;
                    v = fmaxf(v, 0.1f * v);
                    u32 hb = f2bf(v);
                    u32 mb = f2bf(v - bf2f(hb));
                    int sw = ((row >> 2) & 3) << 3;
                    lds32[row * 128 + (coln ^ sw)] = (hb << 16) | mb;
                }
        }
        __syncthreads();
        #pragma unroll
        for (int rbw = 0; rbw < 2; ++rbw) {
            int rrb = wid * 2 + rbw;
            int row = rrb * 16 + (lane & 15);
            int sw  = ((row >> 2) & 3) << 3;
            size_t rbg = mb0 + rrb;
            #pragma unroll
            for (int kc = 0; kc < 4; ++kc) {
                int c0 = kc * 32 + (lane >> 4) * 8;
                const u32* bp_ = lds32 + row * 128 + (c0 ^ sw);
                uint4 u0 = *(const uint4*)bp_;
                uint4 u1 = *(const uint4*)(bp_ + 4);
                short8 h8, m8;
                h8[0] = (short)(u0.x >> 16); m8[0] = (short)(u0.x & 0xFFFF);
                h8[1] = (short)(u0.y >> 16); m8[1] = (short)(u0.y & 0xFFFF);
                h8[2] = (short)(u0.z >> 16); m8[2] = (short)(u0.z & 0xFFFF);
                h8[3] = (short)(u0.w >> 16); m8[3] = (short)(u0.w & 0xFFFF);
                h8[4] = (short)(u1.x >> 16); m8[4] = (short)(u1.x & 0xFFFF);
                h8[5] = (short)(u1.y >> 16); m8[5] = (short)(u1.y & 0xFFFF);
                h8[6] = (short)(u1.z >> 16); m8[6] = (short)(u1.z & 0xFFFF);
                h8[7] = (short)(u1.w >> 16); m8[7] = (short)(u1.w & 0xFFFF);
                int ku = (n0 >> 5) + kc;     // hi unit of KD2=1024 (AU2=32)
                *(short8*)(Hp + ((size_t)(rbg * 64 + ku)      * 64 + lane) * 8) = h8;
                *(short8*)(Hp + ((size_t)(rbg * 64 + 32 + ku) * 64 + lane) * 8) = m8;
            }
        }
    }
}

extern "C" void kernel_launch(void* const* d_in, const int* in_sizes, int n_in,
                              void* d_out, int out_size, void* d_ws, size_t ws_size,
                              hipStream_t stream) {
    const float* X    = (const float*)d_in[0];
    const float* embd = (const float*)d_in[1];
    const float* W1   = (const float*)d_in[2];
    const float* b1   = (const float*)d_in[3];
    const float* W2   = (const float*)d_in[4];
    const float* b2   = (const float*)d_in[5];
    float* out = (float*)d_out;

    // ws layout (MiB): t2[0,0.06) ptop[1,17) Xp[17,25) Ep[25,41)
    // after dist/merge: Hp[1,33) (over ptop+Xp+Ep-low), Zp[33,41), W1p[41,42), W2p[42,43)
    char* w = (char*)d_ws;
    float* t2 = (float*)w;
    u64*  ptop = (u64*)(w + (1u << 20));
    unsigned short* Xp  = (unsigned short*)(w + (17u << 20));
    unsigned short* Ep  = (unsigned short*)(w + (25u << 20));
    unsigned short* Hp  = (unsigned short*)(w + (1u  << 20));
    unsigned short* Zp  = (unsigned short*)(w + (33u << 20));
    unsigned short* W1p = (unsigned short*)(w + (41u << 20));
    unsigned short* W2p = (unsigned short*)(w + (42u << 20));

    pack_kernel<256> <<<dim3(1024), dim3(256), 0, stream>>>(X, Xp);
    pack_kernel<256> <<<dim3(2048), dim3(256), 0, stream>>>(embd, Ep);
    pack_kernel<256> <<<dim3(128),  dim3(256), 0, stream>>>(W1, W1p);
    pack_kernel<1024><<<dim3(128),  dim3(256), 0, stream>>>(W2, W2p);
    t2_kernel<<<dim3(NK / 4), dim3(256), 0, stream>>>(embd, t2);
    dist_topk_kernel<<<dim3(8192), dim3(256), 0, stream>>>(Xp, Ep, t2, ptop);
    merge_rescreen_kernel<<<dim3(NBN / 4), dim3(256), 0, stream>>>(X, embd, ptop, out);
    pack_kernel<256> <<<dim3(1024), dim3(256), 0, stream>>>(out + OFF_ZEMB, Zp);
    gemm_mfma_kernel<256, 8, 8, true><<<dim3(512), dim3(256), 0, stream>>>(
        Zp, W1p, b1, nullptr, Hp);
    gemm_mfma_kernel<1024, 4, 4, false><<<dim3(256), dim3(256), 0, stream>>>(
        Hp, W2p, b2, out + OFF_ZREC, nullptr);
}

// Round 4
// 234.514 us; speedup vs baseline: 6.0353x; 1.4214x over previous
//
#include <hip/hip_runtime.h>
#include <float.h>

// B=8, N=1024, D=256, K=16384, H=1024, IN=256
#define DIM      256
#define NK       16384
#define NH       1024
#define NIN      256
#define NBN      8192
#define NTILES   128           // NK / 128

#define OFF_ZREC 0
#define OFF_ZENC (NBN * DIM)
#define OFF_ZEMB (2 * NBN * DIM)

using short8 = __attribute__((ext_vector_type(8))) short;
using f32x4  = __attribute__((ext_vector_type(4))) float;
typedef unsigned long long u64;
typedef unsigned int u32;

__device__ __forceinline__ u32 f2bf(float f) {
    u32 u = __float_as_uint(f);
    return (u + 0x7FFFu + ((u >> 16) & 1u)) >> 16;   // RNE
}
__device__ __forceinline__ float bf2f(u32 h) {
    return __uint_as_float(h << 16);
}
__device__ __forceinline__ u64 umin64(u64 a, u64 b) { return a < b ? a : b; }
__device__ __forceinline__ u64 umax64(u64 a, u64 b) { return a > b ? a : b; }

__device__ __forceinline__ void gload16(const void* g, void* l) {
    __builtin_amdgcn_global_load_lds(
        (const __attribute__((address_space(1))) void*)g,
        (__attribute__((address_space(3))) void*)l, 16, 0, 0);
}

// pack one 16x32 chunk of fp32 [rows][KD] into bf16 MFMA fragment(s).
// Fragment (16x16x32 bf16): lane l <-> row = l&15, k = (l>>4)*8 + i.
// dst[rb][unit][lane][8]: hi unit = kc, mid unit = KD/32 + kc.
__device__ __forceinline__ void pack_frag(const float* __restrict__ src,
                                          unsigned short* __restrict__ dst,
                                          int KD, int KBT, int rb, int kc,
                                          int lane, bool with_mid) {
    int row = rb * 16 + (lane & 15);
    int k0  = kc * 32 + (lane >> 4) * 8;
    const float* p = src + (size_t)row * KD + k0;
    float x[8];
    *(float4*)(x)     = *(const float4*)(p);
    *(float4*)(x + 4) = *(const float4*)(p + 4);
    short8 hv, mv;
    #pragma unroll
    for (int i = 0; i < 8; ++i) {
        u32 hb = f2bf(x[i]);
        hv[i] = (short)hb;
        mv[i] = (short)f2bf(x[i] - bf2f(hb));
    }
    *(short8*)(dst + ((size_t)(rb * KBT + kc) * 64 + lane) * 8) = hv;
    if (with_mid)
        *(short8*)(dst + ((size_t)(rb * KBT + KD / 32 + kc) * 64 + lane) * 8) = mv;
}

// ---------------- fused prep: pack X(hi), E(full), W1(full), W2(full) + t2 ----------------
__global__ __launch_bounds__(256) void prep_kernel(
    const float* __restrict__ X, const float* __restrict__ E,
    const float* __restrict__ W1, const float* __restrict__ W2,
    unsigned short* __restrict__ Xp, unsigned short* __restrict__ Ep,
    unsigned short* __restrict__ W1p, unsigned short* __restrict__ W2p,
    float* __restrict__ t2)
{
    int b = blockIdx.x;
    int wid = threadIdx.x >> 6, lane = threadIdx.x & 63;
    if (b < 1024) {                         // X hi-only: 4096 gids (512 rb x 8 kc)
        int gid = b * 4 + wid;
        pack_frag(X, Xp, 256, 8, gid >> 3, gid & 7, lane, false);
    } else if (b < 3072) {                  // E full: 8192 gids (1024 rb x 8 kc)
        int gid = (b - 1024) * 4 + wid;
        pack_frag(E, Ep, 256, 16, gid >> 3, gid & 7, lane, true);
    } else if (b < 3200) {                  // W1 full: 512 gids (64 rb x 8 kc)
        int gid = (b - 3072) * 4 + wid;
        pack_frag(W1, W1p, 256, 16, gid >> 3, gid & 7, lane, true);
    } else if (b < 3328) {                  // W2 full: 512 gids (16 rb x 32 kc)
        int gid = (b - 3200) * 4 + wid;
        pack_frag(W2, W2p, 1024, 64, gid >> 5, gid & 31, lane, true);
    } else {                                // t2: 4096 gids x 4 rows
        int gid = (b - 3328) * 4 + wid;
        #pragma unroll
        for (int r = 0; r < 4; ++r) {
            int row = gid * 4 + r;
            float4 v = ((const float4*)(E + (size_t)row * DIM))[lane];
            float s = v.x * v.x + v.y * v.y + v.z * v.z + v.w * v.w;
            #pragma unroll
            for (int off = 32; off > 0; off >>= 1) s += __shfl_down(s, off);
            if (lane == 0) t2[row] = s;
        }
    }
}

// ---------------- MFMA distance (bf16 hi-only) + per-block top-2 ----------------
__global__ __launch_bounds__(256) void dist_topk_kernel(
    const unsigned short* __restrict__ Xp, const unsigned short* __restrict__ Ep,
    const float* __restrict__ t2, u64* __restrict__ ptop)
{
    __shared__ __align__(16) char lds[67584];   // main: 2 x 32K dbuf; epi: 128x33x16B

    int bx = blockIdx.x;
    int mt = bx >> 7;          // 64 m-tiles
    int nt = bx & 127;         // 128 n-tiles
    int mb0 = mt * 8, nb0 = nt * 8;
    int m0 = mt * 128, n0 = nt * 128;

    int tid = threadIdx.x;
    int wid = tid >> 6, lane = tid & 63;
    int wm = wid >> 1, wn = wid & 1;

    f32x4 acc[4][4] = {};

    auto STAGE = [&](int s, int b) {
        char* LA = lds + b * 32768;
        char* LB = LA + 16384;
        #pragma unroll
        for (int r = 0; r < 4; ++r) {
            int ci = wid * 4 + r;              // 16 chunks: rbl = ci>>1, kbl = ci&1
            int rbl = ci >> 1, kbl = ci & 1;
            gload16(Xp + ((size_t)((mb0 + rbl) * 8  + s * 2 + kbl) * 64 + lane) * 8,
                    LA + ci * 1024);
            gload16(Ep + ((size_t)((nb0 + rbl) * 16 + s * 2 + kbl) * 64 + lane) * 8,
                    LB + ci * 1024);
        }
    };

    STAGE(0, 0);
    __syncthreads();
    #pragma unroll
    for (int s = 0; s < 4; ++s) {
        int cur = s & 1;
        if (s + 1 < 4) STAGE(s + 1, cur ^ 1);
        const char* LA = lds + cur * 32768;
        const char* LB = LA + 16384;
        #pragma unroll
        for (int kk = 0; kk < 2; ++kk) {
            short8 a[4], b[4];
            #pragma unroll
            for (int i = 0; i < 4; ++i)
                a[i] = *(const short8*)(LA + (((wm * 4 + i) * 2 + kk) << 10) + (lane << 4));
            #pragma unroll
            for (int j = 0; j < 4; ++j)
                b[j] = *(const short8*)(LB + (((wn * 4 + j) * 2 + kk) << 10) + (lane << 4));
            #pragma unroll
            for (int i = 0; i < 4; ++i)
                #pragma unroll
                for (int j = 0; j < 4; ++j)
                    acc[i][j] = __builtin_amdgcn_mfma_f32_16x16x32_bf16(
                        a[i], b[j], acc[i][j], 0, 0, 0);
        }
        __syncthreads();
    }

    // ---- epilogue: per-row top-2 over this block's 128 cols ----
    // C frag: col = lane&15, row = (lane>>4)*4 + r
    int col_l = lane & 15, lg = lane >> 4;
    float t2v[4];
    #pragma unroll
    for (int j = 0; j < 4; ++j) t2v[j] = t2[n0 + wn * 64 + j * 16 + col_l];

    u64* cand = (u64*)lds;                     // [128 rows][33 slots][2]
    #pragma unroll
    for (int i = 0; i < 4; ++i)
        #pragma unroll
        for (int r = 0; r < 4; ++r) {
            int row_l = wm * 64 + i * 16 + lg * 4 + r;
            u64 kkey[4];
            #pragma unroll
            for (int j = 0; j < 4; ++j) {
                float sc = fmaf(-2.0f, acc[i][j][r], t2v[j]);
                u32 u = __float_as_uint(sc);
                u ^= ((u32)((int)u >> 31)) | 0x80000000u;   // order-preserving map
                kkey[j] = ((u64)u << 32) | (u32)(n0 + wn * 64 + j * 16 + col_l);
            }
            u64 m01 = umin64(kkey[0], kkey[1]), M01 = umax64(kkey[0], kkey[1]);
            u64 m23 = umin64(kkey[2], kkey[3]), M23 = umax64(kkey[2], kkey[3]);
            u64 a0 = umin64(m01, m23);
            u64 a1 = umin64(umax64(m01, m23), umin64(M01, M23));
            u64* p = cand + ((size_t)row_l * 33 + wn * 16 + col_l) * 2;
            p[0] = a0; p[1] = a1;
        }
    __syncthreads();
    if (tid < 128) {
        int row = tid;
        u64 b0 = ~0ull, b1 = ~0ull;
        #pragma unroll
        for (int sl = 0; sl < 32; ++sl) {
            u64 a0 = cand[((size_t)row * 33 + sl) * 2];
            u64 a1 = cand[((size_t)row * 33 + sl) * 2 + 1];
            u64 n0_ = umin64(b0, a0);
            u64 n1_ = umin64(umax64(b0, a0), umin64(b1, a1));
            b0 = n0_; b1 = n1_;
        }
        size_t o = ((size_t)(m0 + row) * NTILES + nt) * 2;
        ptop[o] = b0; ptop[o + 1] = b1;
    }
}

// ---------------- merge -> top-3 -> exact fp64 rescreen -> gather + final idx ----------------
__global__ __launch_bounds__(256) void merge_rescreen_kernel(
    const float* __restrict__ X, const float* __restrict__ E,
    const u64* __restrict__ ptop, float* __restrict__ out, int* __restrict__ fidx)
{
    int wid = threadIdx.x >> 6, lane = threadIdx.x & 63;
    int q = blockIdx.x * 4 + wid;
    const u64* row = ptop + (size_t)q * (NTILES * 2);
    u64 k[4];
    #pragma unroll
    for (int t = 0; t < 4; ++t) k[t] = row[lane * 4 + t];
    int cand[3];
    #pragma unroll
    for (int pass = 0; pass < 3; ++pass) {
        u64 m = umin64(umin64(k[0], k[1]), umin64(k[2], k[3]));
        #pragma unroll
        for (int mask = 1; mask < 64; mask <<= 1)
            m = umin64(m, (u64)__shfl_xor((unsigned long long)m, mask));
        cand[pass] = (int)(u32)m;
        #pragma unroll
        for (int t = 0; t < 4; ++t) if (k[t] == m) k[t] = ~0ull;
    }
    float4 qv = ((const float4*)(X + (size_t)q * DIM))[lane];
    double bd = 1e300; int bi = NK;
    #pragma unroll 1
    for (int c = 0; c < 3; ++c) {
        int idx = cand[c];
        float4 ev = ((const float4*)(E + (size_t)idx * DIM))[lane];
        double d0 = (double)qv.x - (double)ev.x;
        double d1 = (double)qv.y - (double)ev.y;
        double d2 = (double)qv.z - (double)ev.z;
        double d3 = (double)qv.w - (double)ev.w;
        double s = d0 * d0 + d1 * d1 + d2 * d2 + d3 * d3;
        #pragma unroll
        for (int off = 32; off > 0; off >>= 1) s += __shfl_down(s, off);
        s = __shfl(s, 0);
        if (s < bd || (s == bd && idx < bi)) { bd = s; bi = idx; }
    }
    float4 ev = ((const float4*)(E + (size_t)bi * DIM))[lane];
    ((float4*)(out + OFF_ZEMB + (size_t)q * DIM))[lane] = ev;
    ((float4*)(out + OFF_ZENC + (size_t)q * DIM))[lane] = qv;
    if (lane == 0) fidx[q] = bi;
}

// ---------------- multi-limb bf16 MFMA GEMM: C[M][N] = A[M][KD]*B[N][KD]^T + bias ----------
// GATHER: A-fragments gathered per-lane from Ap (codebook pack) via selidx.
// G1: bias+LeakyReLU, repack hi-limb into Hp (gemm2 A-fragment layout, 32 units).
template <int KD, int A_KBT, int B_KBT, int NPROD, int AO1, int BO1, int AO2, int BO2,
          int NRB_B, int NT, bool G1, bool GATHER>
__global__ __launch_bounds__(256) void gemm_mfma_kernel(
    const unsigned short* __restrict__ Ap, const unsigned short* __restrict__ Bp,
    const int* __restrict__ selidx, const float* __restrict__ bias,
    float* __restrict__ C, unsigned short* __restrict__ Hp)
{
    constexpr int KQ    = KD / 64;
    constexpr int STEPS = NPROD * KQ;
    constexpr int FJ    = NRB_B / 2;
    constexpr int CB    = NRB_B * 2;
    constexpr int PW    = (16 + CB) / 4;
    constexpr int BUFSZ = (16 + CB) * 1024;
    constexpr int BN    = NRB_B * 16;
    constexpr int LDSSZ = (2 * BUFSZ > 65536 || G1) ? 65536 : 2 * BUFSZ;

    __shared__ __align__(16) char lds[LDSSZ];

    int bx = blockIdx.x;
    int mt = bx / NT, nt = bx % NT;
    int mb0 = mt * 8, nb0 = nt * NRB_B;
    int m0 = mt * 128, n0 = nt * BN;

    int tid = threadIdx.x;
    int wid = tid >> 6, lane = tid & 63;
    int wm = wid >> 1, wn = wid & 1;

    f32x4 acc[4][FJ] = {};

    auto STAGE = [&](int s, int b) {
        int p = s / KQ, kq = s % KQ;
        int akb = (p == 0 ? 0 : (p == 1 ? AO1 : AO2)) + kq * 2;
        int bkb = (p == 0 ? 0 : (p == 1 ? BO1 : BO2)) + kq * 2;
        char* LA = lds + b * BUFSZ;
        char* LB = LA + 16384;
        #pragma unroll
        for (int r = 0; r < PW; ++r) {
            int ci = wid * PW + r;
            if (ci < 16) {
                int rbl = ci >> 1, kbl = ci & 1;
                size_t ga;
                if constexpr (GATHER) {
                    int sel = selidx[(mb0 + rbl) * 16 + (lane & 15)];
                    ga = ((size_t)((sel >> 4) * A_KBT + akb + kbl) * 64
                          + (lane >> 4) * 16 + (sel & 15)) * 8;
                } else {
                    ga = ((size_t)((mb0 + rbl) * A_KBT + akb + kbl) * 64 + lane) * 8;
                }
                gload16(Ap + ga, LA + ci * 1024);
            } else {
                int cj = ci - 16, rbl = cj >> 1, kbl = cj & 1;
                gload16(Bp + ((size_t)((nb0 + rbl) * B_KBT + bkb + kbl) * 64 + lane) * 8,
                        LB + cj * 1024);
            }
        }
    };

    STAGE(0, 0);
    __syncthreads();
    for (int s = 0; s < STEPS; ++s) {
        int cur = s & 1;
        if (s + 1 < STEPS) STAGE(s + 1, cur ^ 1);
        const char* LA = lds + cur * BUFSZ;
        const char* LB = LA + 16384;
        #pragma unroll
        for (int kk = 0; kk < 2; ++kk) {
            short8 a[4], b[FJ];
            #pragma unroll
            for (int i = 0; i < 4; ++i)
                a[i] = *(const short8*)(LA + (((wm * 4 + i) * 2 + kk) << 10) + (lane << 4));
            #pragma unroll
            for (int j = 0; j < FJ; ++j)
                b[j] = *(const short8*)(LB + (((wn * FJ + j) * 2 + kk) << 10) + (lane << 4));
            #pragma unroll
            for (int i = 0; i < 4; ++i)
                #pragma unroll
                for (int j = 0; j < FJ; ++j)
                    acc[i][j] = __builtin_amdgcn_mfma_f32_16x16x32_bf16(
                        a[i], b[j], acc[i][j], 0, 0, 0);
        }
        __syncthreads();
    }

    int col_l = lane & 15, lg = lane >> 4;
    if (!G1) {
        #pragma unroll
        for (int j = 0; j < FJ; ++j) {
            int n = n0 + wn * (BN / 2) + j * 16 + col_l;
            float bb = bias[n];
            #pragma unroll
            for (int i = 0; i < 4; ++i)
                #pragma unroll
                for (int r = 0; r < 4; ++r) {
                    int m = m0 + wm * 64 + i * 16 + lg * 4 + r;
                    C[(size_t)m * (NT * BN) + n] = acc[i][j][r] + bb;
                }
        }
    } else {
        // bias + LeakyReLU + bf16(hi) -> swizzled LDS u16 tile -> repack to Hp frags
        unsigned short* lds16 = (unsigned short*)lds;
        #pragma unroll
        for (int j = 0; j < FJ; ++j) {
            int coln = wn * 64 + j * 16 + col_l;
            float bb = bias[n0 + coln];
            #pragma unroll
            for (int i = 0; i < 4; ++i)
                #pragma unroll
                for (int r = 0; r < 4; ++r) {
                    int row = wm * 64 + i * 16 + lg * 4 + r;
                    float v = acc[i][j][r] + bb;
                    v = fmaxf(v, 0.1f * v);
                    int sw = ((row >> 2) & 3) << 3;
                    lds16[row * 128 + (coln ^ sw)] = (unsigned short)f2bf(v);
                }
        }
        __syncthreads();
        #pragma unroll
        for (int rbw = 0; rbw < 2; ++rbw) {
            int rrb = wid * 2 + rbw;
            int rloc = lane & 15, ls = lane >> 4;
            int row = rrb * 16 + rloc;
            int sw  = ((row >> 2) & 3) << 3;
            #pragma unroll
            for (int kc = 0; kc < 4; ++kc) {
                int c0 = (kc * 32 + ls * 8) ^ sw;
                short8 h8 = *(const short8*)(lds16 + row * 128 + c0);
                int ku = nt * 4 + kc;              // unit within KD2=1024 hi (32 units)
                *(short8*)(Hp + ((size_t)((mb0 + rrb) * 32 + ku) * 64 + lane) * 8) = h8;
            }
        }
    }
}

extern "C" void kernel_launch(void* const* d_in, const int* in_sizes, int n_in,
                              void* d_out, int out_size, void* d_ws, size_t ws_size,
                              hipStream_t stream) {
    const float* X    = (const float*)d_in[0];
    const float* embd = (const float*)d_in[1];
    const float* W1   = (const float*)d_in[2];
    const float* b1   = (const float*)d_in[3];
    const float* W2   = (const float*)d_in[4];
    const float* b2   = (const float*)d_in[5];
    float* out = (float*)d_out;

    // ws (MiB): t2[0,.06) fidx[.06,.09) ptop[1,17) Xp[17,21) Ep[21,37) W1p[37,38) W2p[38,39)
    // Hp[1,17) aliases ptop (dead after merge). Ep survives gemm1 (A-gather source).
    char* w = (char*)d_ws;
    float* t2 = (float*)w;
    int*  fidx = (int*)(w + 65536);
    u64*  ptop = (u64*)(w + (1u << 20));
    unsigned short* Hp  = (unsigned short*)(w + (1u << 20));
    unsigned short* Xp  = (unsigned short*)(w + (17u << 20));
    unsigned short* Ep  = (unsigned short*)(w + (21u << 20));
    unsigned short* W1p = (unsigned short*)(w + (37u << 20));
    unsigned short* W2p = (unsigned short*)(w + (38u << 20));

    prep_kernel<<<dim3(4352), dim3(256), 0, stream>>>(
        X, embd, W1, W2, Xp, Ep, W1p, W2p, t2);
    dist_topk_kernel<<<dim3(8192), dim3(256), 0, stream>>>(Xp, Ep, t2, ptop);
    merge_rescreen_kernel<<<dim3(NBN / 4), dim3(256), 0, stream>>>(
        X, embd, ptop, out, fidx);
    // gemm1: h = Zemb*W1^T (+b1, LReLU): A gathered from Ep(full) via fidx, 3 limbs
    gemm_mfma_kernel<256, 16, 16, 3, 0, 8, 8, 0, 8, 8, true, true>
        <<<dim3(512), dim3(256), 0, stream>>>(Ep, W1p, fidx, b1, nullptr, Hp);
    // gemm2: Zrec = h*W2^T (+b2): A = Hp (hi-only), 2 limbs (hh + h*W2m)
    gemm_mfma_kernel<1024, 32, 64, 2, 0, 32, 0, 0, 4, 4, false, false>
        <<<dim3(256), dim3(256), 0, stream>>>(Hp, W2p, nullptr, b2, out + OFF_ZREC, nullptr);
}

// Round 5
// 217.259 us; speedup vs baseline: 6.5147x; 1.0794x over previous
//
#include <hip/hip_runtime.h>
#include <float.h>

// B=8, N=1024, D=256, K=16384, H=1024, IN=256
#define DIM      256
#define NK       16384
#define NH       1024
#define NIN      256
#define NBN      8192
#define NT2      64            // NK / 256 (dist n-tiles)

#define OFF_ZREC 0
#define OFF_ZENC (NBN * DIM)
#define OFF_ZEMB (2 * NBN * DIM)

using short8 = __attribute__((ext_vector_type(8))) short;
using f32x4  = __attribute__((ext_vector_type(4))) float;
typedef unsigned long long u64;
typedef unsigned int u32;

__device__ __forceinline__ u32 f2bf(float f) {
    u32 u = __float_as_uint(f);
    return (u + 0x7FFFu + ((u >> 16) & 1u)) >> 16;   // RNE
}
__device__ __forceinline__ float bf2f(u32 h) {
    return __uint_as_float(h << 16);
}
__device__ __forceinline__ u64 umin64(u64 a, u64 b) { return a < b ? a : b; }
__device__ __forceinline__ u32 umin32(u32 a, u32 b) { return a < b ? a : b; }
__device__ __forceinline__ u32 umax32(u32 a, u32 b) { return a > b ? a : b; }

__device__ __forceinline__ void gload16(const void* g, void* l) {
    __builtin_amdgcn_global_load_lds(
        (const __attribute__((address_space(1))) void*)g,
        (__attribute__((address_space(3))) void*)l, 16, 0, 0);
}

// pack one 16x32 chunk of fp32 [rows][KD] into bf16 MFMA fragment(s).
// Fragment (16x16x32 bf16): lane l <-> row = l&15, k = (l>>4)*8 + i.
// dst[rb][unit][lane][8]: hi unit = kc, mid unit = KD/32 + kc.
__device__ __forceinline__ void pack_frag(const float* __restrict__ src,
                                          unsigned short* __restrict__ dst,
                                          int KD, int KBT, int rb, int kc,
                                          int lane, bool with_mid) {
    int row = rb * 16 + (lane & 15);
    int k0  = kc * 32 + (lane >> 4) * 8;
    const float* p = src + (size_t)row * KD + k0;
    float x[8];
    *(float4*)(x)     = *(const float4*)(p);
    *(float4*)(x + 4) = *(const float4*)(p + 4);
    short8 hv, mv;
    #pragma unroll
    for (int i = 0; i < 8; ++i) {
        u32 hb = f2bf(x[i]);
        hv[i] = (short)hb;
        mv[i] = (short)f2bf(x[i] - bf2f(hb));
    }
    *(short8*)(dst + ((size_t)(rb * KBT + kc) * 64 + lane) * 8) = hv;
    if (with_mid)
        *(short8*)(dst + ((size_t)(rb * KBT + KD / 32 + kc) * 64 + lane) * 8) = mv;
}

// ---------------- fused prep: pack X(hi), E(full), W1(full), W2(full) + t2 ----------------
__global__ __launch_bounds__(256) void prep_kernel(
    const float* __restrict__ X, const float* __restrict__ E,
    const float* __restrict__ W1, const float* __restrict__ W2,
    unsigned short* __restrict__ Xp, unsigned short* __restrict__ Ep,
    unsigned short* __restrict__ W1p, unsigned short* __restrict__ W2p,
    float* __restrict__ t2)
{
    int b = blockIdx.x;
    int wid = threadIdx.x >> 6, lane = threadIdx.x & 63;
    if (b < 1024) {                         // X hi-only: 4096 gids (512 rb x 8 kc)
        int gid = b * 4 + wid;
        pack_frag(X, Xp, 256, 8, gid >> 3, gid & 7, lane, false);
    } else if (b < 3072) {                  // E full: 8192 gids (1024 rb x 8 kc)
        int gid = (b - 1024) * 4 + wid;
        pack_frag(E, Ep, 256, 16, gid >> 3, gid & 7, lane, true);
    } else if (b < 3200) {                  // W1 full: 512 gids (64 rb x 8 kc)
        int gid = (b - 3072) * 4 + wid;
        pack_frag(W1, W1p, 256, 16, gid >> 3, gid & 7, lane, true);
    } else if (b < 3328) {                  // W2 full: 512 gids (16 rb x 32 kc)
        int gid = (b - 3200) * 4 + wid;
        pack_frag(W2, W2p, 1024, 64, gid >> 5, gid & 31, lane, true);
    } else {                                // t2: 1024 blocks x 4 gids x 4 rows
        int gid = (b - 3328) * 4 + wid;
        #pragma unroll
        for (int r = 0; r < 4; ++r) {
            int row = gid * 4 + r;
            float4 v = ((const float4*)(E + (size_t)row * DIM))[lane];
            float s = v.x * v.x + v.y * v.y + v.z * v.z + v.w * v.w;
            #pragma unroll
            for (int off = 32; off > 0; off >>= 1) s += __shfl_down(s, off);
            if (lane == 0) t2[row] = s;
        }
    }
}

// ---------------- MFMA distance (bf16 hi-only), 256x256 tile, 8 waves ----------------
// Per-block top-2 per row via u32 keys: [24b truncated mapped score | 8b local col].
__global__ __launch_bounds__(512, 2) void dist_topk_kernel(
    const unsigned short* __restrict__ Xp, const unsigned short* __restrict__ Ep,
    const float* __restrict__ t2, u64* __restrict__ ptop)
{
    __shared__ __align__(16) char lds[65536];   // 2 x (16K A + 16K B); epi: 128x64x8B

    int bx = blockIdx.x;          // 32 mt x 64 nt
    int mt = bx >> 6, nt = bx & 63;
    int mb0 = mt * 16, nb0 = nt * 16;
    int m0 = mt * 256, n0 = nt * 256;

    int tid = threadIdx.x;
    int wid = tid >> 6, lane = tid & 63;
    int wm = wid >> 2, wn = wid & 3;            // 2 x 4 wave grid; wave = 128x64 out

    f32x4 acc[8][4] = {};

    auto STAGE = [&](int s, int b) {            // stage K32-slice s into buffer b
        char* L = lds + b * 32768;
        #pragma unroll
        for (int c = 0; c < 4; ++c) {
            int ci = wid * 4 + c;               // 0..31: A rb 0..15, B rb 0..15
            if (ci < 16)
                gload16(Xp + ((size_t)((mb0 + ci) * 8 + s) * 64 + lane) * 8,
                        L + ci * 1024);
            else
                gload16(Ep + ((size_t)((nb0 + (ci - 16)) * 16 + s) * 64 + lane) * 8,
                        L + 16384 + (ci - 16) * 1024);
        }
    };

    STAGE(0, 0);
    __syncthreads();
    #pragma unroll
    for (int s = 0; s < 8; ++s) {
        int cur = s & 1;
        if (s + 1 < 8) STAGE(s + 1, cur ^ 1);
        const char* LA = lds + cur * 32768;
        const char* LB = LA + 16384;
        short8 a[8], b[4];
        #pragma unroll
        for (int i = 0; i < 8; ++i)
            a[i] = *(const short8*)(LA + ((wm * 8 + i) << 10) + (lane << 4));
        #pragma unroll
        for (int j = 0; j < 4; ++j)
            b[j] = *(const short8*)(LB + ((wn * 4 + j) << 10) + (lane << 4));
        #pragma unroll
        for (int i = 0; i < 8; ++i)
            #pragma unroll
            for (int j = 0; j < 4; ++j)
                acc[i][j] = __builtin_amdgcn_mfma_f32_16x16x32_bf16(
                    a[i], b[j], acc[i][j], 0, 0, 0);
        __syncthreads();
    }

    // ---- epilogue: per-row top-2 over 256 cols, two 128-row passes ----
    // C frag: col = lane&15, row = (lane>>4)*4 + r
    int col_l = lane & 15, lg = lane >> 4;
    float t2v[4];
    #pragma unroll
    for (int j = 0; j < 4; ++j) t2v[j] = t2[n0 + wn * 64 + j * 16 + col_l];

    u32* sl = (u32*)lds;                        // [128 lds-rows][64 slots][2] u32
    #pragma unroll
    for (int p = 0; p < 2; ++p) {
        __syncthreads();
        #pragma unroll
        for (int i2 = 0; i2 < 4; ++i2) {
            int i = p * 4 + i2;
            #pragma unroll
            for (int r = 0; r < 4; ++r) {
                u32 b0 = 0xFFFFFFFFu, b1 = 0xFFFFFFFFu;
                #pragma unroll
                for (int j = 0; j < 4; ++j) {
                    float sc = fmaf(-2.0f, acc[i][j][r], t2v[j]);
                    u32 u = __float_as_uint(sc);
                    u ^= ((u32)((int)u >> 31)) | 0x80000000u;    // order-preserving
                    u = (u & 0xFFFFFF00u) | (u32)(wn * 64 + j * 16 + col_l);
                    u32 t = umin32(b0, u);
                    b1 = umin32(b1, umax32(b0, u));
                    b0 = t;
                }
                int rr = wm * 64 + i2 * 16 + lg * 4 + r;         // 0..127
                u32* q = sl + ((size_t)rr * 64 + wn * 16 + col_l) * 2;
                q[0] = b0; q[1] = b1;
            }
        }
        __syncthreads();
        if (tid < 128) {
            int rr = tid;
            u32 c0 = 0xFFFFFFFFu, c1 = 0xFFFFFFFFu;
            #pragma unroll 4
            for (int it = 0; it < 64; ++it) {
                int slt = (tid + it) & 63;                       // staggered scan
                u32 a0 = sl[((size_t)rr * 64 + slt) * 2];
                u32 a1 = sl[((size_t)rr * 64 + slt) * 2 + 1];
                u32 lo = umin32(c0, a0);
                c1 = umin32(umax32(c0, a0), umin32(c1, a1));
                c0 = lo;
            }
            int row_g = m0 + (rr >> 6) * 128 + p * 64 + (rr & 63);
            u64 e0 = ((u64)(c0 >> 8) << 14) | (u32)(n0 + (c0 & 0xFF));
            u64 e1 = ((u64)(c1 >> 8) << 14) | (u32)(n0 + (c1 & 0xFF));
            size_t o = ((size_t)row_g * NT2 + nt) * 2;
            ptop[o] = e0; ptop[o + 1] = e1;
        }
    }
}

// ---------------- merge -> top-3 -> exact fp64 rescreen -> gather + final idx ----------------
__global__ __launch_bounds__(256) void merge_rescreen_kernel(
    const float* __restrict__ X, const float* __restrict__ E,
    const u64* __restrict__ ptop, float* __restrict__ out, int* __restrict__ fidx)
{
    int wid = threadIdx.x >> 6, lane = threadIdx.x & 63;
    int q = blockIdx.x * 4 + wid;
    const u64* row = ptop + (size_t)q * (NT2 * 2);
    u64 k[2];
    #pragma unroll
    for (int t = 0; t < 2; ++t) k[t] = row[lane * 2 + t];
    int cand[3];
    #pragma unroll
    for (int pass = 0; pass < 3; ++pass) {
        u64 m = umin64(k[0], k[1]);
        #pragma unroll
        for (int mask = 1; mask < 64; mask <<= 1)
            m = umin64(m, (u64)__shfl_xor((unsigned long long)m, mask));
        cand[pass] = (int)(m & 0x3FFF);
        #pragma unroll
        for (int t = 0; t < 2; ++t) if (k[t] == m) k[t] = ~0ull;
    }
    float4 qv = ((const float4*)(X + (size_t)q * DIM))[lane];
    double bd = 1e300; int bi = NK;
    #pragma unroll 1
    for (int c = 0; c < 3; ++c) {
        int idx = cand[c];
        float4 ev = ((const float4*)(E + (size_t)idx * DIM))[lane];
        double d0 = (double)qv.x - (double)ev.x;
        double d1 = (double)qv.y - (double)ev.y;
        double d2 = (double)qv.z - (double)ev.z;
        double d3 = (double)qv.w - (double)ev.w;
        double s = d0 * d0 + d1 * d1 + d2 * d2 + d3 * d3;
        #pragma unroll
        for (int off = 32; off > 0; off >>= 1) s += __shfl_down(s, off);
        s = __shfl(s, 0);
        if (s < bd || (s == bd && idx < bi)) { bd = s; bi = idx; }
    }
    float4 ev = ((const float4*)(E + (size_t)bi * DIM))[lane];
    ((float4*)(out + OFF_ZEMB + (size_t)q * DIM))[lane] = ev;
    ((float4*)(out + OFF_ZENC + (size_t)q * DIM))[lane] = qv;
    if (lane == 0) fidx[q] = bi;
}

// ---------------- multi-limb bf16 MFMA GEMM: C[M][N] = A[M][KD]*B[N][KD]^T + bias ----------
// GATHER: A-fragments gathered per-lane from Ap (codebook pack) via selidx.
// G1: bias+LeakyReLU, repack hi-limb into Hp (gemm2 A-fragment layout, 32 units).
template <int KD, int A_KBT, int B_KBT, int NPROD, int AO1, int BO1, int AO2, int BO2,
          int NRB_B, int NT, bool G1, bool GATHER>
__global__ __launch_bounds__(256) void gemm_mfma_kernel(
    const unsigned short* __restrict__ Ap, const unsigned short* __restrict__ Bp,
    const int* __restrict__ selidx, const float* __restrict__ bias,
    float* __restrict__ C, unsigned short* __restrict__ Hp)
{
    constexpr int KQ    = KD / 64;
    constexpr int STEPS = NPROD * KQ;
    constexpr int FJ    = NRB_B / 2;
    constexpr int CB    = NRB_B * 2;
    constexpr int PW    = (16 + CB) / 4;
    constexpr int BUFSZ = (16 + CB) * 1024;
    constexpr int BN    = NRB_B * 16;
    constexpr int LDSSZ = (2 * BUFSZ > 65536 || G1) ? 65536 : 2 * BUFSZ;

    __shared__ __align__(16) char lds[LDSSZ];

    int bx = blockIdx.x;
    int mt = bx / NT, nt = bx % NT;
    int mb0 = mt * 8, nb0 = nt * NRB_B;
    int m0 = mt * 128, n0 = nt * BN;

    int tid = threadIdx.x;
    int wid = tid >> 6, lane = tid & 63;
    int wm = wid >> 1, wn = wid & 1;

    f32x4 acc[4][FJ] = {};

    auto STAGE = [&](int s, int b) {
        int p = s / KQ, kq = s % KQ;
        int akb = (p == 0 ? 0 : (p == 1 ? AO1 : AO2)) + kq * 2;
        int bkb = (p == 0 ? 0 : (p == 1 ? BO1 : BO2)) + kq * 2;
        char* LA = lds + b * BUFSZ;
        char* LB = LA + 16384;
        #pragma unroll
        for (int r = 0; r < PW; ++r) {
            int ci = wid * PW + r;
            if (ci < 16) {
                int rbl = ci >> 1, kbl = ci & 1;
                size_t ga;
                if constexpr (GATHER) {
                    int sel = selidx[(mb0 + rbl) * 16 + (lane & 15)];
                    ga = ((size_t)((sel >> 4) * A_KBT + akb + kbl) * 64
                          + (lane >> 4) * 16 + (sel & 15)) * 8;
                } else {
                    ga = ((size_t)((mb0 + rbl) * A_KBT + akb + kbl) * 64 + lane) * 8;
                }
                gload16(Ap + ga, LA + ci * 1024);
            } else {
                int cj = ci - 16, rbl = cj >> 1, kbl = cj & 1;
                gload16(Bp + ((size_t)((nb0 + rbl) * B_KBT + bkb + kbl) * 64 + lane) * 8,
                        LB + cj * 1024);
            }
        }
    };

    STAGE(0, 0);
    __syncthreads();
    for (int s = 0; s < STEPS; ++s) {
        int cur = s & 1;
        if (s + 1 < STEPS) STAGE(s + 1, cur ^ 1);
        const char* LA = lds + cur * BUFSZ;
        const char* LB = LA + 16384;
        #pragma unroll
        for (int kk = 0; kk < 2; ++kk) {
            short8 a[4], b[FJ];
            #pragma unroll
            for (int i = 0; i < 4; ++i)
                a[i] = *(const short8*)(LA + (((wm * 4 + i) * 2 + kk) << 10) + (lane << 4));
            #pragma unroll
            for (int j = 0; j < FJ; ++j)
                b[j] = *(const short8*)(LB + (((wn * FJ + j) * 2 + kk) << 10) + (lane << 4));
            #pragma unroll
            for (int i = 0; i < 4; ++i)
                #pragma unroll
                for (int j = 0; j < FJ; ++j)
                    acc[i][j] = __builtin_amdgcn_mfma_f32_16x16x32_bf16(
                        a[i], b[j], acc[i][j], 0, 0, 0);
        }
        __syncthreads();
    }

    int col_l = lane & 15, lg = lane >> 4;
    if (!G1) {
        #pragma unroll
        for (int j = 0; j < FJ; ++j) {
            int n = n0 + wn * (BN / 2) + j * 16 + col_l;
            float bb = bias[n];
            #pragma unroll
            for (int i = 0; i < 4; ++i)
                #pragma unroll
                for (int r = 0; r < 4; ++r) {
                    int m = m0 + wm * 64 + i * 16 + lg * 4 + r;
                    C[(size_t)m * (NT * BN) + n] = acc[i][j][r] + bb;
                }
        }
    } else {
        // bias + LeakyReLU + bf16(hi) -> swizzled LDS u16 tile -> repack to Hp frags
        unsigned short* lds16 = (unsigned short*)lds;
        #pragma unroll
        for (int j = 0; j < FJ; ++j) {
            int coln = wn * 64 + j * 16 + col_l;
            float bb = bias[n0 + coln];
            #pragma unroll
            for (int i = 0; i < 4; ++i)
                #pragma unroll
                for (int r = 0; r < 4; ++r) {
                    int row = wm * 64 + i * 16 + lg * 4 + r;
                    float v = acc[i][j][r] + bb;
                    v = fmaxf(v, 0.1f * v);
                    int sw = ((row >> 2) & 3) << 3;
                    lds16[row * 128 + (coln ^ sw)] = (unsigned short)f2bf(v);
                }
        }
        __syncthreads();
        #pragma unroll
        for (int rbw = 0; rbw < 2; ++rbw) {
            int rrb = wid * 2 + rbw;
            int rloc = lane & 15, ls = lane >> 4;
            int row = rrb * 16 + rloc;
            int sw  = ((row >> 2) & 3) << 3;
            #pragma unroll
            for (int kc = 0; kc < 4; ++kc) {
                int c0 = (kc * 32 + ls * 8) ^ sw;
                short8 h8 = *(const short8*)(lds16 + row * 128 + c0);
                int ku = nt * 4 + kc;              // unit within KD2=1024 hi (32 units)
                *(short8*)(Hp + ((size_t)((mb0 + rrb) * 32 + ku) * 64 + lane) * 8) = h8;
            }
        }
    }
}

extern "C" void kernel_launch(void* const* d_in, const int* in_sizes, int n_in,
                              void* d_out, int out_size, void* d_ws, size_t ws_size,
                              hipStream_t stream) {
    const float* X    = (const float*)d_in[0];
    const float* embd = (const float*)d_in[1];
    const float* W1   = (const float*)d_in[2];
    const float* b1   = (const float*)d_in[3];
    const float* W2   = (const float*)d_in[4];
    const float* b2   = (const float*)d_in[5];
    float* out = (float*)d_out;

    // ws (MiB): t2[0,.06) fidx[.06,.09) ptop[1,9) Xp[17,21) Ep[21,37) W1p[37,38) W2p[38,39)
    // Hp[1,17) aliases ptop (dead after merge). Ep survives gemm1 (A-gather source).
    char* w = (char*)d_ws;
    float* t2 = (float*)w;
    int*  fidx = (int*)(w + 65536);
    u64*  ptop = (u64*)(w + (1u << 20));
    unsigned short* Hp  = (unsigned short*)(w + (1u << 20));
    unsigned short* Xp  = (unsigned short*)(w + (17u << 20));
    unsigned short* Ep  = (unsigned short*)(w + (21u << 20));
    unsigned short* W1p = (unsigned short*)(w + (37u << 20));
    unsigned short* W2p = (unsigned short*)(w + (38u << 20));

    prep_kernel<<<dim3(4352), dim3(256), 0, stream>>>(
        X, embd, W1, W2, Xp, Ep, W1p, W2p, t2);
    dist_topk_kernel<<<dim3(2048), dim3(512), 0, stream>>>(Xp, Ep, t2, ptop);
    merge_rescreen_kernel<<<dim3(NBN / 4), dim3(256), 0, stream>>>(
        X, embd, ptop, out, fidx);
    // gemm1: h = Zemb*W1^T (+b1, LReLU): A gathered from Ep(full) via fidx, 3 limbs
    gemm_mfma_kernel<256, 16, 16, 3, 0, 8, 8, 0, 8, 8, true, true>
        <<<dim3(512), dim3(256), 0, stream>>>(Ep, W1p, fidx, b1, nullptr, Hp);
    // gemm2: Zrec = h*W2^T (+b2): A = Hp (hi-only), 2 limbs (hh + h*W2m)
    gemm_mfma_kernel<1024, 32, 64, 2, 0, 32, 0, 0, 4, 4, false, false>
        <<<dim3(256), dim3(256), 0, stream>>>(Hp, W2p, nullptr, b2, out + OFF_ZREC, nullptr);
}

// Round 6
// 204.375 us; speedup vs baseline: 6.9254x; 1.0630x over previous
//
#include <hip/hip_runtime.h>
#include <float.h>

// B=8, N=1024, D=256, K=16384, H=1024, IN=256
#define DIM      256
#define NK       16384
#define NH       1024
#define NIN      256
#define NBN      8192
#define NT2      64            // NK / 256 (dist n-tiles)

#define OFF_ZREC 0
#define OFF_ZENC (NBN * DIM)
#define OFF_ZEMB (2 * NBN * DIM)

using short8 = __attribute__((ext_vector_type(8))) short;
using f32x4  = __attribute__((ext_vector_type(4))) float;
typedef unsigned long long u64;
typedef unsigned int u32;

#define WAITVM(n)  asm volatile("s_waitcnt vmcnt(" #n ")" ::: "memory")
#define WAITLGKM0  asm volatile("s_waitcnt lgkmcnt(0)" ::: "memory")

__device__ __forceinline__ u32 f2bf(float f) {
    u32 u = __float_as_uint(f);
    return (u + 0x7FFFu + ((u >> 16) & 1u)) >> 16;   // RNE
}
__device__ __forceinline__ float bf2f(u32 h) {
    return __uint_as_float(h << 16);
}
__device__ __forceinline__ u64 umin64(u64 a, u64 b) { return a < b ? a : b; }
__device__ __forceinline__ u32 umin32(u32 a, u32 b) { return a < b ? a : b; }
__device__ __forceinline__ u32 umax32(u32 a, u32 b) { return a > b ? a : b; }

__device__ __forceinline__ void gload16(const void* g, void* l) {
    __builtin_amdgcn_global_load_lds(
        (const __attribute__((address_space(1))) void*)g,
        (__attribute__((address_space(3))) void*)l, 16, 0, 0);
}

// pack one 16x32 chunk of fp32 [rows][KD] into bf16 MFMA fragment(s).
// Fragment (16x16x32 bf16): lane l <-> row = l&15, k = (l>>4)*8 + i.
// dst[rb][unit][lane][8]: hi unit = kc, mid unit = KD/32 + kc.
__device__ __forceinline__ void pack_frag(const float* __restrict__ src,
                                          unsigned short* __restrict__ dst,
                                          int KD, int KBT, int rb, int kc,
                                          int lane, bool with_mid) {
    int row = rb * 16 + (lane & 15);
    int k0  = kc * 32 + (lane >> 4) * 8;
    const float* p = src + (size_t)row * KD + k0;
    float x[8];
    *(float4*)(x)     = *(const float4*)(p);
    *(float4*)(x + 4) = *(const float4*)(p + 4);
    short8 hv, mv;
    #pragma unroll
    for (int i = 0; i < 8; ++i) {
        u32 hb = f2bf(x[i]);
        hv[i] = (short)hb;
        mv[i] = (short)f2bf(x[i] - bf2f(hb));
    }
    *(short8*)(dst + ((size_t)(rb * KBT + kc) * 64 + lane) * 8) = hv;
    if (with_mid)
        *(short8*)(dst + ((size_t)(rb * KBT + KD / 32 + kc) * 64 + lane) * 8) = mv;
}

// ---------------- fused prep: pack X(hi), E(full), W1(full), W2(full) + t2 ----------------
__global__ __launch_bounds__(256) void prep_kernel(
    const float* __restrict__ X, const float* __restrict__ E,
    const float* __restrict__ W1, const float* __restrict__ W2,
    unsigned short* __restrict__ Xp, unsigned short* __restrict__ Ep,
    unsigned short* __restrict__ W1p, unsigned short* __restrict__ W2p,
    float* __restrict__ t2)
{
    int b = blockIdx.x;
    int wid = threadIdx.x >> 6, lane = threadIdx.x & 63;
    if (b < 1024) {                         // X hi-only: 4096 gids (512 rb x 8 kc)
        int gid = b * 4 + wid;
        pack_frag(X, Xp, 256, 8, gid >> 3, gid & 7, lane, false);
    } else if (b < 3072) {                  // E full: 8192 gids (1024 rb x 8 kc)
        int gid = (b - 1024) * 4 + wid;
        pack_frag(E, Ep, 256, 16, gid >> 3, gid & 7, lane, true);
    } else if (b < 3200) {                  // W1 full: 512 gids (64 rb x 8 kc)
        int gid = (b - 3072) * 4 + wid;
        pack_frag(W1, W1p, 256, 16, gid >> 3, gid & 7, lane, true);
    } else if (b < 3328) {                  // W2 full: 512 gids (16 rb x 32 kc)
        int gid = (b - 3200) * 4 + wid;
        pack_frag(W2, W2p, 1024, 64, gid >> 5, gid & 31, lane, true);
    } else {                                // t2: 1024 blocks x 4 gids x 4 rows
        int gid = (b - 3328) * 4 + wid;
        #pragma unroll
        for (int r = 0; r < 4; ++r) {
            int row = gid * 4 + r;
            float4 v = ((const float4*)(E + (size_t)row * DIM))[lane];
            float s = v.x * v.x + v.y * v.y + v.z * v.z + v.w * v.w;
            #pragma unroll
            for (int off = 32; off > 0; off >>= 1) s += __shfl_down(s, off);
            if (lane == 0) t2[row] = s;
        }
    }
}

// ---------------- MFMA distance (bf16 hi-only), 256x256 tile, 8 waves ----------------
// Counted-vmcnt 4-buffer pipeline (depth-3 prefetch, never drain mid-loop).
// Per-block top-2 per row via u32 keys: [24b positive-score bits | 8b local col].
__global__ __launch_bounds__(512, 2) void dist_topk_kernel(
    const unsigned short* __restrict__ Xp, const unsigned short* __restrict__ Ep,
    const float* __restrict__ t2, u64* __restrict__ ptop)
{
    __shared__ __align__(16) char lds[131072];   // 4 x (16K A + 16K B); epi: [128][65] uint2

    int bx = blockIdx.x;          // 32 mt x 64 nt
    int mt = bx >> 6, nt = bx & 63;
    int mb0 = mt * 16, nb0 = nt * 16;
    int m0 = mt * 256, n0 = nt * 256;

    int tid = threadIdx.x;
    int wid = tid >> 6, lane = tid & 63;
    int wm = wid >> 2, wn = wid & 3;            // 2 x 4 wave grid; wave = 128x64 out

    f32x4 acc[8][4] = {};

    auto STAGE = [&](int s) {                   // stage K32-slice s into buffer s&3
        char* L = lds + (s & 3) * 32768;
        #pragma unroll
        for (int c = 0; c < 4; ++c) {
            int ci = wid * 4 + c;               // 0..31: A rb 0..15, B rb 0..15
            if (ci < 16)
                gload16(Xp + ((size_t)((mb0 + ci) * 8 + s) * 64 + lane) * 8,
                        L + ci * 1024);
            else
                gload16(Ep + ((size_t)((nb0 + (ci - 16)) * 16 + s) * 64 + lane) * 8,
                        L + 16384 + (ci - 16) * 1024);
        }
    };

    STAGE(0); STAGE(1); STAGE(2);               // prologue: depth-3 prefetch
    #pragma unroll
    for (int s = 0; s < 8; ++s) {
        if (s + 3 < 8) STAGE(s + 3);
        // wait for stage s to land: pending stages = min(3, 7-s) x 4 loads
        if (s <= 4)      WAITVM(12);
        else if (s == 5) WAITVM(8);
        else if (s == 6) WAITVM(4);
        else             WAITVM(0);
        __builtin_amdgcn_s_barrier();
        __builtin_amdgcn_sched_barrier(0);
        const char* LA = lds + (s & 3) * 32768;
        const char* LB = LA + 16384;
        short8 a[8], b[4];
        #pragma unroll
        for (int i = 0; i < 8; ++i)
            a[i] = *(const short8*)(LA + ((wm * 8 + i) << 10) + (lane << 4));
        #pragma unroll
        for (int j = 0; j < 4; ++j)
            b[j] = *(const short8*)(LB + ((wn * 4 + j) << 10) + (lane << 4));
        #pragma unroll
        for (int i = 0; i < 8; ++i)
            #pragma unroll
            for (int j = 0; j < 4; ++j)
                acc[i][j] = __builtin_amdgcn_mfma_f32_16x16x32_bf16(
                    a[i], b[j], acc[i][j], 0, 0, 0);
        WAITLGKM0;
        __builtin_amdgcn_sched_barrier(0);
        __builtin_amdgcn_s_barrier();
    }

    // ---- epilogue: per-row top-2 over 256 cols, two 128-row passes ----
    // C frag: col = lane&15, row = (lane>>4)*4 + r.  Keys: positive floats
    // (score + 4096 > 0) are uint-ordered; key = (bits & 0xFFFFFF00) | local_col.
    int col_l = lane & 15, lg = lane >> 4;
    float t2b[4];
    #pragma unroll
    for (int j = 0; j < 4; ++j) t2b[j] = t2[n0 + wn * 64 + j * 16 + col_l] + 4096.0f;

    uint2* cand = (uint2*)lds;                  // [128 rows][65 slots(pad)]
    #pragma unroll
    for (int p = 0; p < 2; ++p) {
        if (p) __syncthreads();                 // protect cand reuse between passes
        #pragma unroll
        for (int i2 = 0; i2 < 4; ++i2) {
            int i = p * 4 + i2;
            #pragma unroll
            for (int r = 0; r < 4; ++r) {
                u32 b0 = 0xFFFFFFFFu, b1 = 0xFFFFFFFFu;
                #pragma unroll
                for (int j = 0; j < 4; ++j) {
                    float sc = fmaf(-2.0f, acc[i][j][r], t2b[j]);
                    u32 u = (__float_as_uint(sc) & 0xFFFFFF00u)
                          | (u32)(wn * 64 + j * 16 + col_l);
                    u32 t = umin32(b0, u);
                    b1 = umin32(b1, umax32(b0, u));
                    b0 = t;
                }
                int rr = wm * 64 + i2 * 16 + lg * 4 + r;         // 0..127
                cand[rr * 65 + wn * 16 + col_l] = make_uint2(b0, b1);
            }
        }
        __syncthreads();
        // phase B: 4 threads per row, strided slots (bank-spread), 2 shfl merges
        {
            int row = tid >> 2, part = tid & 3;
            u32 c0 = 0xFFFFFFFFu, c1 = 0xFFFFFFFFu;
            #pragma unroll 4
            for (int t = 0; t < 16; ++t) {
                uint2 a2 = cand[row * 65 + part + 4 * t];
                u32 lo = umin32(c0, a2.x);
                c1 = umin32(umax32(c0, a2.x), umin32(c1, a2.y));
                c0 = lo;
            }
            #pragma unroll
            for (int mask = 1; mask <= 2; mask <<= 1) {
                u32 a0 = __shfl_xor(c0, mask);
                u32 a1 = __shfl_xor(c1, mask);
                u32 lo = umin32(c0, a0);
                c1 = umin32(umax32(c0, a0), umin32(c1, a1));
                c0 = lo;
            }
            if (part == 0) {
                int row_g = m0 + (row >> 6) * 128 + p * 64 + (row & 63);
                u64 e0 = ((u64)(c0 >> 8) << 14) | (u32)(n0 + (c0 & 0xFF));
                u64 e1 = ((u64)(c1 >> 8) << 14) | (u32)(n0 + (c1 & 0xFF));
                size_t o = ((size_t)row_g * NT2 + nt) * 2;
                ptop[o] = e0; ptop[o + 1] = e1;
            }
        }
    }
}

// ---------------- merge -> top-3 -> exact fp64 rescreen -> gather + final idx ----------------
__global__ __launch_bounds__(256) void merge_rescreen_kernel(
    const float* __restrict__ X, const float* __restrict__ E,
    const u64* __restrict__ ptop, float* __restrict__ out, int* __restrict__ fidx)
{
    int wid = threadIdx.x >> 6, lane = threadIdx.x & 63;
    int q = blockIdx.x * 4 + wid;
    const u64* row = ptop + (size_t)q * (NT2 * 2);
    u64 k[2];
    #pragma unroll
    for (int t = 0; t < 2; ++t) k[t] = row[lane * 2 + t];
    int cand[3];
    #pragma unroll
    for (int pass = 0; pass < 3; ++pass) {
        u64 m = umin64(k[0], k[1]);
        #pragma unroll
        for (int mask = 1; mask < 64; mask <<= 1)
            m = umin64(m, (u64)__shfl_xor((unsigned long long)m, mask));
        cand[pass] = (int)(m & 0x3FFF);
        #pragma unroll
        for (int t = 0; t < 2; ++t) if (k[t] == m) k[t] = ~0ull;
    }
    float4 qv = ((const float4*)(X + (size_t)q * DIM))[lane];
    double bd = 1e300; int bi = NK;
    #pragma unroll 1
    for (int c = 0; c < 3; ++c) {
        int idx = cand[c];
        float4 ev = ((const float4*)(E + (size_t)idx * DIM))[lane];
        double d0 = (double)qv.x - (double)ev.x;
        double d1 = (double)qv.y - (double)ev.y;
        double d2 = (double)qv.z - (double)ev.z;
        double d3 = (double)qv.w - (double)ev.w;
        double s = d0 * d0 + d1 * d1 + d2 * d2 + d3 * d3;
        #pragma unroll
        for (int off = 32; off > 0; off >>= 1) s += __shfl_down(s, off);
        s = __shfl(s, 0);
        if (s < bd || (s == bd && idx < bi)) { bd = s; bi = idx; }
    }
    float4 ev = ((const float4*)(E + (size_t)bi * DIM))[lane];
    ((float4*)(out + OFF_ZEMB + (size_t)q * DIM))[lane] = ev;
    ((float4*)(out + OFF_ZENC + (size_t)q * DIM))[lane] = qv;
    if (lane == 0) fidx[q] = bi;
}

// ---------------- multi-limb bf16 MFMA GEMM: C[M][N] = A[M][KD]*B[N][KD]^T + bias ----------
// GATHER: A-fragments gathered per-lane from Ap (codebook pack) via selidx.
// G1: bias+LeakyReLU, repack hi-limb into Hp (gemm2 A-fragment layout, 32 units).
template <int KD, int A_KBT, int B_KBT, int NPROD, int AO1, int BO1, int AO2, int BO2,
          int NRB_B, int NT, bool G1, bool GATHER>
__global__ __launch_bounds__(256) void gemm_mfma_kernel(
    const unsigned short* __restrict__ Ap, const unsigned short* __restrict__ Bp,
    const int* __restrict__ selidx, const float* __restrict__ bias,
    float* __restrict__ C, unsigned short* __restrict__ Hp)
{
    constexpr int KQ    = KD / 64;
    constexpr int STEPS = NPROD * KQ;
    constexpr int FJ    = NRB_B / 2;
    constexpr int CB    = NRB_B * 2;
    constexpr int PW    = (16 + CB) / 4;
    constexpr int BUFSZ = (16 + CB) * 1024;
    constexpr int BN    = NRB_B * 16;
    constexpr int LDSSZ = (2 * BUFSZ > 65536 || G1) ? 65536 : 2 * BUFSZ;

    __shared__ __align__(16) char lds[LDSSZ];

    int bx = blockIdx.x;
    int mt = bx / NT, nt = bx % NT;
    int mb0 = mt * 8, nb0 = nt * NRB_B;
    int m0 = mt * 128, n0 = nt * BN;

    int tid = threadIdx.x;
    int wid = tid >> 6, lane = tid & 63;
    int wm = wid >> 1, wn = wid & 1;

    f32x4 acc[4][FJ] = {};

    auto STAGE = [&](int s, int b) {
        int p = s / KQ, kq = s % KQ;
        int akb = (p == 0 ? 0 : (p == 1 ? AO1 : AO2)) + kq * 2;
        int bkb = (p == 0 ? 0 : (p == 1 ? BO1 : BO2)) + kq * 2;
        char* LA = lds + b * BUFSZ;
        char* LB = LA + 16384;
        #pragma unroll
        for (int r = 0; r < PW; ++r) {
            int ci = wid * PW + r;
            if (ci < 16) {
                int rbl = ci >> 1, kbl = ci & 1;
                size_t ga;
                if constexpr (GATHER) {
                    int sel = selidx[(mb0 + rbl) * 16 + (lane & 15)];
                    ga = ((size_t)((sel >> 4) * A_KBT + akb + kbl) * 64
                          + (lane >> 4) * 16 + (sel & 15)) * 8;
                } else {
                    ga = ((size_t)((mb0 + rbl) * A_KBT + akb + kbl) * 64 + lane) * 8;
                }
                gload16(Ap + ga, LA + ci * 1024);
            } else {
                int cj = ci - 16, rbl = cj >> 1, kbl = cj & 1;
                gload16(Bp + ((size_t)((nb0 + rbl) * B_KBT + bkb + kbl) * 64 + lane) * 8,
                        LB + cj * 1024);
            }
        }
    };

    STAGE(0, 0);
    __syncthreads();
    for (int s = 0; s < STEPS; ++s) {
        int cur = s & 1;
        if (s + 1 < STEPS) STAGE(s + 1, cur ^ 1);
        const char* LA = lds + cur * BUFSZ;
        const char* LB = LA + 16384;
        #pragma unroll
        for (int kk = 0; kk < 2; ++kk) {
            short8 a[4], b[FJ];
            #pragma unroll
            for (int i = 0; i < 4; ++i)
                a[i] = *(const short8*)(LA + (((wm * 4 + i) * 2 + kk) << 10) + (lane << 4));
            #pragma unroll
            for (int j = 0; j < FJ; ++j)
                b[j] = *(const short8*)(LB + (((wn * FJ + j) * 2 + kk) << 10) + (lane << 4));
            #pragma unroll
            for (int i = 0; i < 4; ++i)
                #pragma unroll
                for (int j = 0; j < FJ; ++j)
                    acc[i][j] = __builtin_amdgcn_mfma_f32_16x16x32_bf16(
                        a[i], b[j], acc[i][j], 0, 0, 0);
        }
        __syncthreads();
    }

    int col_l = lane & 15, lg = lane >> 4;
    if (!G1) {
        #pragma unroll
        for (int j = 0; j < FJ; ++j) {
            int n = n0 + wn * (BN / 2) + j * 16 + col_l;
            float bb = bias[n];
            #pragma unroll
            for (int i = 0; i < 4; ++i)
                #pragma unroll
                for (int r = 0; r < 4; ++r) {
                    int m = m0 + wm * 64 + i * 16 + lg * 4 + r;
                    C[(size_t)m * (NT * BN) + n] = acc[i][j][r] + bb;
                }
        }
    } else {
        // bias + LeakyReLU + bf16(hi) -> swizzled LDS u16 tile -> repack to Hp frags
        unsigned short* lds16 = (unsigned short*)lds;
        #pragma unroll
        for (int j = 0; j < FJ; ++j) {
            int coln = wn * 64 + j * 16 + col_l;
            float bb = bias[n0 + coln];
            #pragma unroll
            for (int i = 0; i < 4; ++i)
                #pragma unroll
                for (int r = 0; r < 4; ++r) {
                    int row = wm * 64 + i * 16 + lg * 4 + r;
                    float v = acc[i][j][r] + bb;
                    v = fmaxf(v, 0.1f * v);
                    int sw = ((row >> 2) & 3) << 3;
                    lds16[row * 128 + (coln ^ sw)] = (unsigned short)f2bf(v);
                }
        }
        __syncthreads();
        #pragma unroll
        for (int rbw = 0; rbw < 2; ++rbw) {
            int rrb = wid * 2 + rbw;
            int rloc = lane & 15, ls = lane >> 4;
            int row = rrb * 16 + rloc;
            int sw  = ((row >> 2) & 3) << 3;
            #pragma unroll
            for (int kc = 0; kc < 4; ++kc) {
                int c0 = (kc * 32 + ls * 8) ^ sw;
                short8 h8 = *(const short8*)(lds16 + row * 128 + c0);
                int ku = nt * 4 + kc;              // unit within KD2=1024 hi (32 units)
                *(short8*)(Hp + ((size_t)((mb0 + rrb) * 32 + ku) * 64 + lane) * 8) = h8;
            }
        }
    }
}

extern "C" void kernel_launch(void* const* d_in, const int* in_sizes, int n_in,
                              void* d_out, int out_size, void* d_ws, size_t ws_size,
                              hipStream_t stream) {
    const float* X    = (const float*)d_in[0];
    const float* embd = (const float*)d_in[1];
    const float* W1   = (const float*)d_in[2];
    const float* b1   = (const float*)d_in[3];
    const float* W2   = (const float*)d_in[4];
    const float* b2   = (const float*)d_in[5];
    float* out = (float*)d_out;

    // ws (MiB): t2[0,.06) fidx[.06,.09) ptop[1,9.4) Xp[17,21) Ep[21,37) W1p[37,38) W2p[38,39)
    // Hp[1,17) aliases ptop (dead after merge). Ep survives gemm1 (A-gather source).
    char* w = (char*)d_ws;
    float* t2 = (float*)w;
    int*  fidx = (int*)(w + 65536);
    u64*  ptop = (u64*)(w + (1u << 20));
    unsigned short* Hp  = (unsigned short*)(w + (1u << 20));
    unsigned short* Xp  = (unsigned short*)(w + (17u << 20));
    unsigned short* Ep  = (unsigned short*)(w + (21u << 20));
    unsigned short* W1p = (unsigned short*)(w + (37u << 20));
    unsigned short* W2p = (unsigned short*)(w + (38u << 20));

    prep_kernel<<<dim3(4352), dim3(256), 0, stream>>>(
        X, embd, W1, W2, Xp, Ep, W1p, W2p, t2);
    dist_topk_kernel<<<dim3(2048), dim3(512), 0, stream>>>(Xp, Ep, t2, ptop);
    merge_rescreen_kernel<<<dim3(NBN / 4), dim3(256), 0, stream>>>(
        X, embd, ptop, out, fidx);
    // gemm1: h = Zemb*W1^T (+b1, LReLU): A gathered from Ep(full) via fidx, 3 limbs
    gemm_mfma_kernel<256, 16, 16, 3, 0, 8, 8, 0, 8, 8, true, true>
        <<<dim3(512), dim3(256), 0, stream>>>(Ep, W1p, fidx, b1, nullptr, Hp);
    // gemm2: Zrec = h*W2^T (+b2): A = Hp (hi-only), 2 limbs (hh + h*W2m)
    gemm_mfma_kernel<1024, 32, 64, 2, 0, 32, 0, 0, 4, 4, false, false>
        <<<dim3(256), dim3(256), 0, stream>>>(Hp, W2p, nullptr, b2, out + OFF_ZREC, nullptr);
}

// Round 7
// 190.183 us; speedup vs baseline: 7.4421x; 1.0746x over previous
//
#include <hip/hip_runtime.h>
#include <float.h>

// B=8, N=1024, D=256, K=16384, H=1024, IN=256
#define DIM      256
#define NK       16384
#define NH       1024
#define NIN      256
#define NBN      8192
#define NT2      64            // NK / 256 (dist n-tiles)

#define OFF_ZREC 0
#define OFF_ZENC (NBN * DIM)
#define OFF_ZEMB (2 * NBN * DIM)

using short8 = __attribute__((ext_vector_type(8))) short;
using f32x4  = __attribute__((ext_vector_type(4))) float;
typedef unsigned long long u64;
typedef unsigned int u32;

#define WAITVM(n)  asm volatile("s_waitcnt vmcnt(" #n ")" ::: "memory")
#define WAITLGKM0  asm volatile("s_waitcnt lgkmcnt(0)" ::: "memory")

template <int N>
__device__ __forceinline__ void waitvm_c() {
    // s_waitcnt imm: vmcnt[3:0]@[3:0], vmcnt[5:4]@[15:14], expcnt@[6:4], lgkmcnt@[11:8]
    __builtin_amdgcn_s_waitcnt(0x0F70 | (N & 0xF) | (((N >> 4) & 3) << 14));
}

__device__ __forceinline__ u32 f2bf(float f) {
    u32 u = __float_as_uint(f);
    return (u + 0x7FFFu + ((u >> 16) & 1u)) >> 16;   // RNE
}
__device__ __forceinline__ float bf2f(u32 h) {
    return __uint_as_float(h << 16);
}
__device__ __forceinline__ u64 umin64(u64 a, u64 b) { return a < b ? a : b; }
__device__ __forceinline__ u32 umin32(u32 a, u32 b) { return a < b ? a : b; }
__device__ __forceinline__ u32 umax32(u32 a, u32 b) { return a > b ? a : b; }

__device__ __forceinline__ void gload16(const void* g, void* l) {
    __builtin_amdgcn_global_load_lds(
        (const __attribute__((address_space(1))) void*)g,
        (__attribute__((address_space(3))) void*)l, 16, 0, 0);
}

// pack one 16x32 chunk of fp32 [rows][KD] into bf16 MFMA fragment(s).
// Fragment (16x16x32 bf16): lane l <-> row = l&15, k = (l>>4)*8 + i.
// dst[rb][unit][lane][8]: hi unit = kc, mid unit = KD/32 + kc.
__device__ __forceinline__ void pack_frag(const float* __restrict__ src,
                                          unsigned short* __restrict__ dst,
                                          int KD, int KBT, int rb, int kc,
                                          int lane, bool with_mid) {
    int row = rb * 16 + (lane & 15);
    int k0  = kc * 32 + (lane >> 4) * 8;
    const float* p = src + (size_t)row * KD + k0;
    float x[8];
    *(float4*)(x)     = *(const float4*)(p);
    *(float4*)(x + 4) = *(const float4*)(p + 4);
    short8 hv, mv;
    #pragma unroll
    for (int i = 0; i < 8; ++i) {
        u32 hb = f2bf(x[i]);
        hv[i] = (short)hb;
        mv[i] = (short)f2bf(x[i] - bf2f(hb));
    }
    *(short8*)(dst + ((size_t)(rb * KBT + kc) * 64 + lane) * 8) = hv;
    if (with_mid)
        *(short8*)(dst + ((size_t)(rb * KBT + KD / 32 + kc) * 64 + lane) * 8) = mv;
}

// ---------------- fused prep: pack X(hi), E(full), W1(full), W2(full) + t2 ----------------
__global__ __launch_bounds__(256) void prep_kernel(
    const float* __restrict__ X, const float* __restrict__ E,
    const float* __restrict__ W1, const float* __restrict__ W2,
    unsigned short* __restrict__ Xp, unsigned short* __restrict__ Ep,
    unsigned short* __restrict__ W1p, unsigned short* __restrict__ W2p,
    float* __restrict__ t2)
{
    int b = blockIdx.x;
    int wid = threadIdx.x >> 6, lane = threadIdx.x & 63;
    if (b < 1024) {                         // X hi-only: 4096 gids (512 rb x 8 kc)
        int gid = b * 4 + wid;
        pack_frag(X, Xp, 256, 8, gid >> 3, gid & 7, lane, false);
    } else if (b < 3072) {                  // E full: 8192 gids (1024 rb x 8 kc)
        int gid = (b - 1024) * 4 + wid;
        pack_frag(E, Ep, 256, 16, gid >> 3, gid & 7, lane, true);
    } else if (b < 3200) {                  // W1 full: 512 gids (64 rb x 8 kc)
        int gid = (b - 3072) * 4 + wid;
        pack_frag(W1, W1p, 256, 16, gid >> 3, gid & 7, lane, true);
    } else if (b < 3328) {                  // W2 full: 512 gids (16 rb x 32 kc)
        int gid = (b - 3200) * 4 + wid;
        pack_frag(W2, W2p, 1024, 64, gid >> 5, gid & 31, lane, true);
    } else {                                // t2: 1024 blocks x 4 gids x 4 rows
        int gid = (b - 3328) * 4 + wid;
        #pragma unroll
        for (int r = 0; r < 4; ++r) {
            int row = gid * 4 + r;
            float4 v = ((const float4*)(E + (size_t)row * DIM))[lane];
            float s = v.x * v.x + v.y * v.y + v.z * v.z + v.w * v.w;
            #pragma unroll
            for (int off = 32; off > 0; off >>= 1) s += __shfl_down(s, off);
            if (lane == 0) t2[row] = s;
        }
    }
}

// ---------------- MFMA distance (bf16 hi-only), 256x256 tile, 8 waves ----------------
// 2x32KB dbuf, counted vmcnt(4) (never drain mid-loop), 2 blocks/CU.
// Per-block top-2 per row via u32 keys: [24b positive-score bits | 8b local col].
__global__ __launch_bounds__(512, 2) void dist_topk_kernel(
    const unsigned short* __restrict__ Xp, const unsigned short* __restrict__ Ep,
    const float* __restrict__ t2, u64* __restrict__ ptop)
{
    __shared__ __align__(16) char lds[67584];   // main: 2x32KB; epi: [128][66] uint2

    int bx = blockIdx.x;          // 32 mt x 64 nt
    int mt = bx >> 6, nt = bx & 63;
    int mb0 = mt * 16, nb0 = nt * 16;
    int m0 = mt * 256, n0 = nt * 256;

    int tid = threadIdx.x;
    int wid = tid >> 6, lane = tid & 63;
    int wm = wid >> 2, wn = wid & 3;            // 2 x 4 wave grid; wave = 128x64 out

    f32x4 acc[8][4] = {};

    auto STAGE = [&](int s) {                   // stage K32-slice s into buffer s&1
        char* L = lds + (s & 1) * 32768;
        #pragma unroll
        for (int c = 0; c < 4; ++c) {
            int ci = wid * 4 + c;               // 0..31: A rb 0..15, B rb 0..15
            if (ci < 16)
                gload16(Xp + ((size_t)((mb0 + ci) * 8 + s) * 64 + lane) * 8,
                        L + ci * 1024);
            else
                gload16(Ep + ((size_t)((nb0 + (ci - 16)) * 16 + s) * 64 + lane) * 8,
                        L + 16384 + (ci - 16) * 1024);
        }
    };

    STAGE(0);
    #pragma unroll
    for (int s = 0; s < 8; ++s) {
        if (s < 7) { STAGE(s + 1); WAITVM(4); }   // wait stage-s loads only
        else       { WAITVM(0); }
        __builtin_amdgcn_s_barrier();
        __builtin_amdgcn_sched_barrier(0);
        const char* LA = lds + (s & 1) * 32768;
        const char* LB = LA + 16384;
        short8 a[8], b[4];
        #pragma unroll
        for (int i = 0; i < 8; ++i)
            a[i] = *(const short8*)(LA + ((wm * 8 + i) << 10) + (lane << 4));
        #pragma unroll
        for (int j = 0; j < 4; ++j)
            b[j] = *(const short8*)(LB + ((wn * 4 + j) << 10) + (lane << 4));
        #pragma unroll
        for (int i = 0; i < 8; ++i)
            #pragma unroll
            for (int j = 0; j < 4; ++j)
                acc[i][j] = __builtin_amdgcn_mfma_f32_16x16x32_bf16(
                    a[i], b[j], acc[i][j], 0, 0, 0);
        WAITLGKM0;
        __builtin_amdgcn_sched_barrier(0);
        __builtin_amdgcn_s_barrier();
    }

    // ---- epilogue: per-row top-2 over 256 cols, two 128-row passes ----
    // C frag: col = lane&15, row = (lane>>4)*4 + r.  Keys: positive floats
    // (score + 4096 > 0) are uint-ordered; key = (bits & 0xFFFFFF00) | local_col.
    int col_l = lane & 15, lg = lane >> 4;
    float t2b[4];
    #pragma unroll
    for (int j = 0; j < 4; ++j) t2b[j] = t2[n0 + wn * 64 + j * 16 + col_l] + 4096.0f;

    uint2* cand = (uint2*)lds;                  // [128 rows][66 slots] (stride 66: 2-way max)
    #pragma unroll
    for (int p = 0; p < 2; ++p) {
        if (p) __syncthreads();                 // protect cand reuse between passes
        #pragma unroll
        for (int i2 = 0; i2 < 4; ++i2) {
            int i = p * 4 + i2;
            #pragma unroll
            for (int r = 0; r < 4; ++r) {
                u32 b0 = 0xFFFFFFFFu, b1 = 0xFFFFFFFFu;
                #pragma unroll
                for (int j = 0; j < 4; ++j) {
                    float sc = fmaf(-2.0f, acc[i][j][r], t2b[j]);
                    u32 u = (__float_as_uint(sc) & 0xFFFFFF00u)
                          | (u32)(wn * 64 + j * 16 + col_l);
                    u32 t = umin32(b0, u);
                    b1 = umin32(b1, umax32(b0, u));
                    b0 = t;
                }
                int rr = wm * 64 + i2 * 16 + lg * 4 + r;         // 0..127
                cand[rr * 66 + wn * 16 + col_l] = make_uint2(b0, b1);
            }
        }
        __syncthreads();
        // phase B: 4 threads per row, strided slots, 2 shfl merges
        {
            int row = tid >> 2, part = tid & 3;
            u32 c0 = 0xFFFFFFFFu, c1 = 0xFFFFFFFFu;
            #pragma unroll 4
            for (int t = 0; t < 16; ++t) {
                uint2 a2 = cand[row * 66 + part + 4 * t];
                u32 lo = umin32(c0, a2.x);
                c1 = umin32(umax32(c0, a2.x), umin32(c1, a2.y));
                c0 = lo;
            }
            #pragma unroll
            for (int mask = 1; mask <= 2; mask <<= 1) {
                u32 a0 = __shfl_xor(c0, mask);
                u32 a1 = __shfl_xor(c1, mask);
                u32 lo = umin32(c0, a0);
                c1 = umin32(umax32(c0, a0), umin32(c1, a1));
                c0 = lo;
            }
            if (part == 0) {
                int row_g = m0 + (row >> 6) * 128 + p * 64 + (row & 63);
                u64 e0 = ((u64)(c0 >> 8) << 14) | (u32)(n0 + (c0 & 0xFF));
                u64 e1 = ((u64)(c1 >> 8) << 14) | (u32)(n0 + (c1 & 0xFF));
                size_t o = ((size_t)row_g * NT2 + nt) * 2;
                ptop[o] = e0; ptop[o + 1] = e1;
            }
        }
    }
}

// ---------------- merge -> top-3 -> exact fp64 rescreen -> gather + final idx ----------------
__global__ __launch_bounds__(256) void merge_rescreen_kernel(
    const float* __restrict__ X, const float* __restrict__ E,
    const u64* __restrict__ ptop, float* __restrict__ out, int* __restrict__ fidx)
{
    int wid = threadIdx.x >> 6, lane = threadIdx.x & 63;
    int q = blockIdx.x * 4 + wid;
    const u64* row = ptop + (size_t)q * (NT2 * 2);
    u64 k[2];
    #pragma unroll
    for (int t = 0; t < 2; ++t) k[t] = row[lane * 2 + t];
    int cand[3];
    #pragma unroll
    for (int pass = 0; pass < 3; ++pass) {
        u64 m = umin64(k[0], k[1]);
        #pragma unroll
        for (int mask = 1; mask < 64; mask <<= 1)
            m = umin64(m, (u64)__shfl_xor((unsigned long long)m, mask));
        cand[pass] = (int)(m & 0x3FFF);
        #pragma unroll
        for (int t = 0; t < 2; ++t) if (k[t] == m) k[t] = ~0ull;
    }
    float4 qv = ((const float4*)(X + (size_t)q * DIM))[lane];
    double bd = 1e300; int bi = NK;
    #pragma unroll 1
    for (int c = 0; c < 3; ++c) {
        int idx = cand[c];
        float4 ev = ((const float4*)(E + (size_t)idx * DIM))[lane];
        double d0 = (double)qv.x - (double)ev.x;
        double d1 = (double)qv.y - (double)ev.y;
        double d2 = (double)qv.z - (double)ev.z;
        double d3 = (double)qv.w - (double)ev.w;
        double s = d0 * d0 + d1 * d1 + d2 * d2 + d3 * d3;
        #pragma unroll
        for (int off = 32; off > 0; off >>= 1) s += __shfl_down(s, off);
        s = __shfl(s, 0);
        if (s < bd || (s == bd && idx < bi)) { bd = s; bi = idx; }
    }
    float4 ev = ((const float4*)(E + (size_t)bi * DIM))[lane];
    ((float4*)(out + OFF_ZEMB + (size_t)q * DIM))[lane] = ev;
    ((float4*)(out + OFF_ZENC + (size_t)q * DIM))[lane] = qv;
    if (lane == 0) fidx[q] = bi;
}

// ---------------- multi-limb bf16 MFMA GEMM: C[M][N] = A[M][KD]*B[N][KD]^T + bias ----------
// GATHER: A-fragments gathered per-lane from Ap (codebook pack) via selidx.
// G1: bias+LeakyReLU, repack hi-limb into Hp (gemm2 A-fragment layout, 32 units).
// Counted-vmcnt dual-barrier pipeline (same structure as dist).
template <int KD, int A_KBT, int B_KBT, int NPROD, int AO1, int BO1, int AO2, int BO2,
          int NRB_B, int NT, bool G1, bool GATHER>
__global__ __launch_bounds__(256) void gemm_mfma_kernel(
    const unsigned short* __restrict__ Ap, const unsigned short* __restrict__ Bp,
    const int* __restrict__ selidx, const float* __restrict__ bias,
    float* __restrict__ C, unsigned short* __restrict__ Hp)
{
    constexpr int KQ    = KD / 64;
    constexpr int STEPS = NPROD * KQ;
    constexpr int FJ    = NRB_B / 2;
    constexpr int CB    = NRB_B * 2;
    constexpr int PW    = (16 + CB) / 4;
    constexpr int BUFSZ = (16 + CB) * 1024;
    constexpr int BN    = NRB_B * 16;
    constexpr int LDSSZ = (2 * BUFSZ > 65536 || G1) ? 65536 : 2 * BUFSZ;

    __shared__ __align__(16) char lds[LDSSZ];

    int bx = blockIdx.x;
    int mt = bx / NT, nt = bx % NT;
    int mb0 = mt * 8, nb0 = nt * NRB_B;
    int m0 = mt * 128, n0 = nt * BN;

    int tid = threadIdx.x;
    int wid = tid >> 6, lane = tid & 63;
    int wm = wid >> 1, wn = wid & 1;

    f32x4 acc[4][FJ] = {};

    auto STAGE = [&](int s, int b) {
        int p = s / KQ, kq = s % KQ;
        int akb = (p == 0 ? 0 : (p == 1 ? AO1 : AO2)) + kq * 2;
        int bkb = (p == 0 ? 0 : (p == 1 ? BO1 : BO2)) + kq * 2;
        char* LA = lds + b * BUFSZ;
        char* LB = LA + 16384;
        #pragma unroll
        for (int r = 0; r < PW; ++r) {
            int ci = wid * PW + r;
            if (ci < 16) {
                int rbl = ci >> 1, kbl = ci & 1;
                size_t ga;
                if constexpr (GATHER) {
                    int sel = selidx[(mb0 + rbl) * 16 + (lane & 15)];
                    ga = ((size_t)((sel >> 4) * A_KBT + akb + kbl) * 64
                          + (lane >> 4) * 16 + (sel & 15)) * 8;
                } else {
                    ga = ((size_t)((mb0 + rbl) * A_KBT + akb + kbl) * 64 + lane) * 8;
                }
                gload16(Ap + ga, LA + ci * 1024);
            } else {
                int cj = ci - 16, rbl = cj >> 1, kbl = cj & 1;
                gload16(Bp + ((size_t)((nb0 + rbl) * B_KBT + bkb + kbl) * 64 + lane) * 8,
                        LB + cj * 1024);
            }
        }
    };

    STAGE(0, 0);
    for (int s = 0; s < STEPS; ++s) {
        int cur = s & 1;
        if (s + 1 < STEPS) { STAGE(s + 1, cur ^ 1); waitvm_c<PW>(); }
        else               { waitvm_c<0>(); }
        __builtin_amdgcn_s_barrier();
        __builtin_amdgcn_sched_barrier(0);
        const char* LA = lds + cur * BUFSZ;
        const char* LB = LA + 16384;
        #pragma unroll
        for (int kk = 0; kk < 2; ++kk) {
            short8 a[4], b[FJ];
            #pragma unroll
            for (int i = 0; i < 4; ++i)
                a[i] = *(const short8*)(LA + (((wm * 4 + i) * 2 + kk) << 10) + (lane << 4));
            #pragma unroll
            for (int j = 0; j < FJ; ++j)
                b[j] = *(const short8*)(LB + (((wn * FJ + j) * 2 + kk) << 10) + (lane << 4));
            #pragma unroll
            for (int i = 0; i < 4; ++i)
                #pragma unroll
                for (int j = 0; j < FJ; ++j)
                    acc[i][j] = __builtin_amdgcn_mfma_f32_16x16x32_bf16(
                        a[i], b[j], acc[i][j], 0, 0, 0);
        }
        WAITLGKM0;
        __builtin_amdgcn_sched_barrier(0);
        __builtin_amdgcn_s_barrier();
    }

    int col_l = lane & 15, lg = lane >> 4;
    if (!G1) {
        #pragma unroll
        for (int j = 0; j < FJ; ++j) {
            int n = n0 + wn * (BN / 2) + j * 16 + col_l;
            float bb = bias[n];
            #pragma unroll
            for (int i = 0; i < 4; ++i)
                #pragma unroll
                for (int r = 0; r < 4; ++r) {
                    int m = m0 + wm * 64 + i * 16 + lg * 4 + r;
                    C[(size_t)m * (NT * BN) + n] = acc[i][j][r] + bb;
                }
        }
    } else {
        // bias + LeakyReLU + bf16(hi) -> swizzled LDS u16 tile -> repack to Hp frags
        unsigned short* lds16 = (unsigned short*)lds;
        #pragma unroll
        for (int j = 0; j < FJ; ++j) {
            int coln = wn * 64 + j * 16 + col_l;
            float bb = bias[n0 + coln];
            #pragma unroll
            for (int i = 0; i < 4; ++i)
                #pragma unroll
                for (int r = 0; r < 4; ++r) {
                    int row = wm * 64 + i * 16 + lg * 4 + r;
                    float v = acc[i][j][r] + bb;
                    v = fmaxf(v, 0.1f * v);
                    int sw = ((row >> 2) & 3) << 3;
                    lds16[row * 128 + (coln ^ sw)] = (unsigned short)f2bf(v);
                }
        }
        __syncthreads();
        #pragma unroll
        for (int rbw = 0; rbw < 2; ++rbw) {
            int rrb = wid * 2 + rbw;
            int rloc = lane & 15, ls = lane >> 4;
            int row = rrb * 16 + rloc;
            int sw  = ((row >> 2) & 3) << 3;
            #pragma unroll
            for (int kc = 0; kc < 4; ++kc) {
                int c0 = (kc * 32 + ls * 8) ^ sw;
                short8 h8 = *(const short8*)(lds16 + row * 128 + c0);
                int ku = nt * 4 + kc;              // unit within KD2=1024 hi (32 units)
                *(short8*)(Hp + ((size_t)((mb0 + rrb) * 32 + ku) * 64 + lane) * 8) = h8;
            }
        }
    }
}

extern "C" void kernel_launch(void* const* d_in, const int* in_sizes, int n_in,
                              void* d_out, int out_size, void* d_ws, size_t ws_size,
                              hipStream_t stream) {
    const float* X    = (const float*)d_in[0];
    const float* embd = (const float*)d_in[1];
    const float* W1   = (const float*)d_in[2];
    const float* b1   = (const float*)d_in[3];
    const float* W2   = (const float*)d_in[4];
    const float* b2   = (const float*)d_in[5];
    float* out = (float*)d_out;

    // ws (MiB): t2[0,.06) fidx[.06,.09) ptop[1,9.4) Xp[17,21) Ep[21,37) W1p[37,38) W2p[38,39)
    // Hp[1,17) aliases ptop (dead after merge). Ep survives gemm1 (A-gather source).
    char* w = (char*)d_ws;
    float* t2 = (float*)w;
    int*  fidx = (int*)(w + 65536);
    u64*  ptop = (u64*)(w + (1u << 20));
    unsigned short* Hp  = (unsigned short*)(w + (1u << 20));
    unsigned short* Xp  = (unsigned short*)(w + (17u << 20));
    unsigned short* Ep  = (unsigned short*)(w + (21u << 20));
    unsigned short* W1p = (unsigned short*)(w + (37u << 20));
    unsigned short* W2p = (unsigned short*)(w + (38u << 20));

    prep_kernel<<<dim3(4352), dim3(256), 0, stream>>>(
        X, embd, W1, W2, Xp, Ep, W1p, W2p, t2);
    dist_topk_kernel<<<dim3(2048), dim3(512), 0, stream>>>(Xp, Ep, t2, ptop);
    merge_rescreen_kernel<<<dim3(NBN / 4), dim3(256), 0, stream>>>(
        X, embd, ptop, out, fidx);
    // gemm1: h = Zemb*W1^T (+b1, LReLU): A gathered from Ep(full) via fidx, 3 limbs
    gemm_mfma_kernel<256, 16, 16, 3, 0, 8, 8, 0, 8, 8, true, true>
        <<<dim3(512), dim3(256), 0, stream>>>(Ep, W1p, fidx, b1, nullptr, Hp);
    // gemm2: Zrec = h*W2^T (+b2): A = Hp (hi-only), 2 limbs (hh + h*W2m)
    gemm_mfma_kernel<1024, 32, 64, 2, 0, 32, 0, 0, 4, 4, false, false>
        <<<dim3(256), dim3(256), 0, stream>>>(Hp, W2p, nullptr, b2, out + OFF_ZREC, nullptr);
}

// Round 8
// 189.682 us; speedup vs baseline: 7.4618x; 1.0026x over previous
//
#include <hip/hip_runtime.h>
#include <float.h>

// B=8, N=1024, D=256, K=16384, H=1024, IN=256
#define DIM      256
#define NK       16384
#define NH       1024
#define NIN      256
#define NBN      8192
#define NT2      64            // NK / 256 (dist n-tiles)

#define OFF_ZREC 0
#define OFF_ZENC (NBN * DIM)
#define OFF_ZEMB (2 * NBN * DIM)

using short8 = __attribute__((ext_vector_type(8))) short;
using f32x4  = __attribute__((ext_vector_type(4))) float;
typedef unsigned long long u64;
typedef unsigned int u32;

#define WAITVM(n)  asm volatile("s_waitcnt vmcnt(" #n ")" ::: "memory")
#define WAITLGKM0  asm volatile("s_waitcnt lgkmcnt(0)" ::: "memory")

template <int N>
__device__ __forceinline__ void waitvm_c() {
    // s_waitcnt imm: vmcnt[3:0]@[3:0], vmcnt[5:4]@[15:14], expcnt@[6:4], lgkmcnt@[11:8]
    __builtin_amdgcn_s_waitcnt(0x0F70 | (N & 0xF) | (((N >> 4) & 3) << 14));
}

__device__ __forceinline__ u32 f2bf(float f) {
    u32 u = __float_as_uint(f);
    return (u + 0x7FFFu + ((u >> 16) & 1u)) >> 16;   // RNE
}
__device__ __forceinline__ float bf2f(u32 h) {
    return __uint_as_float(h << 16);
}
__device__ __forceinline__ u64 umin64(u64 a, u64 b) { return a < b ? a : b; }
__device__ __forceinline__ u32 umin32(u32 a, u32 b) { return a < b ? a : b; }
__device__ __forceinline__ u32 umax32(u32 a, u32 b) { return a > b ? a : b; }

__device__ __forceinline__ void gload16(const void* g, void* l) {
    __builtin_amdgcn_global_load_lds(
        (const __attribute__((address_space(1))) void*)g,
        (__attribute__((address_space(3))) void*)l, 16, 0, 0);
}

// pack one 16x32 chunk of fp32 [rows][KD] into bf16 MFMA fragment(s).
// Fragment (16x16x32 bf16): lane l <-> row = l&15, k = (l>>4)*8 + i.
// dst[rb][unit][lane][8]: hi unit = kc, mid unit = KD/32 + kc.
__device__ __forceinline__ void pack_frag(const float* __restrict__ src,
                                          unsigned short* __restrict__ dst,
                                          int KD, int KBT, int rb, int kc,
                                          int lane, bool with_mid) {
    int row = rb * 16 + (lane & 15);
    int k0  = kc * 32 + (lane >> 4) * 8;
    const float* p = src + (size_t)row * KD + k0;
    float x[8];
    *(float4*)(x)     = *(const float4*)(p);
    *(float4*)(x + 4) = *(const float4*)(p + 4);
    short8 hv, mv;
    #pragma unroll
    for (int i = 0; i < 8; ++i) {
        u32 hb = f2bf(x[i]);
        hv[i] = (short)hb;
        mv[i] = (short)f2bf(x[i] - bf2f(hb));
    }
    *(short8*)(dst + ((size_t)(rb * KBT + kc) * 64 + lane) * 8) = hv;
    if (with_mid)
        *(short8*)(dst + ((size_t)(rb * KBT + KD / 32 + kc) * 64 + lane) * 8) = mv;
}

// ---------------- fused prep: pack X(hi), E(hi), W1(full), W2(hi) + t2 ----------------
__global__ __launch_bounds__(256) void prep_kernel(
    const float* __restrict__ X, const float* __restrict__ E,
    const float* __restrict__ W1, const float* __restrict__ W2,
    unsigned short* __restrict__ Xp, unsigned short* __restrict__ Ep,
    unsigned short* __restrict__ W1p, unsigned short* __restrict__ W2p,
    float* __restrict__ t2)
{
    int b = blockIdx.x;
    int wid = threadIdx.x >> 6, lane = threadIdx.x & 63;
    if (b < 1024) {                         // X hi: 4096 gids (512 rb x 8 kc)
        int gid = b * 4 + wid;
        pack_frag(X, Xp, 256, 8, gid >> 3, gid & 7, lane, false);
    } else if (b < 3072) {                  // E hi: 8192 gids (1024 rb x 8 kc)
        int gid = (b - 1024) * 4 + wid;
        pack_frag(E, Ep, 256, 8, gid >> 3, gid & 7, lane, false);
    } else if (b < 3200) {                  // W1 full: 512 gids (64 rb x 8 kc)
        int gid = (b - 3072) * 4 + wid;
        pack_frag(W1, W1p, 256, 16, gid >> 3, gid & 7, lane, true);
    } else if (b < 3328) {                  // W2 hi: 512 gids (16 rb x 32 kc)
        int gid = (b - 3200) * 4 + wid;
        pack_frag(W2, W2p, 1024, 32, gid >> 5, gid & 31, lane, false);
    } else {                                // t2: 1024 blocks x 4 gids x 4 rows
        int gid = (b - 3328) * 4 + wid;
        #pragma unroll
        for (int r = 0; r < 4; ++r) {
            int row = gid * 4 + r;
            float4 v = ((const float4*)(E + (size_t)row * DIM))[lane];
            float s = v.x * v.x + v.y * v.y + v.z * v.z + v.w * v.w;
            #pragma unroll
            for (int off = 32; off > 0; off >>= 1) s += __shfl_down(s, off);
            if (lane == 0) t2[row] = s;
        }
    }
}

// ---------------- MFMA distance (bf16 hi-only), 256x256 tile, 8 waves ----------------
// BK=64: 4 steps, 2x64KB dbuf, counted vmcnt(8) (never drain mid-loop).
// Per-block top-2 per row via u32 keys: [24b positive-score bits | 8b local col].
__global__ __launch_bounds__(512, 2) void dist_topk_kernel(
    const unsigned short* __restrict__ Xp, const unsigned short* __restrict__ Ep,
    const float* __restrict__ t2, u64* __restrict__ ptop)
{
    __shared__ __align__(16) char lds[131072];  // 2x64KB dbuf; epi: [128][66] uint2 (alias)

    int bx = blockIdx.x;          // 32 mt x 64 nt
    int mt = bx >> 6, nt = bx & 63;
    int mb0 = mt * 16, nb0 = nt * 16;
    int m0 = mt * 256, n0 = nt * 256;

    int tid = threadIdx.x;
    int wid = tid >> 6, lane = tid & 63;
    int wm = wid >> 2, wn = wid & 3;            // 2 x 4 wave grid; wave = 128x64 out

    f32x4 acc[8][4] = {};

    auto STAGE = [&](int s) {                   // stage K64-slice s into buffer s&1
        char* L = lds + (s & 1) * 65536;
        #pragma unroll
        for (int c = 0; c < 8; ++c) {
            int ci = wid * 8 + c;               // 0..63: A chunks 0..31, B chunks 0..31
            if (ci < 32) {
                int rbl = ci >> 1, kbl = ci & 1;
                gload16(Xp + ((size_t)((mb0 + rbl) * 8 + s * 2 + kbl) * 64 + lane) * 8,
                        L + ci * 1024);
            } else {
                int cj = ci - 32, rbl = cj >> 1, kbl = cj & 1;
                gload16(Ep + ((size_t)((nb0 + rbl) * 8 + s * 2 + kbl) * 64 + lane) * 8,
                        L + 32768 + cj * 1024);
            }
        }
    };

    STAGE(0);
    #pragma unroll
    for (int s = 0; s < 4; ++s) {
        if (s < 3) { STAGE(s + 1); WAITVM(8); }   // wait stage-s loads only
        else       { WAITVM(0); }
        __builtin_amdgcn_s_barrier();
        __builtin_amdgcn_sched_barrier(0);
        const char* LA = lds + (s & 1) * 65536;
        const char* LB = LA + 32768;
        #pragma unroll
        for (int kk = 0; kk < 2; ++kk) {
            short8 a[8], b[4];
            #pragma unroll
            for (int i = 0; i < 8; ++i)
                a[i] = *(const short8*)(LA + (((wm * 8 + i) * 2 + kk) << 10) + (lane << 4));
            #pragma unroll
            for (int j = 0; j < 4; ++j)
                b[j] = *(const short8*)(LB + (((wn * 4 + j) * 2 + kk) << 10) + (lane << 4));
            #pragma unroll
            for (int i = 0; i < 8; ++i)
                #pragma unroll
                for (int j = 0; j < 4; ++j)
                    acc[i][j] = __builtin_amdgcn_mfma_f32_16x16x32_bf16(
                        a[i], b[j], acc[i][j], 0, 0, 0);
        }
        WAITLGKM0;
        __builtin_amdgcn_sched_barrier(0);
        __builtin_amdgcn_s_barrier();
    }

    // ---- epilogue: per-row top-2 over 256 cols, two 128-row passes ----
    // C frag: col = lane&15, row = (lane>>4)*4 + r.  Keys: positive floats
    // (score + 4096 > 0) are uint-ordered; key = (bits & 0xFFFFFF00) | local_col.
    int col_l = lane & 15, lg = lane >> 4;
    float t2b[4];
    #pragma unroll
    for (int j = 0; j < 4; ++j) t2b[j] = t2[n0 + wn * 64 + j * 16 + col_l] + 4096.0f;

    uint2* cand = (uint2*)lds;                  // [128 rows][66 slots] (stride 66: 2-way max)
    #pragma unroll
    for (int p = 0; p < 2; ++p) {
        if (p) __syncthreads();                 // protect cand reuse between passes
        #pragma unroll
        for (int i2 = 0; i2 < 4; ++i2) {
            int i = p * 4 + i2;
            #pragma unroll
            for (int r = 0; r < 4; ++r) {
                u32 b0 = 0xFFFFFFFFu, b1 = 0xFFFFFFFFu;
                #pragma unroll
                for (int j = 0; j < 4; ++j) {
                    float sc = fmaf(-2.0f, acc[i][j][r], t2b[j]);
                    u32 u = (__float_as_uint(sc) & 0xFFFFFF00u)
                          | (u32)(wn * 64 + j * 16 + col_l);
                    u32 t = umin32(b0, u);
                    b1 = umin32(b1, umax32(b0, u));
                    b0 = t;
                }
                int rr = wm * 64 + i2 * 16 + lg * 4 + r;         // 0..127
                cand[rr * 66 + wn * 16 + col_l] = make_uint2(b0, b1);
            }
        }
        __syncthreads();
        // phase B: 4 threads per row, strided slots, 2 shfl merges
        {
            int row = tid >> 2, part = tid & 3;
            u32 c0 = 0xFFFFFFFFu, c1 = 0xFFFFFFFFu;
            #pragma unroll 4
            for (int t = 0; t < 16; ++t) {
                uint2 a2 = cand[row * 66 + part + 4 * t];
                u32 lo = umin32(c0, a2.x);
                c1 = umin32(umax32(c0, a2.x), umin32(c1, a2.y));
                c0 = lo;
            }
            #pragma unroll
            for (int mask = 1; mask <= 2; mask <<= 1) {
                u32 a0 = __shfl_xor(c0, mask);
                u32 a1 = __shfl_xor(c1, mask);
                u32 lo = umin32(c0, a0);
                c1 = umin32(umax32(c0, a0), umin32(c1, a1));
                c0 = lo;
            }
            if (part == 0) {
                int row_g = m0 + (row >> 6) * 128 + p * 64 + (row & 63);
                u64 e0 = ((u64)(c0 >> 8) << 14) | (u32)(n0 + (c0 & 0xFF));
                u64 e1 = ((u64)(c1 >> 8) << 14) | (u32)(n0 + (c1 & 0xFF));
                size_t o = ((size_t)row_g * NT2 + nt) * 2;
                ptop[o] = e0; ptop[o + 1] = e1;
            }
        }
    }
}

// ---------------- merge -> top-3 -> exact fp64 rescreen -> gather + final idx ----------------
__global__ __launch_bounds__(256) void merge_rescreen_kernel(
    const float* __restrict__ X, const float* __restrict__ E,
    const u64* __restrict__ ptop, float* __restrict__ out, int* __restrict__ fidx)
{
    int wid = threadIdx.x >> 6, lane = threadIdx.x & 63;
    int q = blockIdx.x * 4 + wid;
    const u64* row = ptop + (size_t)q * (NT2 * 2);
    u64 k[2];
    #pragma unroll
    for (int t = 0; t < 2; ++t) k[t] = row[lane * 2 + t];
    int cand[3];
    #pragma unroll
    for (int pass = 0; pass < 3; ++pass) {
        u64 m = umin64(k[0], k[1]);
        #pragma unroll
        for (int mask = 1; mask < 64; mask <<= 1)
            m = umin64(m, (u64)__shfl_xor((unsigned long long)m, mask));
        cand[pass] = (int)(m & 0x3FFF);
        #pragma unroll
        for (int t = 0; t < 2; ++t) if (k[t] == m) k[t] = ~0ull;
    }
    float4 qv = ((const float4*)(X + (size_t)q * DIM))[lane];
    double bd = 1e300; int bi = NK;
    #pragma unroll 1
    for (int c = 0; c < 3; ++c) {
        int idx = cand[c];
        float4 ev = ((const float4*)(E + (size_t)idx * DIM))[lane];
        double d0 = (double)qv.x - (double)ev.x;
        double d1 = (double)qv.y - (double)ev.y;
        double d2 = (double)qv.z - (double)ev.z;
        double d3 = (double)qv.w - (double)ev.w;
        double s = d0 * d0 + d1 * d1 + d2 * d2 + d3 * d3;
        #pragma unroll
        for (int off = 32; off > 0; off >>= 1) s += __shfl_down(s, off);
        s = __shfl(s, 0);
        if (s < bd || (s == bd && idx < bi)) { bd = s; bi = idx; }
    }
    float4 ev = ((const float4*)(E + (size_t)bi * DIM))[lane];
    ((float4*)(out + OFF_ZEMB + (size_t)q * DIM))[lane] = ev;
    ((float4*)(out + OFF_ZENC + (size_t)q * DIM))[lane] = qv;
    if (lane == 0) fidx[q] = bi;
}

// ---------------- multi-limb bf16 MFMA GEMM: C[M][N] = A[M][KD]*B[N][KD]^T + bias ----------
// GATHER: A-fragments gathered per-lane from Ap (codebook pack) via selidx.
// G1: bias+LeakyReLU, repack hi-limb into Hp (gemm2 A-fragment layout, 32 units).
// Counted-vmcnt dual-barrier pipeline.
template <int KD, int A_KBT, int B_KBT, int NPROD, int AO1, int BO1,
          int NRB_B, int NT, bool G1, bool GATHER>
__global__ __launch_bounds__(256) void gemm_mfma_kernel(
    const unsigned short* __restrict__ Ap, const unsigned short* __restrict__ Bp,
    const int* __restrict__ selidx, const float* __restrict__ bias,
    float* __restrict__ C, unsigned short* __restrict__ Hp)
{
    constexpr int KQ    = KD / 64;
    constexpr int STEPS = NPROD * KQ;
    constexpr int FJ    = NRB_B / 2;
    constexpr int CB    = NRB_B * 2;
    constexpr int PW    = (16 + CB) / 4;
    constexpr int BUFSZ = (16 + CB) * 1024;
    constexpr int BN    = NRB_B * 16;
    constexpr int LDSSZ = (2 * BUFSZ > 65536 || G1) ? 65536 : 2 * BUFSZ;

    __shared__ __align__(16) char lds[LDSSZ];

    int bx = blockIdx.x;
    int mt = bx / NT, nt = bx % NT;
    int mb0 = mt * 8, nb0 = nt * NRB_B;
    int m0 = mt * 128, n0 = nt * BN;

    int tid = threadIdx.x;
    int wid = tid >> 6, lane = tid & 63;
    int wm = wid >> 1, wn = wid & 1;

    f32x4 acc[4][FJ] = {};

    auto STAGE = [&](int s, int b) {
        int p = s / KQ, kq = s % KQ;
        int akb = (p == 0 ? 0 : AO1) + kq * 2;
        int bkb = (p == 0 ? 0 : BO1) + kq * 2;
        char* LA = lds + b * BUFSZ;
        char* LB = LA + 16384;
        #pragma unroll
        for (int r = 0; r < PW; ++r) {
            int ci = wid * PW + r;
            if (ci < 16) {
                int rbl = ci >> 1, kbl = ci & 1;
                size_t ga;
                if constexpr (GATHER) {
                    int sel = selidx[(mb0 + rbl) * 16 + (lane & 15)];
                    ga = ((size_t)((sel >> 4) * A_KBT + akb + kbl) * 64
                          + (lane >> 4) * 16 + (sel & 15)) * 8;
                } else {
                    ga = ((size_t)((mb0 + rbl) * A_KBT + akb + kbl) * 64 + lane) * 8;
                }
                gload16(Ap + ga, LA + ci * 1024);
            } else {
                int cj = ci - 16, rbl = cj >> 1, kbl = cj & 1;
                gload16(Bp + ((size_t)((nb0 + rbl) * B_KBT + bkb + kbl) * 64 + lane) * 8,
                        LB + cj * 1024);
            }
        }
    };

    STAGE(0, 0);
    for (int s = 0; s < STEPS; ++s) {
        int cur = s & 1;
        if (s + 1 < STEPS) { STAGE(s + 1, cur ^ 1); waitvm_c<PW>(); }
        else               { waitvm_c<0>(); }
        __builtin_amdgcn_s_barrier();
        __builtin_amdgcn_sched_barrier(0);
        const char* LA = lds + cur * BUFSZ;
        const char* LB = LA + 16384;
        #pragma unroll
        for (int kk = 0; kk < 2; ++kk) {
            short8 a[4], b[FJ];
            #pragma unroll
            for (int i = 0; i < 4; ++i)
                a[i] = *(const short8*)(LA + (((wm * 4 + i) * 2 + kk) << 10) + (lane << 4));
            #pragma unroll
            for (int j = 0; j < FJ; ++j)
                b[j] = *(const short8*)(LB + (((wn * FJ + j) * 2 + kk) << 10) + (lane << 4));
            #pragma unroll
            for (int i = 0; i < 4; ++i)
                #pragma unroll
                for (int j = 0; j < FJ; ++j)
                    acc[i][j] = __builtin_amdgcn_mfma_f32_16x16x32_bf16(
                        a[i], b[j], acc[i][j], 0, 0, 0);
        }
        WAITLGKM0;
        __builtin_amdgcn_sched_barrier(0);
        __builtin_amdgcn_s_barrier();
    }

    int col_l = lane & 15, lg = lane >> 4;
    if (!G1) {
        #pragma unroll
        for (int j = 0; j < FJ; ++j) {
            int n = n0 + wn * (BN / 2) + j * 16 + col_l;
            float bb = bias[n];
            #pragma unroll
            for (int i = 0; i < 4; ++i)
                #pragma unroll
                for (int r = 0; r < 4; ++r) {
                    int m = m0 + wm * 64 + i * 16 + lg * 4 + r;
                    C[(size_t)m * (NT * BN) + n] = acc[i][j][r] + bb;
                }
        }
    } else {
        // bias + LeakyReLU + bf16(hi) -> swizzled LDS u16 tile -> repack to Hp frags
        unsigned short* lds16 = (unsigned short*)lds;
        #pragma unroll
        for (int j = 0; j < FJ; ++j) {
            int coln = wn * 64 + j * 16 + col_l;
            float bb = bias[n0 + coln];
            #pragma unroll
            for (int i = 0; i < 4; ++i)
                #pragma unroll
                for (int r = 0; r < 4; ++r) {
                    int row = wm * 64 + i * 16 + lg * 4 + r;
                    float v = acc[i][j][r] + bb;
                    v = fmaxf(v, 0.1f * v);
                    int sw = ((row >> 2) & 3) << 3;
                    lds16[row * 128 + (coln ^ sw)] = (unsigned short)f2bf(v);
                }
        }
        __syncthreads();
        #pragma unroll
        for (int rbw = 0; rbw < 2; ++rbw) {
            int rrb = wid * 2 + rbw;
            int rloc = lane & 15, ls = lane >> 4;
            int row = rrb * 16 + rloc;
            int sw  = ((row >> 2) & 3) << 3;
            #pragma unroll
            for (int kc = 0; kc < 4; ++kc) {
                int c0 = (kc * 32 + ls * 8) ^ sw;
                short8 h8 = *(const short8*)(lds16 + row * 128 + c0);
                int ku = nt * 4 + kc;              // unit within KD2=1024 hi (32 units)
                *(short8*)(Hp + ((size_t)((mb0 + rrb) * 32 + ku) * 64 + lane) * 8) = h8;
            }
        }
    }
}

extern "C" void kernel_launch(void* const* d_in, const int* in_sizes, int n_in,
                              void* d_out, int out_size, void* d_ws, size_t ws_size,
                              hipStream_t stream) {
    const float* X    = (const float*)d_in[0];
    const float* embd = (const float*)d_in[1];
    const float* W1   = (const float*)d_in[2];
    const float* b1   = (const float*)d_in[3];
    const float* W2   = (const float*)d_in[4];
    const float* b2   = (const float*)d_in[5];
    float* out = (float*)d_out;

    // ws (MiB): t2[0,.06) fidx[.06,.09) ptop[1,9) Xp[17,21) Ep[21,29) W1p[37,38) W2p[38,38.5)
    // Hp[1,17) aliases ptop (dead after merge). Ep survives gemm1 (A-gather source).
    char* w = (char*)d_ws;
    float* t2 = (float*)w;
    int*  fidx = (int*)(w + 65536);
    u64*  ptop = (u64*)(w + (1u << 20));
    unsigned short* Hp  = (unsigned short*)(w + (1u << 20));
    unsigned short* Xp  = (unsigned short*)(w + (17u << 20));
    unsigned short* Ep  = (unsigned short*)(w + (21u << 20));
    unsigned short* W1p = (unsigned short*)(w + (37u << 20));
    unsigned short* W2p = (unsigned short*)(w + (38u << 20));

    prep_kernel<<<dim3(4352), dim3(256), 0, stream>>>(
        X, embd, W1, W2, Xp, Ep, W1p, W2p, t2);
    dist_topk_kernel<<<dim3(2048), dim3(512), 0, stream>>>(Xp, Ep, t2, ptop);
    merge_rescreen_kernel<<<dim3(NBN / 4), dim3(256), 0, stream>>>(
        X, embd, ptop, out, fidx);
    // gemm1: h = Zemb*W1^T (+b1, LReLU): A gathered from Ep(hi) via fidx, 2 limbs (xh*wh + xh*wm)
    gemm_mfma_kernel<256, 8, 16, 2, 0, 8, 8, 8, true, true>
        <<<dim3(512), dim3(256), 0, stream>>>(Ep, W1p, fidx, b1, nullptr, Hp);
    // gemm2: Zrec = h*W2^T (+b2): A = Hp (hi), B = W2p (hi), 1 limb
    gemm_mfma_kernel<1024, 32, 32, 1, 0, 0, 4, 4, false, false>
        <<<dim3(256), dim3(256), 0, stream>>>(Hp, W2p, nullptr, b2, out + OFF_ZREC, nullptr);
}

// Round 9
// 161.196 us; speedup vs baseline: 8.7805x; 1.1767x over previous
//
#include <hip/hip_runtime.h>
#include <float.h>

// B=8, N=1024, D=256, K=16384, H=1024, IN=256
#define DIM      256
#define NK       16384
#define NH       1024
#define NIN      256
#define NBN      8192
#define NT2      64            // NK / 256 (dist n-tiles)

#define OFF_ZREC 0
#define OFF_ZENC (NBN * DIM)
#define OFF_ZEMB (2 * NBN * DIM)

using short8 = __attribute__((ext_vector_type(8))) short;
using f32x4  = __attribute__((ext_vector_type(4))) float;
typedef unsigned long long u64;
typedef unsigned int u32;

#define WAITVM(n)  asm volatile("s_waitcnt vmcnt(" #n ")" ::: "memory")
#define WAITLGKM0  asm volatile("s_waitcnt lgkmcnt(0)" ::: "memory")

template <int N>
__device__ __forceinline__ void waitvm_c() {
    // s_waitcnt imm: vmcnt[3:0]@[3:0], vmcnt[5:4]@[15:14], expcnt@[6:4], lgkmcnt@[11:8]
    __builtin_amdgcn_s_waitcnt(0x0F70 | (N & 0xF) | (((N >> 4) & 3) << 14));
}

__device__ __forceinline__ u32 f2bf(float f) {
    u32 u = __float_as_uint(f);
    return (u + 0x7FFFu + ((u >> 16) & 1u)) >> 16;   // RNE
}
__device__ __forceinline__ float bf2f(u32 h) {
    return __uint_as_float(h << 16);
}
__device__ __forceinline__ u64 umin64(u64 a, u64 b) { return a < b ? a : b; }
__device__ __forceinline__ u32 umin32(u32 a, u32 b) { return a < b ? a : b; }
__device__ __forceinline__ u32 umax32(u32 a, u32 b) { return a > b ? a : b; }

__device__ __forceinline__ void gload16(const void* g, void* l) {
    __builtin_amdgcn_global_load_lds(
        (const __attribute__((address_space(1))) void*)g,
        (__attribute__((address_space(3))) void*)l, 16, 0, 0);
}

// pack one 16x32 chunk of fp32 [rows][KD] into bf16 MFMA fragment(s).
// Fragment (16x16x32 bf16): lane l <-> row = l&15, k = (l>>4)*8 + i.
// dst[rb][unit][lane][8]: hi unit = kc, mid unit = KD/32 + kc.
__device__ __forceinline__ void pack_frag(const float* __restrict__ src,
                                          unsigned short* __restrict__ dst,
                                          int KD, int KBT, int rb, int kc,
                                          int lane, bool with_mid) {
    int row = rb * 16 + (lane & 15);
    int k0  = kc * 32 + (lane >> 4) * 8;
    const float* p = src + (size_t)row * KD + k0;
    float x[8];
    *(float4*)(x)     = *(const float4*)(p);
    *(float4*)(x + 4) = *(const float4*)(p + 4);
    short8 hv, mv;
    #pragma unroll
    for (int i = 0; i < 8; ++i) {
        u32 hb = f2bf(x[i]);
        hv[i] = (short)hb;
        mv[i] = (short)f2bf(x[i] - bf2f(hb));
    }
    *(short8*)(dst + ((size_t)(rb * KBT + kc) * 64 + lane) * 8) = hv;
    if (with_mid)
        *(short8*)(dst + ((size_t)(rb * KBT + KD / 32 + kc) * 64 + lane) * 8) = mv;
}

// ---------------- fused prep: pack X(hi), E(hi), W1(full), W2(hi) + t2 ----------------
__global__ __launch_bounds__(256) void prep_kernel(
    const float* __restrict__ X, const float* __restrict__ E,
    const float* __restrict__ W1, const float* __restrict__ W2,
    unsigned short* __restrict__ Xp, unsigned short* __restrict__ Ep,
    unsigned short* __restrict__ W1p, unsigned short* __restrict__ W2p,
    float* __restrict__ t2)
{
    int b = blockIdx.x;
    int wid = threadIdx.x >> 6, lane = threadIdx.x & 63;
    if (b < 1024) {                         // X hi: 4096 gids (512 rb x 8 kc)
        int gid = b * 4 + wid;
        pack_frag(X, Xp, 256, 8, gid >> 3, gid & 7, lane, false);
    } else if (b < 3072) {                  // E hi: 8192 gids (1024 rb x 8 kc)
        int gid = (b - 1024) * 4 + wid;
        pack_frag(E, Ep, 256, 8, gid >> 3, gid & 7, lane, false);
    } else if (b < 3200) {                  // W1 full: 512 gids (64 rb x 8 kc)
        int gid = (b - 3072) * 4 + wid;
        pack_frag(W1, W1p, 256, 16, gid >> 3, gid & 7, lane, true);
    } else if (b < 3328) {                  // W2 hi: 512 gids (16 rb x 32 kc)
        int gid = (b - 3200) * 4 + wid;
        pack_frag(W2, W2p, 1024, 32, gid >> 5, gid & 31, lane, false);
    } else {                                // t2: 1024 blocks x 4 gids x 4 rows
        int gid = (b - 3328) * 4 + wid;
        #pragma unroll
        for (int r = 0; r < 4; ++r) {
            int row = gid * 4 + r;
            float4 v = ((const float4*)(E + (size_t)row * DIM))[lane];
            float s = v.x * v.x + v.y * v.y + v.z * v.z + v.w * v.w;
            #pragma unroll
            for (int off = 32; off > 0; off >>= 1) s += __shfl_down(s, off);
            if (lane == 0) t2[row] = s;
        }
    }
}

// ---------------- MFMA distance (bf16 hi-only), 256x256 tile, 8 waves ----------------
// BK=32: 8 steps, 2x32KB dbuf, counted vmcnt(4), 2 blocks/CU co-residency.
// Per-block top-2 per row via u32 keys: [24b positive-score bits | 8b local col].
__global__ __launch_bounds__(512, 2) void dist_topk_kernel(
    const unsigned short* __restrict__ Xp, const unsigned short* __restrict__ Ep,
    const float* __restrict__ t2, u64* __restrict__ ptop)
{
    __shared__ __align__(16) char lds[67584];   // main: 2x32KB; epi: [128][66] uint2

    int bx = blockIdx.x;          // 32 mt x 64 nt
    int mt = bx >> 6, nt = bx & 63;
    int mb0 = mt * 16, nb0 = nt * 16;
    int m0 = mt * 256, n0 = nt * 256;

    int tid = threadIdx.x;
    int wid = tid >> 6, lane = tid & 63;
    int wm = wid >> 2, wn = wid & 3;            // 2 x 4 wave grid; wave = 128x64 out

    f32x4 acc[8][4] = {};

    auto STAGE = [&](int s) {                   // stage K32-slice s into buffer s&1
        char* L = lds + (s & 1) * 32768;
        #pragma unroll
        for (int c = 0; c < 4; ++c) {
            int ci = wid * 4 + c;               // 0..31: A rb 0..15, B rb 0..15
            if (ci < 16)
                gload16(Xp + ((size_t)((mb0 + ci) * 8 + s) * 64 + lane) * 8,
                        L + ci * 1024);
            else
                gload16(Ep + ((size_t)((nb0 + (ci - 16)) * 8 + s) * 64 + lane) * 8,
                        L + 16384 + (ci - 16) * 1024);
        }
    };

    STAGE(0);
    #pragma unroll
    for (int s = 0; s < 8; ++s) {
        if (s < 7) { STAGE(s + 1); WAITVM(4); }   // wait stage-s loads only
        else       { WAITVM(0); }
        __builtin_amdgcn_s_barrier();
        __builtin_amdgcn_sched_barrier(0);
        const char* LA = lds + (s & 1) * 32768;
        const char* LB = LA + 16384;
        short8 a[8], b[4];
        #pragma unroll
        for (int i = 0; i < 8; ++i)
            a[i] = *(const short8*)(LA + ((wm * 8 + i) << 10) + (lane << 4));
        #pragma unroll
        for (int j = 0; j < 4; ++j)
            b[j] = *(const short8*)(LB + ((wn * 4 + j) << 10) + (lane << 4));
        #pragma unroll
        for (int i = 0; i < 8; ++i)
            #pragma unroll
            for (int j = 0; j < 4; ++j)
                acc[i][j] = __builtin_amdgcn_mfma_f32_16x16x32_bf16(
                    a[i], b[j], acc[i][j], 0, 0, 0);
        WAITLGKM0;
        __builtin_amdgcn_sched_barrier(0);
        __builtin_amdgcn_s_barrier();
    }

    // ---- epilogue: per-row top-2 over 256 cols, two 128-row passes ----
    // C frag: col = lane&15, row = (lane>>4)*4 + r.  Keys: positive floats
    // (score + 4096 > 0) are uint-ordered; key = (bits & 0xFFFFFF00) | local_col.
    int col_l = lane & 15, lg = lane >> 4;
    float t2b[4];
    #pragma unroll
    for (int j = 0; j < 4; ++j) t2b[j] = t2[n0 + wn * 64 + j * 16 + col_l] + 4096.0f;

    uint2* cand = (uint2*)lds;                  // [128 rows][66 slots] (stride 66: 2-way max)
    #pragma unroll
    for (int p = 0; p < 2; ++p) {
        if (p) __syncthreads();                 // protect cand reuse between passes
        #pragma unroll
        for (int i2 = 0; i2 < 4; ++i2) {
            int i = p * 4 + i2;
            #pragma unroll
            for (int r = 0; r < 4; ++r) {
                u32 b0 = 0xFFFFFFFFu, b1 = 0xFFFFFFFFu;
                #pragma unroll
                for (int j = 0; j < 4; ++j) {
                    float sc = fmaf(-2.0f, acc[i][j][r], t2b[j]);
                    u32 u = (__float_as_uint(sc) & 0xFFFFFF00u)
                          | (u32)(wn * 64 + j * 16 + col_l);
                    u32 t = umin32(b0, u);
                    b1 = umin32(b1, umax32(b0, u));
                    b0 = t;
                }
                int rr = wm * 64 + i2 * 16 + lg * 4 + r;         // 0..127
                cand[rr * 66 + wn * 16 + col_l] = make_uint2(b0, b1);
            }
        }
        __syncthreads();
        // phase B: 4 threads per row, strided slots, 2 shfl merges
        {
            int row = tid >> 2, part = tid & 3;
            u32 c0 = 0xFFFFFFFFu, c1 = 0xFFFFFFFFu;
            #pragma unroll 4
            for (int t = 0; t < 16; ++t) {
                uint2 a2 = cand[row * 66 + part + 4 * t];
                u32 lo = umin32(c0, a2.x);
                c1 = umin32(umax32(c0, a2.x), umin32(c1, a2.y));
                c0 = lo;
            }
            #pragma unroll
            for (int mask = 1; mask <= 2; mask <<= 1) {
                u32 a0 = __shfl_xor(c0, mask);
                u32 a1 = __shfl_xor(c1, mask);
                u32 lo = umin32(c0, a0);
                c1 = umin32(umax32(c0, a0), umin32(c1, a1));
                c0 = lo;
            }
            if (part == 0) {
                int row_g = m0 + (row >> 6) * 128 + p * 64 + (row & 63);
                u64 e0 = ((u64)(c0 >> 8) << 14) | (u32)(n0 + (c0 & 0xFF));
                u64 e1 = ((u64)(c1 >> 8) << 14) | (u32)(n0 + (c1 & 0xFF));
                size_t o = ((size_t)row_g * NT2 + nt) * 2;
                ptop[o] = e0; ptop[o + 1] = e1;
            }
        }
    }
}

// ---------------- merge -> top-3 -> exact fp64 rescreen -> gather + final idx ----------------
__global__ __launch_bounds__(256) void merge_rescreen_kernel(
    const float* __restrict__ X, const float* __restrict__ E,
    const u64* __restrict__ ptop, float* __restrict__ out, int* __restrict__ fidx)
{
    int wid = threadIdx.x >> 6, lane = threadIdx.x & 63;
    int q = blockIdx.x * 4 + wid;
    const u64* row = ptop + (size_t)q * (NT2 * 2);
    u64 k[2];
    #pragma unroll
    for (int t = 0; t < 2; ++t) k[t] = row[lane * 2 + t];
    int cand[3];
    #pragma unroll
    for (int pass = 0; pass < 3; ++pass) {
        u64 m = umin64(k[0], k[1]);
        #pragma unroll
        for (int mask = 1; mask < 64; mask <<= 1)
            m = umin64(m, (u64)__shfl_xor((unsigned long long)m, mask));
        cand[pass] = (int)(m & 0x3FFF);
        #pragma unroll
        for (int t = 0; t < 2; ++t) if (k[t] == m) k[t] = ~0ull;
    }
    float4 qv = ((const float4*)(X + (size_t)q * DIM))[lane];
    double bd = 1e300; int bi = NK;
    #pragma unroll 1
    for (int c = 0; c < 3; ++c) {
        int idx = cand[c];
        float4 ev = ((const float4*)(E + (size_t)idx * DIM))[lane];
        double d0 = (double)qv.x - (double)ev.x;
        double d1 = (double)qv.y - (double)ev.y;
        double d2 = (double)qv.z - (double)ev.z;
        double d3 = (double)qv.w - (double)ev.w;
        double s = d0 * d0 + d1 * d1 + d2 * d2 + d3 * d3;
        #pragma unroll
        for (int off = 32; off > 0; off >>= 1) s += __shfl_down(s, off);
        s = __shfl(s, 0);
        if (s < bd || (s == bd && idx < bi)) { bd = s; bi = idx; }
    }
    float4 ev = ((const float4*)(E + (size_t)bi * DIM))[lane];
    ((float4*)(out + OFF_ZEMB + (size_t)q * DIM))[lane] = ev;
    ((float4*)(out + OFF_ZENC + (size_t)q * DIM))[lane] = qv;
    if (lane == 0) fidx[q] = bi;
}

// ---------------- multi-limb bf16 MFMA GEMM: C[M][N] = A[M][KD]*B[N][KD]^T + bias ----------
// GATHER: A-fragments gathered per-lane from Ap (codebook pack) via selidx.
// G1: bias+LeakyReLU, repack hi-limb into Hp (gemm2 A-fragment layout, 32 units).
// Counted-vmcnt dual-barrier pipeline.
template <int KD, int A_KBT, int B_KBT, int NPROD, int AO1, int BO1,
          int NRB_B, int NT, bool G1, bool GATHER>
__global__ __launch_bounds__(256) void gemm_mfma_kernel(
    const unsigned short* __restrict__ Ap, const unsigned short* __restrict__ Bp,
    const int* __restrict__ selidx, const float* __restrict__ bias,
    float* __restrict__ C, unsigned short* __restrict__ Hp)
{
    constexpr int KQ    = KD / 64;
    constexpr int STEPS = NPROD * KQ;
    constexpr int FJ    = NRB_B / 2;
    constexpr int CB    = NRB_B * 2;
    constexpr int PW    = (16 + CB) / 4;
    constexpr int BUFSZ = (16 + CB) * 1024;
    constexpr int BN    = NRB_B * 16;
    constexpr int LDSSZ = (2 * BUFSZ > 65536 || G1) ? 65536 : 2 * BUFSZ;

    __shared__ __align__(16) char lds[LDSSZ];

    int bx = blockIdx.x;
    int mt = bx / NT, nt = bx % NT;
    int mb0 = mt * 8, nb0 = nt * NRB_B;
    int m0 = mt * 128, n0 = nt * BN;

    int tid = threadIdx.x;
    int wid = tid >> 6, lane = tid & 63;
    int wm = wid >> 1, wn = wid & 1;

    f32x4 acc[4][FJ] = {};

    auto STAGE = [&](int s, int b) {
        int p = s / KQ, kq = s % KQ;
        int akb = (p == 0 ? 0 : AO1) + kq * 2;
        int bkb = (p == 0 ? 0 : BO1) + kq * 2;
        char* LA = lds + b * BUFSZ;
        char* LB = LA + 16384;
        #pragma unroll
        for (int r = 0; r < PW; ++r) {
            int ci = wid * PW + r;
            if (ci < 16) {
                int rbl = ci >> 1, kbl = ci & 1;
                size_t ga;
                if constexpr (GATHER) {
                    int sel = selidx[(mb0 + rbl) * 16 + (lane & 15)];
                    ga = ((size_t)((sel >> 4) * A_KBT + akb + kbl) * 64
                          + (lane >> 4) * 16 + (sel & 15)) * 8;
                } else {
                    ga = ((size_t)((mb0 + rbl) * A_KBT + akb + kbl) * 64 + lane) * 8;
                }
                gload16(Ap + ga, LA + ci * 1024);
            } else {
                int cj = ci - 16, rbl = cj >> 1, kbl = cj & 1;
                gload16(Bp + ((size_t)((nb0 + rbl) * B_KBT + bkb + kbl) * 64 + lane) * 8,
                        LB + cj * 1024);
            }
        }
    };

    STAGE(0, 0);
    for (int s = 0; s < STEPS; ++s) {
        int cur = s & 1;
        if (s + 1 < STEPS) { STAGE(s + 1, cur ^ 1); waitvm_c<PW>(); }
        else               { waitvm_c<0>(); }
        __builtin_amdgcn_s_barrier();
        __builtin_amdgcn_sched_barrier(0);
        const char* LA = lds + cur * BUFSZ;
        const char* LB = LA + 16384;
        #pragma unroll
        for (int kk = 0; kk < 2; ++kk) {
            short8 a[4], b[FJ];
            #pragma unroll
            for (int i = 0; i < 4; ++i)
                a[i] = *(const short8*)(LA + (((wm * 4 + i) * 2 + kk) << 10) + (lane << 4));
            #pragma unroll
            for (int j = 0; j < FJ; ++j)
                b[j] = *(const short8*)(LB + (((wn * FJ + j) * 2 + kk) << 10) + (lane << 4));
            #pragma unroll
            for (int i = 0; i < 4; ++i)
                #pragma unroll
                for (int j = 0; j < FJ; ++j)
                    acc[i][j] = __builtin_amdgcn_mfma_f32_16x16x32_bf16(
                        a[i], b[j], acc[i][j], 0, 0, 0);
        }
        WAITLGKM0;
        __builtin_amdgcn_sched_barrier(0);
        __builtin_amdgcn_s_barrier();
    }

    int col_l = lane & 15, lg = lane >> 4;
    if (!G1) {
        #pragma unroll
        for (int j = 0; j < FJ; ++j) {
            int n = n0 + wn * (BN / 2) + j * 16 + col_l;
            float bb = bias[n];
            #pragma unroll
            for (int i = 0; i < 4; ++i)
                #pragma unroll
                for (int r = 0; r < 4; ++r) {
                    int m = m0 + wm * 64 + i * 16 + lg * 4 + r;
                    C[(size_t)m * (NT * BN) + n] = acc[i][j][r] + bb;
                }
        }
    } else {
        // bias + LeakyReLU + bf16(hi) -> swizzled LDS u16 tile -> repack to Hp frags
        unsigned short* lds16 = (unsigned short*)lds;
        #pragma unroll
        for (int j = 0; j < FJ; ++j) {
            int coln = wn * 64 + j * 16 + col_l;
            float bb = bias[n0 + coln];
            #pragma unroll
            for (int i = 0; i < 4; ++i)
                #pragma unroll
                for (int r = 0; r < 4; ++r) {
                    int row = wm * 64 + i * 16 + lg * 4 + r;
                    float v = acc[i][j][r] + bb;
                    v = fmaxf(v, 0.1f * v);
                    int sw = ((row >> 2) & 3) << 3;
                    lds16[row * 128 + (coln ^ sw)] = (unsigned short)f2bf(v);
                }
        }
        __syncthreads();
        #pragma unroll
        for (int rbw = 0; rbw < 2; ++rbw) {
            int rrb = wid * 2 + rbw;
            int rloc = lane & 15, ls = lane >> 4;
            int row = rrb * 16 + rloc;
            int sw  = ((row >> 2) & 3) << 3;
            #pragma unroll
            for (int kc = 0; kc < 4; ++kc) {
                int c0 = (kc * 32 + ls * 8) ^ sw;
                short8 h8 = *(const short8*)(lds16 + row * 128 + c0);
                int ku = nt * 4 + kc;              // unit within KD2=1024 hi (32 units)
                *(short8*)(Hp + ((size_t)((mb0 + rrb) * 32 + ku) * 64 + lane) * 8) = h8;
            }
        }
    }
}

extern "C" void kernel_launch(void* const* d_in, const int* in_sizes, int n_in,
                              void* d_out, int out_size, void* d_ws, size_t ws_size,
                              hipStream_t stream) {
    const float* X    = (const float*)d_in[0];
    const float* embd = (const float*)d_in[1];
    const float* W1   = (const float*)d_in[2];
    const float* b1   = (const float*)d_in[3];
    const float* W2   = (const float*)d_in[4];
    const float* b2   = (const float*)d_in[5];
    float* out = (float*)d_out;

    // ws (MiB): t2[0,.06) fidx[.06,.09) ptop[1,9) Xp[17,21) Ep[21,29) W1p[37,38) W2p[38,38.5)
    // Hp[1,17) aliases ptop (dead after merge). Ep survives gemm1 (A-gather source).
    char* w = (char*)d_ws;
    float* t2 = (float*)w;
    int*  fidx = (int*)(w + 65536);
    u64*  ptop = (u64*)(w + (1u << 20));
    unsigned short* Hp  = (unsigned short*)(w + (1u << 20));
    unsigned short* Xp  = (unsigned short*)(w + (17u << 20));
    unsigned short* Ep  = (unsigned short*)(w + (21u << 20));
    unsigned short* W1p = (unsigned short*)(w + (37u << 20));
    unsigned short* W2p = (unsigned short*)(w + (38u << 20));

    prep_kernel<<<dim3(4352), dim3(256), 0, stream>>>(
        X, embd, W1, W2, Xp, Ep, W1p, W2p, t2);
    dist_topk_kernel<<<dim3(2048), dim3(512), 0, stream>>>(Xp, Ep, t2, ptop);
    merge_rescreen_kernel<<<dim3(NBN / 4), dim3(256), 0, stream>>>(
        X, embd, ptop, out, fidx);
    // gemm1: h = Zemb*W1^T (+b1, LReLU): A gathered from Ep(hi) via fidx, 2 limbs (xh*wh + xh*wm)
    gemm_mfma_kernel<256, 8, 16, 2, 0, 8, 8, 8, true, true>
        <<<dim3(512), dim3(256), 0, stream>>>(Ep, W1p, fidx, b1, nullptr, Hp);
    // gemm2: Zrec = h*W2^T (+b2): A = Hp (hi), B = W2p (hi), 1 limb
    gemm_mfma_kernel<1024, 32, 32, 1, 0, 0, 4, 4, false, false>
        <<<dim3(256), dim3(256), 0, stream>>>(Hp, W2p, nullptr, b2, out + OFF_ZREC, nullptr);
}

// Round 10
// 160.156 us; speedup vs baseline: 8.8375x; 1.0065x over previous
//
#include <hip/hip_runtime.h>
#include <float.h>

// B=8, N=1024, D=256, K=16384, H=1024, IN=256
#define DIM      256
#define NK       16384
#define NH       1024
#define NIN      256
#define NBN      8192
#define NT2      128           // NK / 128 (dist n-tiles)

#define OFF_ZREC 0
#define OFF_ZENC (NBN * DIM)
#define OFF_ZEMB (2 * NBN * DIM)

using short8 = __attribute__((ext_vector_type(8))) short;
using f32x4  = __attribute__((ext_vector_type(4))) float;
typedef unsigned long long u64;
typedef unsigned int u32;

#define WAITVM(n)  asm volatile("s_waitcnt vmcnt(" #n ")" ::: "memory")
#define WAITLGKM0  asm volatile("s_waitcnt lgkmcnt(0)" ::: "memory")

template <int N>
__device__ __forceinline__ void waitvm_c() {
    // s_waitcnt imm: vmcnt[3:0]@[3:0], vmcnt[5:4]@[15:14], expcnt@[6:4], lgkmcnt@[11:8]
    __builtin_amdgcn_s_waitcnt(0x0F70 | (N & 0xF) | (((N >> 4) & 3) << 14));
}

__device__ __forceinline__ u32 f2bf(float f) {
    u32 u = __float_as_uint(f);
    return (u + 0x7FFFu + ((u >> 16) & 1u)) >> 16;   // RNE
}
__device__ __forceinline__ float bf2f(u32 h) {
    return __uint_as_float(h << 16);
}
__device__ __forceinline__ u64 umin64(u64 a, u64 b) { return a < b ? a : b; }
__device__ __forceinline__ u32 umin32(u32 a, u32 b) { return a < b ? a : b; }
__device__ __forceinline__ u32 umax32(u32 a, u32 b) { return a > b ? a : b; }

__device__ __forceinline__ void gload16(const void* g, void* l) {
    __builtin_amdgcn_global_load_lds(
        (const __attribute__((address_space(1))) void*)g,
        (__attribute__((address_space(3))) void*)l, 16, 0, 0);
}

// pack one 16x32 chunk of fp32 [rows][KD] into bf16 MFMA fragment(s).
// Fragment (16x16x32 bf16): lane l <-> row = l&15, k = (l>>4)*8 + i.
// dst[rb][unit][lane][8]: hi unit = kc, mid unit = KD/32 + kc.
__device__ __forceinline__ void pack_frag(const float* __restrict__ src,
                                          unsigned short* __restrict__ dst,
                                          int KD, int KBT, int rb, int kc,
                                          int lane, bool with_mid) {
    int row = rb * 16 + (lane & 15);
    int k0  = kc * 32 + (lane >> 4) * 8;
    const float* p = src + (size_t)row * KD + k0;
    float x[8];
    *(float4*)(x)     = *(const float4*)(p);
    *(float4*)(x + 4) = *(const float4*)(p + 4);
    short8 hv, mv;
    #pragma unroll
    for (int i = 0; i < 8; ++i) {
        u32 hb = f2bf(x[i]);
        hv[i] = (short)hb;
        mv[i] = (short)f2bf(x[i] - bf2f(hb));
    }
    *(short8*)(dst + ((size_t)(rb * KBT + kc) * 64 + lane) * 8) = hv;
    if (with_mid)
        *(short8*)(dst + ((size_t)(rb * KBT + KD / 32 + kc) * 64 + lane) * 8) = mv;
}

// ---------------- fused prep: pack X(hi), E(hi), W1(full), W2(hi) + t2 ----------------
__global__ __launch_bounds__(256) void prep_kernel(
    const float* __restrict__ X, const float* __restrict__ E,
    const float* __restrict__ W1, const float* __restrict__ W2,
    unsigned short* __restrict__ Xp, unsigned short* __restrict__ Ep,
    unsigned short* __restrict__ W1p, unsigned short* __restrict__ W2p,
    float* __restrict__ t2)
{
    int b = blockIdx.x;
    int wid = threadIdx.x >> 6, lane = threadIdx.x & 63;
    if (b < 1024) {                         // X hi: 4096 gids (512 rb x 8 kc)
        int gid = b * 4 + wid;
        pack_frag(X, Xp, 256, 8, gid >> 3, gid & 7, lane, false);
    } else if (b < 3072) {                  // E hi: 8192 gids (1024 rb x 8 kc)
        int gid = (b - 1024) * 4 + wid;
        pack_frag(E, Ep, 256, 8, gid >> 3, gid & 7, lane, false);
    } else if (b < 3200) {                  // W1 full: 512 gids (64 rb x 8 kc)
        int gid = (b - 3072) * 4 + wid;
        pack_frag(W1, W1p, 256, 16, gid >> 3, gid & 7, lane, true);
    } else if (b < 3328) {                  // W2 hi: 512 gids (16 rb x 32 kc)
        int gid = (b - 3200) * 4 + wid;
        pack_frag(W2, W2p, 1024, 32, gid >> 5, gid & 31, lane, false);
    } else {                                // t2: 1024 blocks x 4 gids x 4 rows
        int gid = (b - 3328) * 4 + wid;
        #pragma unroll
        for (int r = 0; r < 4; ++r) {
            int row = gid * 4 + r;
            float4 v = ((const float4*)(E + (size_t)row * DIM))[lane];
            float s = v.x * v.x + v.y * v.y + v.z * v.z + v.w * v.w;
            #pragma unroll
            for (int off = 32; off > 0; off >>= 1) s += __shfl_down(s, off);
            if (lane == 0) t2[row] = s;
        }
    }
}

// ---------------- MFMA distance (bf16 hi-only), 256x128 tile, 8 waves (4m x 2n) ----------
// Wave tile 64x64 (acc[4][4] = 64 regs -> 3 waves/SIMD). BK=32, 2x24KB dbuf, vmcnt(3).
// Per-block top-2 per row via u32 keys: [24b positive-score bits | 8b local col].
__global__ __launch_bounds__(512, 3) void dist_topk_kernel(
    const unsigned short* __restrict__ Xp, const unsigned short* __restrict__ Ep,
    const float* __restrict__ t2, uint2* __restrict__ ptop)
{
    __shared__ __align__(16) char lds[67584];   // main: 2x24KB; epi: 2 x [256][33] u32

    int bx = blockIdx.x;          // 32 mt x 128 nt
    int mt = bx >> 7, nt = bx & 127;
    int mb0 = mt * 16, nb0 = nt * 8;
    int m0 = mt * 256, n0 = nt * 128;

    int tid = threadIdx.x;
    int wid = tid >> 6, lane = tid & 63;
    int wm = wid >> 1, wn = wid & 1;            // 4 x 2 wave grid; wave = 64x64 out

    f32x4 acc[4][4] = {};

    auto STAGE = [&](int s) {                   // stage K32-slice s into buffer s&1
        char* L = lds + (s & 1) * 24576;
        #pragma unroll
        for (int c = 0; c < 3; ++c) {
            int ci = wid * 3 + c;               // 0..23: A rb 0..15, B rb 0..7
            if (ci < 16)
                gload16(Xp + ((size_t)((mb0 + ci) * 8 + s) * 64 + lane) * 8,
                        L + ci * 1024);
            else
                gload16(Ep + ((size_t)((nb0 + (ci - 16)) * 8 + s) * 64 + lane) * 8,
                        L + 16384 + (ci - 16) * 1024);
        }
    };

    STAGE(0);
    #pragma unroll
    for (int s = 0; s < 8; ++s) {
        if (s < 7) { STAGE(s + 1); WAITVM(3); }   // wait stage-s loads only
        else       { WAITVM(0); }
        __builtin_amdgcn_s_barrier();
        __builtin_amdgcn_sched_barrier(0);
        const char* LA = lds + (s & 1) * 24576;
        const char* LB = LA + 16384;
        short8 a[4], b[4];
        #pragma unroll
        for (int i = 0; i < 4; ++i)
            a[i] = *(const short8*)(LA + ((wm * 4 + i) << 10) + (lane << 4));
        #pragma unroll
        for (int j = 0; j < 4; ++j)
            b[j] = *(const short8*)(LB + ((wn * 4 + j) << 10) + (lane << 4));
        #pragma unroll
        for (int i = 0; i < 4; ++i)
            #pragma unroll
            for (int j = 0; j < 4; ++j)
                acc[i][j] = __builtin_amdgcn_mfma_f32_16x16x32_bf16(
                    a[i], b[j], acc[i][j], 0, 0, 0);
        WAITLGKM0;
        __builtin_amdgcn_sched_barrier(0);
        __builtin_amdgcn_s_barrier();
    }

    // ---- epilogue: per-row top-2 over this block's 128 cols, single pass ----
    // C frag: col = lane&15, row = (lane>>4)*4 + r.  Keys: positive floats
    // (score + 4096 > 0) are uint-ordered; key = (bits & 0xFFFFFF00) | local_col.
    int col_l = lane & 15, lg = lane >> 4;
    float t2b[4];
    #pragma unroll
    for (int j = 0; j < 4; ++j) t2b[j] = t2[n0 + wn * 64 + j * 16 + col_l] + 4096.0f;

    u32* cand0 = (u32*)lds;                     // [256 rows][33 slots]
    u32* cand1 = cand0 + 256 * 33;
    #pragma unroll
    for (int i = 0; i < 4; ++i)
        #pragma unroll
        for (int r = 0; r < 4; ++r) {
            u32 b0 = 0xFFFFFFFFu, b1 = 0xFFFFFFFFu;
            #pragma unroll
            for (int j = 0; j < 4; ++j) {
                float sc = fmaf(-2.0f, acc[i][j][r], t2b[j]);
                u32 u = (__float_as_uint(sc) & 0xFFFFFF00u)
                      | (u32)(wn * 64 + j * 16 + col_l);
                u32 t = umin32(b0, u);
                b1 = umin32(b1, umax32(b0, u));
                b0 = t;
            }
            int row = wm * 64 + i * 16 + lg * 4 + r;             // 0..255
            int slot = wn * 16 + col_l;                          // 0..31
            cand0[row * 33 + slot] = b0;
            cand1[row * 33 + slot] = b1;
        }
    __syncthreads();
    // scan: 2 threads per row, 16 staggered slots each, 1 shfl merge
    {
        int row = tid >> 1, part = tid & 1;
        u32 c0 = 0xFFFFFFFFu, c1 = 0xFFFFFFFFu;
        #pragma unroll 4
        for (int t = 0; t < 16; ++t) {
            int sl = part * 16 + ((t + row) & 15);
            u32 a0 = cand0[row * 33 + sl];
            u32 a1 = cand1[row * 33 + sl];
            u32 lo = umin32(c0, a0);
            c1 = umin32(umax32(c0, a0), umin32(c1, a1));
            c0 = lo;
        }
        u32 a0 = __shfl_xor(c0, 1);
        u32 a1 = __shfl_xor(c1, 1);
        u32 lo = umin32(c0, a0);
        c1 = umin32(umax32(c0, a0), umin32(c1, a1));
        c0 = lo;
        if (part == 0)
            ptop[(size_t)(m0 + row) * NT2 + nt] = make_uint2(c0, c1);
    }
}

// ---------------- merge -> top-3 -> exact fp64 rescreen -> gather + final idx ----------------
__global__ __launch_bounds__(256) void merge_rescreen_kernel(
    const float* __restrict__ X, const float* __restrict__ E,
    const uint2* __restrict__ ptop, float* __restrict__ out, int* __restrict__ fidx)
{
    int wid = threadIdx.x >> 6, lane = threadIdx.x & 63;
    int q = blockIdx.x * 4 + wid;
    const uint2* row = ptop + (size_t)q * NT2;
    uint2 A = row[lane * 2], B = row[lane * 2 + 1];
    // rebuild globally-ordered keys: [24b score @ bits 14..37 | 14b global k]
    u64 k[4];
    k[0] = ((u64)(A.x & 0xFFFFFF00u) << 6) | (u32)((lane * 2) * 128 + (A.x & 0xFF));
    k[1] = ((u64)(A.y & 0xFFFFFF00u) << 6) | (u32)((lane * 2) * 128 + (A.y & 0xFF));
    k[2] = ((u64)(B.x & 0xFFFFFF00u) << 6) | (u32)((lane * 2 + 1) * 128 + (B.x & 0xFF));
    k[3] = ((u64)(B.y & 0xFFFFFF00u) << 6) | (u32)((lane * 2 + 1) * 128 + (B.y & 0xFF));
    int cand[3];
    #pragma unroll
    for (int pass = 0; pass < 3; ++pass) {
        u64 m = umin64(umin64(k[0], k[1]), umin64(k[2], k[3]));
        #pragma unroll
        for (int mask = 1; mask < 64; mask <<= 1)
            m = umin64(m, (u64)__shfl_xor((unsigned long long)m, mask));
        cand[pass] = (int)(m & 0x3FFF);
        #pragma unroll
        for (int t = 0; t < 4; ++t) if (k[t] == m) k[t] = ~0ull;
    }
    float4 qv = ((const float4*)(X + (size_t)q * DIM))[lane];
    double bd = 1e300; int bi = NK;
    #pragma unroll 1
    for (int c = 0; c < 3; ++c) {
        int idx = cand[c];
        float4 ev = ((const float4*)(E + (size_t)idx * DIM))[lane];
        double d0 = (double)qv.x - (double)ev.x;
        double d1 = (double)qv.y - (double)ev.y;
        double d2 = (double)qv.z - (double)ev.z;
        double d3 = (double)qv.w - (double)ev.w;
        double s = d0 * d0 + d1 * d1 + d2 * d2 + d3 * d3;
        #pragma unroll
        for (int off = 32; off > 0; off >>= 1) s += __shfl_down(s, off);
        s = __shfl(s, 0);
        if (s < bd || (s == bd && idx < bi)) { bd = s; bi = idx; }
    }
    float4 ev = ((const float4*)(E + (size_t)bi * DIM))[lane];
    ((float4*)(out + OFF_ZEMB + (size_t)q * DIM))[lane] = ev;
    ((float4*)(out + OFF_ZENC + (size_t)q * DIM))[lane] = qv;
    if (lane == 0) fidx[q] = bi;
}

// ---------------- multi-limb bf16 MFMA GEMM: C[M][N] = A[M][KD]*B[N][KD]^T + bias ----------
// GATHER: A-fragments gathered per-lane from Ap (codebook pack) via selidx.
// G1: bias+LeakyReLU, repack hi-limb into Hp (gemm2 A-fragment layout, 32 units).
// Counted-vmcnt dual-barrier pipeline.
template <int KD, int A_KBT, int B_KBT, int NPROD, int AO1, int BO1,
          int NRB_B, int NT, bool G1, bool GATHER>
__global__ __launch_bounds__(256) void gemm_mfma_kernel(
    const unsigned short* __restrict__ Ap, const unsigned short* __restrict__ Bp,
    const int* __restrict__ selidx, const float* __restrict__ bias,
    float* __restrict__ C, unsigned short* __restrict__ Hp)
{
    constexpr int KQ    = KD / 64;
    constexpr int STEPS = NPROD * KQ;
    constexpr int FJ    = NRB_B / 2;
    constexpr int CB    = NRB_B * 2;
    constexpr int PW    = (16 + CB) / 4;
    constexpr int BUFSZ = (16 + CB) * 1024;
    constexpr int BN    = NRB_B * 16;
    constexpr int LDSSZ = (2 * BUFSZ > 65536 || G1) ? 65536 : 2 * BUFSZ;

    __shared__ __align__(16) char lds[LDSSZ];

    int bx = blockIdx.x;
    int mt = bx / NT, nt = bx % NT;
    int mb0 = mt * 8, nb0 = nt * NRB_B;
    int m0 = mt * 128, n0 = nt * BN;

    int tid = threadIdx.x;
    int wid = tid >> 6, lane = tid & 63;
    int wm = wid >> 1, wn = wid & 1;

    f32x4 acc[4][FJ] = {};

    auto STAGE = [&](int s, int b) {
        int p = s / KQ, kq = s % KQ;
        int akb = (p == 0 ? 0 : AO1) + kq * 2;
        int bkb = (p == 0 ? 0 : BO1) + kq * 2;
        char* LA = lds + b * BUFSZ;
        char* LB = LA + 16384;
        #pragma unroll
        for (int r = 0; r < PW; ++r) {
            int ci = wid * PW + r;
            if (ci < 16) {
                int rbl = ci >> 1, kbl = ci & 1;
                size_t ga;
                if constexpr (GATHER) {
                    int sel = selidx[(mb0 + rbl) * 16 + (lane & 15)];
                    ga = ((size_t)((sel >> 4) * A_KBT + akb + kbl) * 64
                          + (lane >> 4) * 16 + (sel & 15)) * 8;
                } else {
                    ga = ((size_t)((mb0 + rbl) * A_KBT + akb + kbl) * 64 + lane) * 8;
                }
                gload16(Ap + ga, LA + ci * 1024);
            } else {
                int cj = ci - 16, rbl = cj >> 1, kbl = cj & 1;
                gload16(Bp + ((size_t)((nb0 + rbl) * B_KBT + bkb + kbl) * 64 + lane) * 8,
                        LB + cj * 1024);
            }
        }
    };

    STAGE(0, 0);
    for (int s = 0; s < STEPS; ++s) {
        int cur = s & 1;
        if (s + 1 < STEPS) { STAGE(s + 1, cur ^ 1); waitvm_c<PW>(); }
        else               { waitvm_c<0>(); }
        __builtin_amdgcn_s_barrier();
        __builtin_amdgcn_sched_barrier(0);
        const char* LA = lds + cur * BUFSZ;
        const char* LB = LA + 16384;
        #pragma unroll
        for (int kk = 0; kk < 2; ++kk) {
            short8 a[4], b[FJ];
            #pragma unroll
            for (int i = 0; i < 4; ++i)
                a[i] = *(const short8*)(LA + (((wm * 4 + i) * 2 + kk) << 10) + (lane << 4));
            #pragma unroll
            for (int j = 0; j < FJ; ++j)
                b[j] = *(const short8*)(LB + (((wn * FJ + j) * 2 + kk) << 10) + (lane << 4));
            #pragma unroll
            for (int i = 0; i < 4; ++i)
                #pragma unroll
                for (int j = 0; j < FJ; ++j)
                    acc[i][j] = __builtin_amdgcn_mfma_f32_16x16x32_bf16(
                        a[i], b[j], acc[i][j], 0, 0, 0);
        }
        WAITLGKM0;
        __builtin_amdgcn_sched_barrier(0);
        __builtin_amdgcn_s_barrier();
    }

    int col_l = lane & 15, lg = lane >> 4;
    if (!G1) {
        #pragma unroll
        for (int j = 0; j < FJ; ++j) {
            int n = n0 + wn * (BN / 2) + j * 16 + col_l;
            float bb = bias[n];
            #pragma unroll
            for (int i = 0; i < 4; ++i)
                #pragma unroll
                for (int r = 0; r < 4; ++r) {
                    int m = m0 + wm * 64 + i * 16 + lg * 4 + r;
                    C[(size_t)m * (NT * BN) + n] = acc[i][j][r] + bb;
                }
        }
    } else {
        // bias + LeakyReLU + bf16(hi) -> swizzled LDS u16 tile -> repack to Hp frags
        unsigned short* lds16 = (unsigned short*)lds;
        #pragma unroll
        for (int j = 0; j < FJ; ++j) {
            int coln = wn * 64 + j * 16 + col_l;
            float bb = bias[n0 + coln];
            #pragma unroll
            for (int i = 0; i < 4; ++i)
                #pragma unroll
                for (int r = 0; r < 4; ++r) {
                    int row = wm * 64 + i * 16 + lg * 4 + r;
                    float v = acc[i][j][r] + bb;
                    v = fmaxf(v, 0.1f * v);
                    int sw = ((row >> 2) & 3) << 3;
                    lds16[row * 128 + (coln ^ sw)] = (unsigned short)f2bf(v);
                }
        }
        __syncthreads();
        #pragma unroll
        for (int rbw = 0; rbw < 2; ++rbw) {
            int rrb = wid * 2 + rbw;
            int rloc = lane & 15, ls = lane >> 4;
            int row = rrb * 16 + rloc;
            int sw  = ((row >> 2) & 3) << 3;
            #pragma unroll
            for (int kc = 0; kc < 4; ++kc) {
                int c0 = (kc * 32 + ls * 8) ^ sw;
                short8 h8 = *(const short8*)(lds16 + row * 128 + c0);
                int ku = nt * 4 + kc;              // unit within KD2=1024 hi (32 units)
                *(short8*)(Hp + ((size_t)((mb0 + rrb) * 32 + ku) * 64 + lane) * 8) = h8;
            }
        }
    }
}

extern "C" void kernel_launch(void* const* d_in, const int* in_sizes, int n_in,
                              void* d_out, int out_size, void* d_ws, size_t ws_size,
                              hipStream_t stream) {
    const float* X    = (const float*)d_in[0];
    const float* embd = (const float*)d_in[1];
    const float* W1   = (const float*)d_in[2];
    const float* b1   = (const float*)d_in[3];
    const float* W2   = (const float*)d_in[4];
    const float* b2   = (const float*)d_in[5];
    float* out = (float*)d_out;

    // ws (MiB): t2[0,.06) fidx[.06,.09) ptop[1,9.4) Xp[17,21) Ep[21,29) W1p[37,38) W2p[38,38.5)
    // Hp[1,17) aliases ptop (dead after merge). Ep survives gemm1 (A-gather source).
    char* w = (char*)d_ws;
    float* t2 = (float*)w;
    int*  fidx = (int*)(w + 65536);
    uint2* ptop = (uint2*)(w + (1u << 20));
    unsigned short* Hp  = (unsigned short*)(w + (1u << 20));
    unsigned short* Xp  = (unsigned short*)(w + (17u << 20));
    unsigned short* Ep  = (unsigned short*)(w + (21u << 20));
    unsigned short* W1p = (unsigned short*)(w + (37u << 20));
    unsigned short* W2p = (unsigned short*)(w + (38u << 20));

    prep_kernel<<<dim3(4352), dim3(256), 0, stream>>>(
        X, embd, W1, W2, Xp, Ep, W1p, W2p, t2);
    dist_topk_kernel<<<dim3(4096), dim3(512), 0, stream>>>(Xp, Ep, t2, ptop);
    merge_rescreen_kernel<<<dim3(NBN / 4), dim3(256), 0, stream>>>(
        X, embd, ptop, out, fidx);
    // gemm1: h = Zemb*W1^T (+b1, LReLU): A gathered from Ep(hi) via fidx, 2 limbs (xh*wh + xh*wm)
    gemm_mfma_kernel<256, 8, 16, 2, 0, 8, 8, 8, true, true>
        <<<dim3(512), dim3(256), 0, stream>>>(Ep, W1p, fidx, b1, nullptr, Hp);
    // gemm2: Zrec = h*W2^T (+b2): A = Hp (hi), B = W2p (hi), 1 limb
    gemm_mfma_kernel<1024, 32, 32, 1, 0, 0, 4, 4, false, false>
        <<<dim3(256), dim3(256), 0, stream>>>(Hp, W2p, nullptr, b2, out + OFF_ZREC, nullptr);
}